// Round 2
// baseline (5901.614 us; speedup 1.0000x reference)
//
#include <hip/hip_runtime.h>

typedef unsigned short u16;
typedef unsigned int   u32;
typedef __attribute__((ext_vector_type(8))) __bf16 bfrag;   // 8 bf16 = 4 VGPR
typedef __attribute__((ext_vector_type(4))) float  f32x4;

#define DEVI static __device__ __forceinline__

// ---------------- geometry ----------------
// T=32 B=64 S=64 E=512 H=1024 L=2 (4H=4096)
// d_out (float) offsets: outputs, h_T, c_T, attn_std, attn_copy
constexpr long OUT_OFF = 0;         // 32*64*1024
constexpr long HT_OFF  = 2097152;   // 2*64*1024
constexpr long CT_OFF  = 2228224;
constexpr long AS_OFF  = 2359296;   // 32*64*64
constexpr long AC_OFF  = 2490368;

// ---------------- workspace layout (bytes) ----------------
constexpr long WIE_O   = 0;                        // W_ih0[:, :512]   bf16 4096x512
constexpr long WIF_O   = WIE_O  + 4096l*512*2;     // W_ih0[:, 512:]   bf16 4096x1024
constexpr long WHH0_O  = WIF_O  + 4096l*1024*2;    // W_hh0            bf16
constexpr long WIH1_O  = WHH0_O + 4096l*1024*2;    // W_ih1            bf16
constexpr long WHH1_O  = WIH1_O + 4096l*1024*2;    // W_hh1            bf16
constexpr long WAO_O   = WHH1_O + 4096l*1024*2;    // attn_out_w       bf16 1024x2048
constexpr long WAI_O   = WAO_O  + 1024l*2048*2;    // attn_in_w^T      bf16 (WaiT[j][k]=Wai[k][j])
constexpr long WC_O    = WAI_O  + 1024l*1024*2;    // copy_in_w^T      bf16
constexpr long CTX_O   = WC_O   + 1024l*1024*2;    // ctx (b,s,k)      bf16 64*64*1024
constexpr long CTXW_O  = CTX_O  + 64l*64*1024*2;   // ctx @ Wai        bf16
constexpr long CTXWC_O = CTXW_O + 64l*64*1024*2;   // ctx @ Wc         bf16
constexpr long EBF_O   = CTXWC_O+ 64l*64*1024*2;   // gathered emb     bf16 2048x512
constexpr long OUTS_O  = EBF_O  + 2048l*512*2;     // out-feed slots   bf16 33*64*1024
constexpr long HBF_O   = OUTS_O + 33l*64*1024*2;   // h state, 4 slots bf16 4*65536
constexpr long CWS_O   = HBF_O  + 4l*65536*2;      // c state          f32  2*65536
constexpr long WCTX_O  = CWS_O  + 2l*65536*4;      // weighted ctx     bf16 64*1024
constexpr long BAR_O   = WCTX_O + 65536l*2;        // barrier counters
// total ~78.9 MB

struct KParams {
  const int* input; const float* h0; const float* c0; const float* context;
  const float* init_output; const float* embedding;
  const float* W_ih0; const float* W_hh0; const float* b0;
  const float* W_ih1; const float* W_hh1; const float* b1;
  const float* attn_in; const float* attn_out; const float* copy_in;
  float* out; char* ws;
};

// ---------------- small helpers ----------------
DEVI float bf2f(u16 u) { u32 x = ((u32)u) << 16; return __builtin_bit_cast(float, x); }
DEVI u16 f2bf(float f) {
  u32 x = __builtin_bit_cast(u32, f);
  u32 r = x + 0x7fffu + ((x >> 16) & 1u);   // RNE
  return (u16)(r >> 16);
}
DEVI void cvtc(const float* s, u16* d) {    // 4 contiguous f32 -> 4 bf16
  float4 v = *(const float4*)s;
  uint2 u;
  u.x = (u32)f2bf(v.x) | ((u32)f2bf(v.y) << 16);
  u.y = (u32)f2bf(v.z) | ((u32)f2bf(v.w) << 16);
  *(uint2*)d = u;
}
DEVI float sigm(float x)  { return 1.f / (1.f + __expf(-x)); }
DEVI float tanh_(float x) { return 1.f - 2.f / (__expf(2.f * x) + 1.f); }

DEVI f32x4 mfma16(bfrag a, bfrag b, f32x4 c) {
  return __builtin_amdgcn_mfma_f32_16x16x32_bf16(a, b, c, 0, 0, 0);
}
DEVI bfrag ldf(const u16* p) { return *(const bfrag*)p; }

DEVI void unpack16(const u16* p, float* v) {
  const u32* u = (const u32*)p;
#pragma unroll
  for (int i = 0; i < 8; ++i) {
    u32 x = u[i];
    v[2 * i]     = bf2f((u16)(x & 0xffff));
    v[2 * i + 1] = bf2f((u16)(x >> 16));
  }
}

// grid barrier: bar[0]=count, bar[1]=generation (agent scope)
DEVI void gsync(u32* bar, u32 nblk) {
  __syncthreads();
  if (threadIdx.x == 0) {
    __builtin_amdgcn_fence(__ATOMIC_RELEASE, "agent");
    u32 gen  = __hip_atomic_load(bar + 1, __ATOMIC_RELAXED, __HIP_MEMORY_SCOPE_AGENT);
    u32 prev = __hip_atomic_fetch_add(bar, 1u, __ATOMIC_ACQ_REL, __HIP_MEMORY_SCOPE_AGENT);
    if (prev == nblk - 1) {
      __hip_atomic_store(bar, 0u, __ATOMIC_RELAXED, __HIP_MEMORY_SCOPE_AGENT);
      __hip_atomic_fetch_add(bar + 1, 1u, __ATOMIC_RELEASE, __HIP_MEMORY_SCOPE_AGENT);
    } else {
      while (__hip_atomic_load(bar + 1, __ATOMIC_RELAXED, __HIP_MEMORY_SCOPE_AGENT) == gen)
        __builtin_amdgcn_s_sleep(1);
    }
    __builtin_amdgcn_fence(__ATOMIC_ACQUIRE, "agent");
  }
  __syncthreads();
}

// ---------------- fused LSTM phase ----------------
// Block jt owns hidden units [jt*16, jt*16+16) for all 4 gates; 8 waves:
// wave w -> m-tile (w&3), gate pair (w>>2)*2. Up to 3 K-segments.
DEVI void lstm_phase(int jt,
                     const u16* A0, const u16* W0, int K0,
                     const u16* A1, const u16* W1, int K1,
                     const u16* A2, const u16* W2, int K2,
                     const float* bias, float* cstate, u16* hout, float* lds) {
  const int tid = threadIdx.x, lane = tid & 63, w = tid >> 6;
  const int mt = w & 3, ga = (w >> 2) * 2;
  const int arow = mt * 16 + (lane & 15);
  const int ke = (lane >> 4) * 8;
  const int ncol = jt * 16 + (lane & 15);
  f32x4 acc0 = {0.f, 0.f, 0.f, 0.f}, acc1 = acc0;
  {
    const u16* a  = A0 + (long)arow * K0 + ke;
    const u16* b0 = W0 + (long)(ga * 1024 + ncol) * K0 + ke;
    const u16* b1 = W0 + (long)((ga + 1) * 1024 + ncol) * K0 + ke;
    for (int kk = 0; kk < K0; kk += 32) {
      bfrag av = ldf(a + kk);
      acc0 = mfma16(av, ldf(b0 + kk), acc0);
      acc1 = mfma16(av, ldf(b1 + kk), acc1);
    }
  }
  {
    const u16* a  = A1 + (long)arow * K1 + ke;
    const u16* b0 = W1 + (long)(ga * 1024 + ncol) * K1 + ke;
    const u16* b1 = W1 + (long)((ga + 1) * 1024 + ncol) * K1 + ke;
    for (int kk = 0; kk < K1; kk += 32) {
      bfrag av = ldf(a + kk);
      acc0 = mfma16(av, ldf(b0 + kk), acc0);
      acc1 = mfma16(av, ldf(b1 + kk), acc1);
    }
  }
  if (K2 > 0) {
    const u16* a  = A2 + (long)arow * K2 + ke;
    const u16* b0 = W2 + (long)(ga * 1024 + ncol) * K2 + ke;
    const u16* b1 = W2 + (long)((ga + 1) * 1024 + ncol) * K2 + ke;
    for (int kk = 0; kk < K2; kk += 32) {
      bfrag av = ldf(a + kk);
      acc0 = mfma16(av, ldf(b0 + kk), acc0);
      acc1 = mfma16(av, ldf(b1 + kk), acc1);
    }
  }
  // exchange gates through LDS: lds[gate][m][j], 4*64*16 f32 = 16 KiB
  const int mr = mt * 16 + (lane >> 4) * 4;
#pragma unroll
  for (int r = 0; r < 4; ++r) {
    lds[((ga)     * 64 + mr + r) * 16 + (lane & 15)] = acc0[r];
    lds[((ga + 1) * 64 + mr + r) * 16 + (lane & 15)] = acc1[r];
  }
  __syncthreads();
  for (int p = tid; p < 1024; p += 512) {
    int m = p >> 4, j = p & 15, jg = jt * 16 + j;
    float gi = lds[(0 * 64 + m) * 16 + j] + bias[jg];
    float gf = lds[(1 * 64 + m) * 16 + j] + bias[1024 + jg];
    float gg = lds[(2 * 64 + m) * 16 + j] + bias[2048 + jg];
    float go = lds[(3 * 64 + m) * 16 + j] + bias[3072 + jg];
    float co = cstate[m * 1024 + jg];
    float cn = sigm(gf) * co + sigm(gi) * tanh_(gg);
    cstate[m * 1024 + jg] = cn;
    hout[m * 1024 + jg] = f2bf(sigm(go) * tanh_(cn));
  }
}

// ---------------- attention phase (block b = batch) ----------------
DEVI void attn_phase(int b, int t, int cur, const u16* Hbf, const u16* Ctx,
                     u16* Wctx, float* dout, const u16* ctxw_lds, float* scratch) {
  const int tid = threadIdx.x, lane = tid & 63, w = tid >> 6;
  float* lds_s = scratch;
  float* lds_a = scratch + 64;
  float h1v[16];
  unpack16(Hbf + (long)(2 + cur) * 65536 + b * 1024 + lane * 16, h1v);
#pragma unroll
  for (int si = 0; si < 8; ++si) {
    int s = w * 8 + si;
    const u32* u = (const u32*)(ctxw_lds + s * 1024 + lane * 16);
    float acc = 0.f;
#pragma unroll
    for (int i = 0; i < 8; ++i) {
      u32 x = u[i];
      acc += h1v[2 * i]     * bf2f((u16)(x & 0xffff));
      acc += h1v[2 * i + 1] * bf2f((u16)(x >> 16));
    }
#pragma unroll
    for (int off = 32; off; off >>= 1) acc += __shfl_down(acc, off, 64);
    if (lane == 0) lds_s[s] = acc;
  }
  __syncthreads();
  if (w == 0) {
    float v = lds_s[lane];
    float mx = v;
#pragma unroll
    for (int off = 32; off; off >>= 1) mx = fmaxf(mx, __shfl_xor(mx, off, 64));
    float e = __expf(v - mx);
    float sm = e;
#pragma unroll
    for (int off = 32; off; off >>= 1) sm += __shfl_xor(sm, off, 64);
    float a = e / sm;
    lds_a[lane] = a;
    dout[AS_OFF + (long)t * 4096 + b * 64 + lane] = a;
  }
  __syncthreads();
  // weighted context (f32 accumulate over bf16 ctx)
  int k0 = w * 128 + lane * 2;
  const u16* cb = Ctx + (long)b * 65536 + k0;
  float a0 = 0.f, a1 = 0.f;
  for (int s = 0; s < 64; ++s) {
    float as = lds_a[s];
    u32 x = *(const u32*)(cb + (long)s * 1024);
    a0 += as * bf2f((u16)(x & 0xffff));
    a1 += as * bf2f((u16)(x >> 16));
  }
  *(u32*)(Wctx + b * 1024 + k0) = (u32)f2bf(a0) | ((u32)f2bf(a1) << 16);
}

// ---------------- out-projection: tanh([wctx|h1] @ Wao^T) ----------------
DEVI void outproj_phase(int jt, int t, const u16* Wctx, const u16* H1,
                        const u16* Wao, float* dout, u16* outs_next, float* lds) {
  const int tid = threadIdx.x, lane = tid & 63, w = tid >> 6;
  const int half = w >> 2, mt = w & 3;
  const int arow = mt * 16 + (lane & 15);
  const int ke = (lane >> 4) * 8;
  const int ncol = jt * 16 + (lane & 15);
  const u16* A  = (half ? H1 : Wctx) + (long)arow * 1024 + ke;
  const u16* Bw = Wao + (long)ncol * 2048 + half * 1024 + ke;
  f32x4 acc = {0.f, 0.f, 0.f, 0.f};
  for (int kk = 0; kk < 1024; kk += 32)
    acc = mfma16(ldf(A + kk), ldf(Bw + kk), acc);
  if (half) {
#pragma unroll
    for (int r = 0; r < 4; ++r)
      lds[mt * 256 + ((lane >> 4) * 4 + r) * 16 + (lane & 15)] = acc[r];
  }
  __syncthreads();
  if (!half) {
#pragma unroll
    for (int r = 0; r < 4; ++r) {
      float v = acc[r] + lds[mt * 256 + ((lane >> 4) * 4 + r) * 16 + (lane & 15)];
      v = tanh_(v);
      int m = mt * 16 + (lane >> 4) * 4 + r, j = jt * 16 + (lane & 15);
      dout[(long)t * 65536 + m * 1024 + j] = v;
      outs_next[m * 1024 + j] = f2bf(v);
    }
  }
}

// ---------------- setup GEMM: dst[(b,s),j] = ctx[(b,s),:] . Wrow[j,:] ----------------
DEVI void ctxw_gemm(int mt, const u16* Ctx, const u16* Wm, u16* dst) {
  const int tid = threadIdx.x, lane = tid & 63, w = tid >> 6;
  const int arow = mt * 16 + (lane & 15);
  const int ke = (lane >> 4) * 8;
#pragma unroll
  for (int i = 0; i < 8; ++i) {
    int nt = w * 8 + i;
    const u16* A = Ctx + (long)arow * 1024 + ke;
    const u16* B = Wm + (long)(nt * 16 + (lane & 15)) * 1024 + ke;
    f32x4 acc = {0.f, 0.f, 0.f, 0.f};
    for (int kk = 0; kk < 1024; kk += 32)
      acc = mfma16(ldf(A + kk), ldf(B + kk), acc);
#pragma unroll
    for (int r = 0; r < 4; ++r)
      dst[(long)(mt * 16 + (lane >> 4) * 4 + r) * 1024 + nt * 16 + (lane & 15)] = f2bf(acc[r]);
  }
}

// ---------------- deferred copy-attention ----------------
DEVI void copy_attn(int b, const u16* Outs, const u16* ctxw_lds, float* dout, float* scratch) {
  const int tid = threadIdx.x, lane = tid & 63, w = tid >> 6;
  float* lds_s = scratch;
  for (int t = 0; t < 32; ++t) {
    float ov[16];
    unpack16(Outs + ((long)(t + 1) * 64 + b) * 1024 + lane * 16, ov);
#pragma unroll
    for (int si = 0; si < 8; ++si) {
      int s = w * 8 + si;
      const u32* u = (const u32*)(ctxw_lds + s * 1024 + lane * 16);
      float acc = 0.f;
#pragma unroll
      for (int i = 0; i < 8; ++i) {
        u32 x = u[i];
        acc += ov[2 * i]     * bf2f((u16)(x & 0xffff));
        acc += ov[2 * i + 1] * bf2f((u16)(x >> 16));
      }
#pragma unroll
      for (int off = 32; off; off >>= 1) acc += __shfl_down(acc, off, 64);
      if (lane == 0) lds_s[s] = acc;
    }
    __syncthreads();
    if (w == 0) {
      float v = lds_s[lane];
      float mx = v;
#pragma unroll
      for (int off = 32; off; off >>= 1) mx = fmaxf(mx, __shfl_xor(mx, off, 64));
      float e = __expf(v - mx);
      float sm = e;
#pragma unroll
      for (int off = 32; off; off >>= 1) sm += __shfl_xor(sm, off, 64);
      dout[AC_OFF + (long)t * 4096 + b * 64 + lane] = e / sm;
    }
    __syncthreads();
  }
}

// ---------------- the kernel ----------------
__global__ __launch_bounds__(512, 1) void decoder_kernel(KParams p) {
  extern __shared__ char smem[];
  u16*   ctxw_lds = (u16*)smem;                 // 131072 B
  float* scratch  = (float*)(smem + 131072);    // 16384 B

  char* ws = p.ws;
  u16* Wie   = (u16*)(ws + WIE_O);
  u16* Wif   = (u16*)(ws + WIF_O);
  u16* Whh0  = (u16*)(ws + WHH0_O);
  u16* Wih1  = (u16*)(ws + WIH1_O);
  u16* Whh1  = (u16*)(ws + WHH1_O);
  u16* Wao   = (u16*)(ws + WAO_O);
  u16* Wai   = (u16*)(ws + WAI_O);
  u16* Wc    = (u16*)(ws + WC_O);
  u16* Ctx   = (u16*)(ws + CTX_O);
  u16* CtxW  = (u16*)(ws + CTXW_O);
  u16* CtxWc = (u16*)(ws + CTXWC_O);
  u16* Ebf   = (u16*)(ws + EBF_O);
  u16* Outs  = (u16*)(ws + OUTS_O);
  u16* Hbf   = (u16*)(ws + HBF_O);
  float* Cws = (float*)(ws + CWS_O);
  u16* Wctx  = (u16*)(ws + WCTX_O);
  u32* bar   = (u32*)(ws + BAR_O);

  const int bid = blockIdx.x, tid = threadIdx.x;
  const long gtid = (long)bid * 512 + tid, NT = 256l * 512;

  // ---- S0: convert everything to bf16 working copies (all 256 blocks) ----
  for (long i = gtid; i < 524288; i += NT) { long n = i >> 7, kq = i & 127; cvtc(p.W_ih0 + n * 1536 + kq * 4, Wie + i * 4); }
  for (long i = gtid; i < 1048576; i += NT) { long n = i >> 8, kq = i & 255; cvtc(p.W_ih0 + n * 1536 + 512 + kq * 4, Wif + i * 4); }
  for (long i = gtid; i < 1048576; i += NT) cvtc(p.W_hh0 + i * 4, Whh0 + i * 4);
  for (long i = gtid; i < 1048576; i += NT) cvtc(p.W_ih1 + i * 4, Wih1 + i * 4);
  for (long i = gtid; i < 1048576; i += NT) cvtc(p.W_hh1 + i * 4, Whh1 + i * 4);
  for (long i = gtid; i < 524288;  i += NT) cvtc(p.attn_out + i * 4, Wao + i * 4);
  // TRANSPOSED copies: WaiT[j][k] = attn_in[k][j]; WcT[j][k] = copy_in[k][j]
  for (long i = gtid; i < 524288;  i += NT) {
    long j = i >> 9, k = (i & 511) * 2;
    u32 lo = f2bf(p.attn_in[k * 1024 + j]);
    u32 hi = f2bf(p.attn_in[(k + 1) * 1024 + j]);
    *(u32*)(Wai + j * 1024 + k) = lo | (hi << 16);
  }
  for (long i = gtid; i < 524288;  i += NT) {
    long j = i >> 9, k = (i & 511) * 2;
    u32 lo = f2bf(p.copy_in[k * 1024 + j]);
    u32 hi = f2bf(p.copy_in[(k + 1) * 1024 + j]);
    *(u32*)(Wc + j * 1024 + k) = lo | (hi << 16);
  }
  for (long i = gtid; i < 1048576; i += NT) {
    long b = i >> 14, s = (i >> 8) & 63, kq = i & 255;
    cvtc(p.context + ((s * 64 + b) * 1024 + kq * 4), Ctx + i * 4);
  }
  for (long i = gtid; i < 262144;  i += NT) {
    long row = i >> 7; long tok = p.input[row];
    cvtc(p.embedding + tok * 512 + (i & 127) * 4, Ebf + i * 4);
  }
  for (long i = gtid; i < 16384;   i += NT) cvtc(p.init_output + i * 4, Outs + i * 4);
  for (long i = gtid; i < 32768;   i += NT) { long l = i >> 14; cvtc(p.h0 + i * 4, Hbf + (l * 2 + 1) * 65536 + (i & 16383) * 4); }
  for (long i = gtid; i < 32768;   i += NT) ((float4*)Cws)[i] = ((const float4*)p.c0)[i];

  gsync(bar, 256);

  // ---- S1: precompute ctx@Wai and ctx@Wc (kills per-step q / qc GEMMs) ----
  ctxw_gemm(bid, Ctx, Wai, CtxW);
  ctxw_gemm(bid, Ctx, Wc, CtxWc);
  gsync(bar, 256);

  if (bid >= 64) return;     // extras only helped with setup
  const int b = bid;

  // pin ctxW[b] (64x1024 bf16 = 128 KiB) in LDS for the whole loop
  {
    const bfrag* src = (const bfrag*)(CtxW + (long)b * 65536);
    bfrag* dst = (bfrag*)ctxw_lds;
    for (int i = tid; i < 8192; i += 512) dst[i] = src[i];
  }
  __syncthreads();

  for (int t = 0; t < 32; ++t) {
    const int cur = t & 1, prev = cur ^ 1;
    // P1: layer0 LSTM (K = 512 emb + 1024 feed + 1024 h0)
    lstm_phase(bid,
               Ebf + (long)t * 32768, Wie, 512,
               Outs + (long)t * 65536, Wif, 1024,
               Hbf + (long)prev * 65536, Whh0, 1024,
               p.b0, Cws, Hbf + (long)cur * 65536, scratch);
    gsync(bar, 64);
    // P2: layer1 LSTM (K = 1024 h0n + 1024 h1_prev)
    lstm_phase(bid,
               Hbf + (long)cur * 65536, Wih1, 1024,
               Hbf + (long)(2 + prev) * 65536, Whh1, 1024,
               nullptr, nullptr, 0,
               p.b1, Cws + 65536, Hbf + (long)(2 + cur) * 65536, scratch);
    gsync(bar, 64);
    // P3: attention scores/softmax/weighted-context for batch b
    attn_phase(b, t, cur, Hbf, Ctx, Wctx, p.out, ctxw_lds, scratch);
    gsync(bar, 64);
    // P4: out = tanh([wctx|h1] @ Wao^T) -> d_out + next input-feed
    outproj_phase(bid, t, Wctx, Hbf + (long)(2 + cur) * 65536, Wao,
                  p.out, Outs + (long)(t + 1) * 65536, scratch);
    gsync(bar, 64);
  }

  // ---- epilogue: final states ----
  for (int k = tid; k < 1024; k += 512) {
    for (int l = 0; l < 2; ++l) {
      p.out[HT_OFF + (long)l * 65536 + b * 1024 + k] = bf2f(Hbf[(l * 2 + 1) * 65536 + b * 1024 + k]);
      p.out[CT_OFF + (long)l * 65536 + b * 1024 + k] = Cws[l * 65536 + b * 1024 + k];
    }
  }
  __syncthreads();
  // reload LDS with ctxWc[b], run deferred copy-attention for all t
  {
    const bfrag* src = (const bfrag*)(CtxWc + (long)b * 65536);
    bfrag* dst = (bfrag*)ctxw_lds;
    for (int i = tid; i < 8192; i += 512) dst[i] = src[i];
  }
  __syncthreads();
  copy_attn(b, Outs, ctxw_lds, p.out, scratch);
}

// ---------------- host ----------------
extern "C" void kernel_launch(void* const* d_in, const int* in_sizes, int n_in,
                              void* d_out, int out_size, void* d_ws, size_t ws_size,
                              hipStream_t stream) {
  KParams p;
  p.input       = (const int*)d_in[0];
  p.h0          = (const float*)d_in[1];
  p.c0          = (const float*)d_in[2];
  p.context     = (const float*)d_in[3];
  p.init_output = (const float*)d_in[4];
  p.embedding   = (const float*)d_in[5];
  p.W_ih0       = (const float*)d_in[6];
  p.W_hh0       = (const float*)d_in[7];
  p.b0          = (const float*)d_in[8];
  p.W_ih1       = (const float*)d_in[9];
  p.W_hh1       = (const float*)d_in[10];
  p.b1          = (const float*)d_in[11];
  p.attn_in     = (const float*)d_in[12];
  p.attn_out    = (const float*)d_in[13];
  p.copy_in     = (const float*)d_in[14];
  p.out         = (float*)d_out;
  p.ws          = (char*)d_ws;

  hipFuncSetAttribute((const void*)decoder_kernel,
                      hipFuncAttributeMaxDynamicSharedMemorySize, 147456);
  hipMemsetAsync((char*)d_ws + BAR_O, 0, 256, stream);
  void* args[] = { &p };
  hipLaunchCooperativeKernel((void*)decoder_kernel, dim3(256), dim3(512),
                             args, 147456, stream);
}

// Round 3
// 5358.185 us; speedup vs baseline: 1.1014x; 1.1014x over previous
//
#include <hip/hip_runtime.h>

typedef unsigned short u16;
typedef unsigned int   u32;
typedef __attribute__((ext_vector_type(8))) __bf16 bfrag;   // 8 bf16 = 4 VGPR
typedef __attribute__((ext_vector_type(4))) float  f32x4;

#define DEVI static __device__ __forceinline__

// ---------------- geometry ----------------
// T=32 B=64 S=64 E=512 H=1024 L=2 (4H=4096)
constexpr long OUT_OFF = 0;         // 32*64*1024
constexpr long HT_OFF  = 2097152;   // 2*64*1024
constexpr long CT_OFF  = 2228224;
constexpr long AS_OFF  = 2359296;   // 32*64*64
constexpr long AC_OFF  = 2490368;

// ---------------- workspace layout (bytes) ----------------
constexpr long WAO_O   = 0;                         // attn_out_w bf16 1024x2048 (4MB)
constexpr long WAI_O   = WAO_O  + 4194304;          // attn_in_w^T bf16 (2MB)
constexpr long WC_O    = WAI_O  + 2097152;          // copy_in_w^T bf16 (2MB)
constexpr long CTX_O   = WC_O   + 2097152;          // ctx (b,s,k) bf16 (8MB)
constexpr long CTXW_O  = CTX_O  + 8388608;          // ctx @ Wai bf16 (8MB)
constexpr long CTXWC_O = CTXW_O + 8388608;          // ctx @ Wc  bf16 (8MB)
constexpr long EBF_O   = CTXWC_O+ 8388608;          // emb gathered bf16 [32][64][512] (2MB)
constexpr long OF_O    = EBF_O  + 2097152;          // out-feed [2][64][1024] bf16 (256KB)
constexpr long HB0_O   = OF_O   + 262144;           // h layer0 [2][64][1024] bf16
constexpr long HB1_O   = HB0_O  + 262144;           // h layer1 [2][64][1024] bf16
constexpr long CST_O   = HB1_O  + 262144;           // c state f32 [2][1024 j][64 m] (512KB)
constexpr long WCTX_O  = CST_O  + 524288;           // weighted ctx bf16 [64][1024] (128KB)
constexpr long BAR_O   = WCTX_O + 131072;           // barrier

// LDS layout (dynamic, 155648 B)
constexpr int W0LDS_O = 0;        // [16 rows][2560] bf16 swizzled = 81920
constexpr int W1LDS_O = 81920;    // [16 rows][2048] bf16 swizzled = 65536
constexpr int SCR_O   = 147456;   // 8192 B f32 scratch

struct KParams {
  const int* input; const float* h0; const float* c0; const float* context;
  const float* init_output; const float* embedding;
  const float* W_ih0; const float* W_hh0; const float* b0;
  const float* W_ih1; const float* W_hh1; const float* b1;
  const float* attn_in; const float* attn_out; const float* copy_in;
  float* out; char* ws;
};

// ---------------- small helpers ----------------
DEVI float bf2f(u16 u) { u32 x = ((u32)u) << 16; return __builtin_bit_cast(float, x); }
DEVI u16 f2bf(float f) {
  u32 x = __builtin_bit_cast(u32, f);
  u32 r = x + 0x7fffu + ((x >> 16) & 1u);   // RNE
  return (u16)(r >> 16);
}
DEVI void cvtc(const float* s, u16* d) {    // 4 contiguous f32 -> 4 bf16
  float4 v = *(const float4*)s;
  uint2 u;
  u.x = (u32)f2bf(v.x) | ((u32)f2bf(v.y) << 16);
  u.y = (u32)f2bf(v.z) | ((u32)f2bf(v.w) << 16);
  *(uint2*)d = u;
}
DEVI float sigm(float x)  { return 1.f / (1.f + __expf(-x)); }
DEVI float tanh_(float x) { return 1.f - 2.f / (__expf(2.f * x) + 1.f); }

DEVI f32x4 mfma16(bfrag a, bfrag b, f32x4 c) {
  return __builtin_amdgcn_mfma_f32_16x16x32_bf16(a, b, c, 0, 0, 0);
}
DEVI bfrag ldf(const u16* p) { return *(const bfrag*)p; }

// grid barrier: bar[0]=count, bar[1]=generation (agent scope)
DEVI void gsync(u32* bar, u32 nblk) {
  __syncthreads();
  if (threadIdx.x == 0) {
    __builtin_amdgcn_fence(__ATOMIC_RELEASE, "agent");
    u32 gen  = __hip_atomic_load(bar + 1, __ATOMIC_RELAXED, __HIP_MEMORY_SCOPE_AGENT);
    u32 prev = __hip_atomic_fetch_add(bar, 1u, __ATOMIC_ACQ_REL, __HIP_MEMORY_SCOPE_AGENT);
    if (prev == nblk - 1) {
      __hip_atomic_store(bar, 0u, __ATOMIC_RELAXED, __HIP_MEMORY_SCOPE_AGENT);
      __hip_atomic_fetch_add(bar + 1, 1u, __ATOMIC_RELEASE, __HIP_MEMORY_SCOPE_AGENT);
    } else {
      while (__hip_atomic_load(bar + 1, __ATOMIC_RELAXED, __HIP_MEMORY_SCOPE_AGENT) == gen)
        __builtin_amdgcn_s_sleep(1);
    }
    __builtin_amdgcn_fence(__ATOMIC_ACQUIRE, "agent");
  }
  __syncthreads();
}

// one K-segment of the gate GEMM: A from global ([m][aRowK] bf16, k-contig),
// B from swizzled LDS weight slice ([16 rows][wRowK] bf16).
DEVI void gemmseg(f32x4& acc, const u16* A, int arow, int aRowK, int segBase,
                  const char* W, int wRowK, int brow, int ke, int kk0, int kk1) {
  const u16* ap = A + (long)arow * aRowK + ke - segBase;
  const u32 sw = (u32)((brow & 7) << 4);
#pragma unroll 8
  for (int kk = kk0; kk < kk1; ++kk) {
    bfrag av = ldf(ap + kk * 32);
    u32 off = ((u32)(brow * wRowK + kk * 32 + ke) * 2) ^ sw;
    bfrag bv = *(const bfrag*)(W + off);
    acc = mfma16(av, bv, acc);
  }
}

// write wave's 16x16 f32 tile into scratch slot
DEVI void scr_store(float* scr, int slot, f32x4 acc) {
  const int lane = threadIdx.x & 63;
#pragma unroll
  for (int r = 0; r < 4; ++r)
    scr[slot * 256 + ((lane >> 4) * 4 + r) * 16 + (lane & 15)] = acc[r];
}

// LSTM pointwise for this block's 4 hidden units (threads 0..255)
DEVI void pointwise(int bid, const float* scr, const float* bias, float* cst, u16* hout) {
  const int p = threadIdx.x;
  const int m = p >> 2, u = p & 3, j = bid * 4 + u;
  float g4[4];
#pragma unroll
  for (int g = 0; g < 4; ++g) {
    int n = g * 4 + u, mt = m >> 4, ml = m & 15;
    g4[g] = scr[(mt * 2) * 256 + ml * 16 + n] + scr[(mt * 2 + 1) * 256 + ml * 16 + n]
          + bias[g * 1024 + j];
  }
  float c = cst[j * 64 + m];
  float cn = sigm(g4[1]) * c + sigm(g4[0]) * tanh_(g4[2]);
  cst[j * 64 + m] = cn;
  hout[m * 1024 + j] = f2bf(sigm(g4[3]) * tanh_(cn));
}

// setup GEMM: dst[(b,s),j] = ctx[(b,s),:] . Wrow[j,:]  (256 blocks, one m-tile each)
DEVI void ctxw_gemm(int mt, const u16* Ctx, const u16* Wm, u16* dst) {
  const int tid = threadIdx.x, lane = tid & 63, w = tid >> 6;
  const int arow = mt * 16 + (lane & 15);
  const int ke = (lane >> 4) * 8;
#pragma unroll
  for (int i = 0; i < 8; ++i) {
    int nt = w * 8 + i;
    const u16* A = Ctx + (long)arow * 1024 + ke;
    const u16* B = Wm + (long)(nt * 16 + (lane & 15)) * 1024 + ke;
    f32x4 acc = {0.f, 0.f, 0.f, 0.f};
    for (int kk = 0; kk < 1024; kk += 32)
      acc = mfma16(ldf(A + kk), ldf(B + kk), acc);
#pragma unroll
    for (int r = 0; r < 4; ++r)
      dst[(long)(mt * 16 + (lane >> 4) * 4 + r) * 1024 + nt * 16 + (lane & 15)] = f2bf(acc[r]);
  }
}

// ---------------- the kernel ----------------
__global__ __launch_bounds__(512, 1) void decoder_kernel(KParams p) {
  extern __shared__ char smem[];
  char*  W0 = smem + W0LDS_O;
  char*  W1 = smem + W1LDS_O;
  float* scr = (float*)(smem + SCR_O);

  char* ws = p.ws;
  u16* Wao   = (u16*)(ws + WAO_O);
  u16* Wai   = (u16*)(ws + WAI_O);
  u16* Wc    = (u16*)(ws + WC_O);
  u16* Ctx   = (u16*)(ws + CTX_O);
  u16* CtxW  = (u16*)(ws + CTXW_O);
  u16* CtxWc = (u16*)(ws + CTXWC_O);
  u16* Ebf   = (u16*)(ws + EBF_O);
  u16* OF    = (u16*)(ws + OF_O);
  u16* Hb0   = (u16*)(ws + HB0_O);
  u16* Hb1   = (u16*)(ws + HB1_O);
  float* Cst = (float*)(ws + CST_O);
  u16* Wctx  = (u16*)(ws + WCTX_O);
  u32* bar   = (u32*)(ws + BAR_O);

  const int bid = blockIdx.x, tid = threadIdx.x;
  const int lane = tid & 63, w = tid >> 6;
  const long gtid = (long)bid * 512 + tid, NT = 256l * 512;

  // ---- S0a: per-block weight slices -> LDS (once, stationary for all 32 steps) ----
  // rows: idx = g*4+u -> global row R = g*1024 + bid*4 + u
  for (int i = tid; i < 5120; i += 512) {           // W0: 16 rows x 2560/8 chunks
    int row = i / 320, k = (i % 320) * 8;
    int R = (row >> 2) * 1024 + bid * 4 + (row & 3);
    const float* src = (k < 1536) ? (p.W_ih0 + (long)R * 1536 + k)
                                  : (p.W_hh0 + (long)R * 1024 + (k - 1536));
    float4 a = *(const float4*)src, b = *(const float4*)(src + 4);
    uint4 q;
    q.x = (u32)f2bf(a.x) | ((u32)f2bf(a.y) << 16);
    q.y = (u32)f2bf(a.z) | ((u32)f2bf(a.w) << 16);
    q.z = (u32)f2bf(b.x) | ((u32)f2bf(b.y) << 16);
    q.w = (u32)f2bf(b.z) | ((u32)f2bf(b.w) << 16);
    u32 off = ((u32)(row * 2560 + k) * 2) ^ ((u32)((row & 7) << 4));
    *(uint4*)(W0 + off) = q;
  }
  for (int i = tid; i < 4096; i += 512) {           // W1: 16 rows x 2048/8 chunks
    int row = i / 256, k = (i % 256) * 8;
    int R = (row >> 2) * 1024 + bid * 4 + (row & 3);
    const float* src = (k < 1024) ? (p.W_ih1 + (long)R * 1024 + k)
                                  : (p.W_hh1 + (long)R * 1024 + (k - 1024));
    float4 a = *(const float4*)src, b = *(const float4*)(src + 4);
    uint4 q;
    q.x = (u32)f2bf(a.x) | ((u32)f2bf(a.y) << 16);
    q.y = (u32)f2bf(a.z) | ((u32)f2bf(a.w) << 16);
    q.z = (u32)f2bf(b.x) | ((u32)f2bf(b.y) << 16);
    q.w = (u32)f2bf(b.z) | ((u32)f2bf(b.w) << 16);
    u32 off = ((u32)(row * 2048 + k) * 2) ^ ((u32)((row & 7) << 4));
    *(uint4*)(W1 + off) = q;
  }

  // ---- S0b: global conversions (grid-stride over all 256 blocks) ----
  for (long i = gtid; i < 524288; i += NT) cvtc(p.attn_out + i * 4, Wao + i * 4);
  for (long i = gtid; i < 524288; i += NT) {   // WaiT[j][k] = attn_in[k][j]
    long j = i >> 9, k = (i & 511) * 2;
    u32 lo = f2bf(p.attn_in[k * 1024 + j]);
    u32 hi = f2bf(p.attn_in[(k + 1) * 1024 + j]);
    *(u32*)(Wai + j * 1024 + k) = lo | (hi << 16);
  }
  for (long i = gtid; i < 524288; i += NT) {
    long j = i >> 9, k = (i & 511) * 2;
    u32 lo = f2bf(p.copy_in[k * 1024 + j]);
    u32 hi = f2bf(p.copy_in[(k + 1) * 1024 + j]);
    *(u32*)(Wc + j * 1024 + k) = lo | (hi << 16);
  }
  for (long i = gtid; i < 1048576; i += NT) {
    long b = i >> 14, s = (i >> 8) & 63, kq = i & 255;
    cvtc(p.context + ((s * 64 + b) * 1024 + kq * 4), Ctx + i * 4);
  }
  for (long i = gtid; i < 262144; i += NT) {
    long row = i >> 7; long tok = p.input[row];
    cvtc(p.embedding + tok * 512 + (i & 127) * 4, Ebf + i * 4);
  }
  for (long i = gtid; i < 16384; i += NT) cvtc(p.init_output + i * 4, OF + i * 4);   // slot 0
  for (long i = gtid; i < 32768; i += NT) {
    long l = i >> 14, rem = i & 16383;
    cvtc(p.h0 + i * 4, (l ? Hb1 : Hb0) + 65536 + rem * 4);   // slot 1 (= prev at t=0)
  }
  for (long i = gtid; i < 131072; i += NT) {   // Cst[l][j][m] = c0[l][m][j]
    long l = i >> 16, rem = i & 65535, j = rem >> 6, m = rem & 63;
    Cst[i] = p.c0[l * 65536 + m * 1024 + j];
  }

  gsync(bar, 256);

  // ---- S1: attention tables ----
  ctxw_gemm(bid, Ctx, Wai, CtxW);
  ctxw_gemm(bid, Ctx, Wc, CtxWc);
  gsync(bar, 256);

  // ---- main loop: 4 phases/step, all 256 blocks ----
  const int mt_ = w & 3, kh_ = w >> 2;
  const int arow_ = mt_ * 16 + (lane & 15);
  const int brow_ = lane & 15;
  const int ke_ = (lane >> 4) * 8;

  for (int t = 0; t < 32; ++t) {
    const int cur = t & 1, prev = cur ^ 1;
    const u16* EbfT = Ebf + (long)t * 32768;
    const u16* OFc  = OF  + (long)cur * 65536;
    u16* Hb0c = Hb0 + (long)cur * 65536;
    const u16* Hb0p = Hb0 + (long)prev * 65536;
    u16* Hb1c = Hb1 + (long)cur * 65536;
    const u16* Hb1p = Hb1 + (long)prev * 65536;

    // P1: layer0 gates (K = 512 emb | 1024 feed | 1024 h0prev), 2-way K-split
    {
      f32x4 acc = {0.f, 0.f, 0.f, 0.f};
      if (kh_ == 0) {
        gemmseg(acc, EbfT, arow_, 512, 0,    W0, 2560, brow_, ke_, 0, 16);
        gemmseg(acc, OFc,  arow_, 1024, 512, W0, 2560, brow_, ke_, 16, 40);
      } else {
        gemmseg(acc, OFc,  arow_, 1024, 512,  W0, 2560, brow_, ke_, 40, 48);
        gemmseg(acc, Hb0p, arow_, 1024, 1536, W0, 2560, brow_, ke_, 48, 80);
      }
      scr_store(scr, mt_ * 2 + kh_, acc);
      __syncthreads();
      if (tid < 256) pointwise(bid, scr, p.b0, Cst, Hb0c);
    }
    gsync(bar, 256);

    // P2: layer1 gates (K = 1024 h0n | 1024 h1prev)
    {
      f32x4 acc = {0.f, 0.f, 0.f, 0.f};
      if (kh_ == 0)
        gemmseg(acc, Hb0c, arow_, 1024, 0,    W1, 2048, brow_, ke_, 0, 32);
      else
        gemmseg(acc, Hb1p, arow_, 1024, 1024, W1, 2048, brow_, ke_, 32, 64);
      scr_store(scr, mt_ * 2 + kh_, acc);
      __syncthreads();
      if (tid < 256) pointwise(bid, scr, p.b1, Cst + 65536, Hb1c);
    }
    gsync(bar, 256);

    // P3: attention for batch b = bid (first 64 blocks)
    if (bid < 64) {
      const int b = bid;
      float* lds_s = scr;
      float* lds_a = scr + 64;
      float h1v[16];
      {
        const u32* u = (const u32*)(Hb1c + (long)b * 1024 + lane * 16);
#pragma unroll
        for (int i = 0; i < 8; ++i) {
          u32 x = u[i];
          h1v[2 * i]     = bf2f((u16)(x & 0xffff));
          h1v[2 * i + 1] = bf2f((u16)(x >> 16));
        }
      }
#pragma unroll
      for (int si = 0; si < 8; ++si) {
        int s = w * 8 + si;
        const u32* u = (const u32*)(CtxW + ((long)(b * 64 + s)) * 1024 + lane * 16);
        float acc = 0.f;
#pragma unroll
        for (int i = 0; i < 8; ++i) {
          u32 x = u[i];
          acc += h1v[2 * i]     * bf2f((u16)(x & 0xffff));
          acc += h1v[2 * i + 1] * bf2f((u16)(x >> 16));
        }
#pragma unroll
        for (int off = 32; off; off >>= 1) acc += __shfl_down(acc, off, 64);
        if (lane == 0) lds_s[s] = acc;
      }
      __syncthreads();
      if (w == 0) {
        float v = lds_s[lane];
        float mx = v;
#pragma unroll
        for (int off = 32; off; off >>= 1) mx = fmaxf(mx, __shfl_xor(mx, off, 64));
        float e = __expf(v - mx);
        float sm = e;
#pragma unroll
        for (int off = 32; off; off >>= 1) sm += __shfl_xor(sm, off, 64);
        float a = e / sm;
        lds_a[lane] = a;
        p.out[AS_OFF + (long)t * 4096 + b * 64 + lane] = a;
      }
      __syncthreads();
      int k0 = w * 128 + lane * 2;
      const u16* cb = Ctx + (long)b * 65536 + k0;
      float a0 = 0.f, a1 = 0.f;
      for (int s = 0; s < 64; ++s) {
        float as = lds_a[s];
        u32 x = *(const u32*)(cb + (long)s * 1024);
        a0 += as * bf2f((u16)(x & 0xffff));
        a1 += as * bf2f((u16)(x >> 16));
      }
      *(u32*)(Wctx + b * 1024 + k0) = (u32)f2bf(a0) | ((u32)f2bf(a1) << 16);
    }
    gsync(bar, 256);

    // P4: out = tanh([wctx|h1] @ Wao^T); 256 blocks, one 16x16 tile each, 8-way K-split
    {
      const int mt = bid & 3, nt = bid >> 2;
      const int arow = mt * 16 + (lane & 15);
      const int brow = nt * 16 + (lane & 15);
      const u16* A = (w < 4 ? Wctx : Hb1c) + (long)arow * 1024 + ke_ - (w < 4 ? 0 : 1024) + 0;
      const u16* Bp = Wao + (long)brow * 2048 + ke_;
      f32x4 acc = {0.f, 0.f, 0.f, 0.f};
      const int segBase = (w < 4) ? 0 : 1024;
#pragma unroll 8
      for (int kk = w * 8; kk < w * 8 + 8; ++kk) {
        bfrag av = ldf(A + kk * 32 - 0);     // A already shifted by segBase via ptr? no:
        (void)segBase;
        av = ldf(((w < 4 ? Wctx : Hb1c) + (long)arow * 1024 + ke_ - segBase) + kk * 32);
        acc = mfma16(av, ldf(Bp + kk * 32), acc);
      }
      scr_store(scr, w, acc);
      __syncthreads();
      if (tid < 256) {
        int m = tid >> 4, n = tid & 15;
        float v = 0.f;
#pragma unroll
        for (int q = 0; q < 8; ++q) v += scr[q * 256 + m * 16 + n];
        v = tanh_(v);
        int mg = mt * 16 + m, jg = nt * 16 + n;
        p.out[(long)t * 65536 + mg * 1024 + jg] = v;
        OF[(long)(cur ^ 1) * 65536 + mg * 1024 + jg] = f2bf(v);   // feed for t+1
      }
    }
    gsync(bar, 256);
  }

  // ---- epilogue: final states (each block its 4 hidden units) ----
  if (tid < 256) {
    int m = tid >> 2, u = tid & 3, j = bid * 4 + u;
    p.out[HT_OFF + (long)m * 1024 + j]          = bf2f(Hb0[65536 + m * 1024 + j]);   // t=31 -> slot 1
    p.out[HT_OFF + 65536 + (long)m * 1024 + j]  = bf2f(Hb1[65536 + m * 1024 + j]);
    p.out[CT_OFF + (long)m * 1024 + j]          = Cst[j * 64 + m];
    p.out[CT_OFF + 65536 + (long)m * 1024 + j]  = Cst[65536 + j * 64 + m];
  }

  // ---- deferred copy-attention (64 blocks; reuse weight LDS as ctxWc[b] buffer) ----
  if (bid < 64) {
    const int b = bid;
    u16* cw = (u16*)smem;   // 128KB region (W0+W1 no longer needed)
    {
      const bfrag* src = (const bfrag*)(CtxWc + (long)b * 65536);
      bfrag* dst = (bfrag*)cw;
      for (int i = tid; i < 8192; i += 512) dst[i] = src[i];
    }
    __syncthreads();
    float* lds_s = scr;
    for (int t = 0; t < 32; ++t) {
      float ov[16];
      {
        const float4* op = (const float4*)(p.out + (long)t * 65536 + b * 1024 + lane * 16);
#pragma unroll
        for (int i = 0; i < 4; ++i) {
          float4 v = op[i];
          ov[4 * i] = v.x; ov[4 * i + 1] = v.y; ov[4 * i + 2] = v.z; ov[4 * i + 3] = v.w;
        }
      }
#pragma unroll
      for (int si = 0; si < 8; ++si) {
        int s = w * 8 + si;
        const u32* u = (const u32*)(cw + s * 1024 + lane * 16);
        float acc = 0.f;
#pragma unroll
        for (int i = 0; i < 8; ++i) {
          u32 x = u[i];
          acc += ov[2 * i]     * bf2f((u16)(x & 0xffff));
          acc += ov[2 * i + 1] * bf2f((u16)(x >> 16));
        }
#pragma unroll
        for (int off = 32; off; off >>= 1) acc += __shfl_down(acc, off, 64);
        if (lane == 0) lds_s[s] = acc;
      }
      __syncthreads();
      if (w == 0) {
        float v = lds_s[lane];
        float mx = v;
#pragma unroll
        for (int off = 32; off; off >>= 1) mx = fmaxf(mx, __shfl_xor(mx, off, 64));
        float e = __expf(v - mx);
        float sm = e;
#pragma unroll
        for (int off = 32; off; off >>= 1) sm += __shfl_xor(sm, off, 64);
        p.out[AC_OFF + (long)t * 4096 + b * 64 + lane] = e / sm;
      }
      __syncthreads();
    }
  }
}

// ---------------- host ----------------
extern "C" void kernel_launch(void* const* d_in, const int* in_sizes, int n_in,
                              void* d_out, int out_size, void* d_ws, size_t ws_size,
                              hipStream_t stream) {
  KParams p;
  p.input       = (const int*)d_in[0];
  p.h0          = (const float*)d_in[1];
  p.c0          = (const float*)d_in[2];
  p.context     = (const float*)d_in[3];
  p.init_output = (const float*)d_in[4];
  p.embedding   = (const float*)d_in[5];
  p.W_ih0       = (const float*)d_in[6];
  p.W_hh0       = (const float*)d_in[7];
  p.b0          = (const float*)d_in[8];
  p.W_ih1       = (const float*)d_in[9];
  p.W_hh1       = (const float*)d_in[10];
  p.b1          = (const float*)d_in[11];
  p.attn_in     = (const float*)d_in[12];
  p.attn_out    = (const float*)d_in[13];
  p.copy_in     = (const float*)d_in[14];
  p.out         = (float*)d_out;
  p.ws          = (char*)d_ws;

  hipFuncSetAttribute((const void*)decoder_kernel,
                      hipFuncAttributeMaxDynamicSharedMemorySize, 155648);
  hipMemsetAsync((char*)d_ws + BAR_O, 0, 256, stream);
  void* args[] = { &p };
  hipLaunchCooperativeKernel((void*)decoder_kernel, dim3(256), dim3(512),
                             args, 155648, stream);
}

// Round 4
// 3958.158 us; speedup vs baseline: 1.4910x; 1.3537x over previous
//
#include <hip/hip_runtime.h>

typedef unsigned short u16;
typedef unsigned int   u32;
typedef __attribute__((ext_vector_type(8))) __bf16 bfrag;   // 8 bf16 = 4 VGPR
typedef __attribute__((ext_vector_type(4))) float  f32x4;

#define DEVI static __device__ __forceinline__

// ---------------- geometry ----------------
// T=32 B=64 S=64 E=512 H=1024 L=2 (4H=4096)
constexpr long OUT_OFF = 0;         // 32*64*1024
constexpr long HT_OFF  = 2097152;   // 2*64*1024
constexpr long CT_OFF  = 2228224;
constexpr long AS_OFF  = 2359296;   // 32*64*64
constexpr long AC_OFF  = 2490368;

// ---------------- workspace layout (bytes) ----------------
constexpr long WAO_O   = 0;                         // attn_out_w bf16 1024x2048 (4MB)
constexpr long WAI_O   = WAO_O  + 4194304;          // attn_in_w^T bf16 (2MB)
constexpr long WC_O    = WAI_O  + 2097152;          // copy_in_w^T bf16 (2MB)
constexpr long CTX_O   = WC_O   + 2097152;          // ctx (b,s,k) bf16 (8MB)
constexpr long CTXW_O  = CTX_O  + 8388608;          // ctx @ Wai bf16 (8MB)
constexpr long CTXWC_O = CTXW_O + 8388608;          // ctx @ Wc  bf16 (8MB)
constexpr long EBF_O   = CTXWC_O+ 8388608;          // emb gathered bf16 [32][64][512] (2MB)
constexpr long OF_O    = EBF_O  + 2097152;          // out-feed [2][64][1024] bf16 (256KB)
constexpr long HB0_O   = OF_O   + 262144;           // h layer0 [2][64][1024] bf16
constexpr long HB1_O   = HB0_O  + 262144;           // h layer1 [2][64][1024] bf16
constexpr long CST_O   = HB1_O  + 262144;           // c state f32 [2][1024 j][64 m] (512KB)
constexpr long WCTX_O  = CST_O  + 524288;           // weighted ctx bf16 [64][1024] (128KB)
constexpr long BAR_O   = WCTX_O + 131072;           // flags[256] + gen

// LDS layout (dynamic, 156160 B)
constexpr int W0LDS_O = 0;        // [16 rows][2560] bf16 swizzled = 81920
constexpr int W1LDS_O = 81920;    // [16 rows][2048] bf16 swizzled = 65536
constexpr int SCR_O   = 147456;   // 8 slots x 272 f32 = 8704 B

struct KParams {
  const int* input; const float* h0; const float* c0; const float* context;
  const float* init_output; const float* embedding;
  const float* W_ih0; const float* W_hh0; const float* b0;
  const float* W_ih1; const float* W_hh1; const float* b1;
  const float* attn_in; const float* attn_out; const float* copy_in;
  float* out; char* ws;
};

// ---------------- small helpers ----------------
DEVI float bf2f(u16 u) { u32 x = ((u32)u) << 16; return __builtin_bit_cast(float, x); }
DEVI u16 f2bf(float f) {
  u32 x = __builtin_bit_cast(u32, f);
  u32 r = x + 0x7fffu + ((x >> 16) & 1u);   // RNE
  return (u16)(r >> 16);
}
DEVI void cvtc(const float* s, u16* d) {    // 4 contiguous f32 -> 4 bf16
  float4 v = *(const float4*)s;
  uint2 u;
  u.x = (u32)f2bf(v.x) | ((u32)f2bf(v.y) << 16);
  u.y = (u32)f2bf(v.z) | ((u32)f2bf(v.w) << 16);
  *(uint2*)d = u;
}
DEVI float sigm(float x)  { return 1.f / (1.f + __expf(-x)); }
DEVI float tanh_(float x) { return 1.f - 2.f / (__expf(2.f * x) + 1.f); }

DEVI f32x4 mfma16(bfrag a, bfrag b, f32x4 c) {
  return __builtin_amdgcn_mfma_f32_16x16x32_bf16(a, b, c, 0, 0, 0);
}
DEVI bfrag ldf(const u16* p) { return *(const bfrag*)p; }

// ---------------- flag-array grid barrier ----------------
// flags[256] (1KB) at bar; gen word at bar[320] (its own cacheline).
DEVI void gsyncF(u32* bar, u32 gen) {
  const int tid = threadIdx.x, bid = blockIdx.x;
  u32* genp = bar + 320;
  __syncthreads();
  if (tid == 0) {
    __builtin_amdgcn_fence(__ATOMIC_RELEASE, "agent");
    __hip_atomic_store(&bar[bid], gen, __ATOMIC_RELAXED, __HIP_MEMORY_SCOPE_AGENT);
  }
  if (bid == 0 && tid < 64) {
    for (;;) {
      u32 a = __hip_atomic_load(&bar[tid],       __ATOMIC_RELAXED, __HIP_MEMORY_SCOPE_AGENT);
      u32 b = __hip_atomic_load(&bar[64 + tid],  __ATOMIC_RELAXED, __HIP_MEMORY_SCOPE_AGENT);
      u32 c = __hip_atomic_load(&bar[128 + tid], __ATOMIC_RELAXED, __HIP_MEMORY_SCOPE_AGENT);
      u32 d = __hip_atomic_load(&bar[192 + tid], __ATOMIC_RELAXED, __HIP_MEMORY_SCOPE_AGENT);
      if (__all(a >= gen && b >= gen && c >= gen && d >= gen)) break;
      __builtin_amdgcn_s_sleep(1);
    }
    if (tid == 0)
      __hip_atomic_store(genp, gen, __ATOMIC_RELAXED, __HIP_MEMORY_SCOPE_AGENT);
  }
  if (tid == 0) {
    while (__hip_atomic_load(genp, __ATOMIC_RELAXED, __HIP_MEMORY_SCOPE_AGENT) < gen)
      __builtin_amdgcn_s_sleep(2);
    __builtin_amdgcn_fence(__ATOMIC_ACQUIRE, "agent");
  }
  __syncthreads();
}

// one K-segment of the gate GEMM: A from global ([m][aRowK] bf16, k-contig),
// B from swizzled LDS weight slice ([16 rows][wRowK] bf16).
DEVI void gemmseg(f32x4& acc, const u16* A, int arow, int aRowK, int segBase,
                  const char* W, int wRowK, int brow, int ke, int kk0, int kk1) {
  const u16* ap = A + (long)arow * aRowK + ke - segBase;
  const u32 sw = (u32)((brow & 7) << 4);
#pragma unroll 8
  for (int kk = kk0; kk < kk1; ++kk) {
    bfrag av = ldf(ap + kk * 32);
    u32 off = ((u32)(brow * wRowK + kk * 32 + ke) * 2) ^ sw;
    bfrag bv = *(const bfrag*)(W + off);
    acc = mfma16(av, bv, acc);
  }
}

// write wave's 16x16 f32 tile into padded scratch slot (stride 17)
DEVI void scr_store(float* scr, int slot, f32x4 acc) {
  const int lane = threadIdx.x & 63;
#pragma unroll
  for (int r = 0; r < 4; ++r)
    scr[slot * 272 + ((lane >> 4) * 4 + r) * 17 + (lane & 15)] = acc[r];
}

// LSTM pointwise for this block's 4 hidden units (threads 0..255, coalesced Cst)
DEVI void pointwise(int bid, const float* scr, const float* bias, float* cst, u16* hout) {
  const int p = threadIdx.x;
  const int u = p >> 6, m = p & 63, j = bid * 4 + u;
  const int mt = m >> 4, ml = m & 15;
  float g4[4];
#pragma unroll
  for (int g = 0; g < 4; ++g) {
    int n = g * 4 + u;
    g4[g] = scr[(mt * 2) * 272 + ml * 17 + n] + scr[(mt * 2 + 1) * 272 + ml * 17 + n]
          + bias[g * 1024 + j];
  }
  float c = cst[j * 64 + m];
  float cn = sigm(g4[1]) * c + sigm(g4[0]) * tanh_(g4[2]);
  cst[j * 64 + m] = cn;
  hout[m * 1024 + j] = f2bf(sigm(g4[3]) * tanh_(cn));
}

// setup GEMM: dst[(b,s),j] = ctx[(b,s),:] . Wrow[j,:]  (256 blocks, one m-tile each)
DEVI void ctxw_gemm(int mt, const u16* Ctx, const u16* Wm, u16* dst) {
  const int tid = threadIdx.x, lane = tid & 63, w = tid >> 6;
  const int arow = mt * 16 + (lane & 15);
  const int ke = (lane >> 4) * 8;
#pragma unroll
  for (int i = 0; i < 8; ++i) {
    int nt = w * 8 + i;
    const u16* A = Ctx + (long)arow * 1024 + ke;
    const u16* B = Wm + (long)(nt * 16 + (lane & 15)) * 1024 + ke;
    f32x4 acc = {0.f, 0.f, 0.f, 0.f};
    for (int kk = 0; kk < 1024; kk += 32)
      acc = mfma16(ldf(A + kk), ldf(B + kk), acc);
#pragma unroll
    for (int r = 0; r < 4; ++r)
      dst[(long)(mt * 16 + (lane >> 4) * 4 + r) * 1024 + nt * 16 + (lane & 15)] = f2bf(acc[r]);
  }
}

// ---------------- the kernel ----------------
__global__ __launch_bounds__(512, 1) void decoder_kernel(KParams p) {
  extern __shared__ char smem[];
  char*  W0 = smem + W0LDS_O;
  char*  W1 = smem + W1LDS_O;
  float* scr = (float*)(smem + SCR_O);

  char* ws = p.ws;
  u16* Wao   = (u16*)(ws + WAO_O);
  u16* Wai   = (u16*)(ws + WAI_O);
  u16* Wc    = (u16*)(ws + WC_O);
  u16* Ctx   = (u16*)(ws + CTX_O);
  u16* CtxW  = (u16*)(ws + CTXW_O);
  u16* CtxWc = (u16*)(ws + CTXWC_O);
  u16* Ebf   = (u16*)(ws + EBF_O);
  u16* OF    = (u16*)(ws + OF_O);
  u16* Hb0   = (u16*)(ws + HB0_O);
  u16* Hb1   = (u16*)(ws + HB1_O);
  float* Cst = (float*)(ws + CST_O);
  u16* Wctx  = (u16*)(ws + WCTX_O);
  u32* bar   = (u32*)(ws + BAR_O);

  const int bid = blockIdx.x, tid = threadIdx.x;
  const int lane = tid & 63, w = tid >> 6;
  const long gtid = (long)bid * 512 + tid, NT = 256l * 512;
  u32 gen = 1;

  // ---- S0-pre: LDS-tiled transposes of attn_in / copy_in (coalesced both sides) ----
  {
    float* tile = (float*)smem;   // 64 x 69 f32 = 17664 B (in W0 region, free now)
    for (int pass = 0; pass < 2; ++pass) {
      const float* src = pass ? p.copy_in : p.attn_in;
      u16* dst = pass ? Wc : Wai;
      int tr = bid >> 4, tc = bid & 15;
      {
        int r = tid >> 3, c = (tid & 7) * 8;
        const float4* s4 = (const float4*)(src + (long)(tr * 64 + r) * 1024 + tc * 64 + c);
        float4 a = s4[0], b = s4[1];
        float* tp = tile + r * 69 + c;
        tp[0] = a.x; tp[1] = a.y; tp[2] = a.z; tp[3] = a.w;
        tp[4] = b.x; tp[5] = b.y; tp[6] = b.z; tp[7] = b.w;
      }
      __syncthreads();
      {
        int r2 = tid >> 3, c2 = (tid & 7) * 8;
        u32 q[4];
#pragma unroll
        for (int i = 0; i < 4; ++i) {
          float lo = tile[(c2 + 2 * i) * 69 + r2];
          float hi = tile[(c2 + 2 * i + 1) * 69 + r2];
          q[i] = (u32)f2bf(lo) | ((u32)f2bf(hi) << 16);
        }
        *(uint4*)(dst + (long)(tc * 64 + r2) * 1024 + tr * 64 + c2) = *(uint4*)q;
      }
      __syncthreads();
    }
  }

  // ---- S0a: per-block weight slices -> LDS (once, stationary for all 32 steps) ----
  for (int i = tid; i < 5120; i += 512) {           // W0: 16 rows x 2560/8 chunks
    int row = i / 320, k = (i % 320) * 8;
    int R = (row >> 2) * 1024 + bid * 4 + (row & 3);
    const float* src = (k < 1536) ? (p.W_ih0 + (long)R * 1536 + k)
                                  : (p.W_hh0 + (long)R * 1024 + (k - 1536));
    float4 a = *(const float4*)src, b = *(const float4*)(src + 4);
    uint4 q;
    q.x = (u32)f2bf(a.x) | ((u32)f2bf(a.y) << 16);
    q.y = (u32)f2bf(a.z) | ((u32)f2bf(a.w) << 16);
    q.z = (u32)f2bf(b.x) | ((u32)f2bf(b.y) << 16);
    q.w = (u32)f2bf(b.z) | ((u32)f2bf(b.w) << 16);
    u32 off = ((u32)(row * 2560 + k) * 2) ^ ((u32)((row & 7) << 4));
    *(uint4*)(W0 + off) = q;
  }
  for (int i = tid; i < 4096; i += 512) {           // W1: 16 rows x 2048/8 chunks
    int row = i / 256, k = (i % 256) * 8;
    int R = (row >> 2) * 1024 + bid * 4 + (row & 3);
    const float* src = (k < 1024) ? (p.W_ih1 + (long)R * 1024 + k)
                                  : (p.W_hh1 + (long)R * 1024 + (k - 1024));
    float4 a = *(const float4*)src, b = *(const float4*)(src + 4);
    uint4 q;
    q.x = (u32)f2bf(a.x) | ((u32)f2bf(a.y) << 16);
    q.y = (u32)f2bf(a.z) | ((u32)f2bf(a.w) << 16);
    q.z = (u32)f2bf(b.x) | ((u32)f2bf(b.y) << 16);
    q.w = (u32)f2bf(b.z) | ((u32)f2bf(b.w) << 16);
    u32 off = ((u32)(row * 2048 + k) * 2) ^ ((u32)((row & 7) << 4));
    *(uint4*)(W1 + off) = q;
  }

  // ---- S0b: global conversions ----
  for (long i = gtid; i < 524288; i += NT) cvtc(p.attn_out + i * 4, Wao + i * 4);
  for (long i = gtid; i < 1048576; i += NT) {
    long b = i >> 14, s = (i >> 8) & 63, kq = i & 255;
    cvtc(p.context + ((s * 64 + b) * 1024 + kq * 4), Ctx + i * 4);
  }
  for (long i = gtid; i < 262144; i += NT) {
    long row = i >> 7; long tok = p.input[row];
    cvtc(p.embedding + tok * 512 + (i & 127) * 4, Ebf + i * 4);
  }
  for (long i = gtid; i < 16384; i += NT) cvtc(p.init_output + i * 4, OF + i * 4);   // slot 0
  for (long i = gtid; i < 32768; i += NT) {
    long l = i >> 14, rem = i & 16383;
    cvtc(p.h0 + i * 4, (l ? Hb1 : Hb0) + 65536 + rem * 4);   // slot 1 (= prev at t=0)
  }
  for (long i = gtid; i < 131072; i += NT) {   // Cst[l][j][m] = c0[l][m][j]
    long l = i >> 16, rem = i & 65535, j = rem >> 6, m = rem & 63;
    Cst[i] = p.c0[l * 65536 + m * 1024 + j];
  }

  gsyncF(bar, gen); ++gen;

  // ---- S1: attention tables ----
  ctxw_gemm(bid, Ctx, Wai, CtxW);
  ctxw_gemm(bid, Ctx, Wc, CtxWc);
  gsyncF(bar, gen); ++gen;

  // ---- register-resident tables ----
  // P4 geometry, XCD-pinned: per XCD the nt set is fixed -> Wao slice L2-resident.
  const int xcd = bid & 7, idx = bid >> 3;
  const int ntP4 = xcd * 8 + (idx & 7), mtP4 = idx >> 3;
  const int arowP4 = mtP4 * 16 + (lane & 15);
  const int browP4 = ntP4 * 16 + (lane & 15);
  const int ke_ = (lane >> 4) * 8;

  bfrag waoreg[8];   // this wave's Wao fragments, loaded once
  {
    const u16* Bp = Wao + (long)browP4 * 2048 + ((w >> 2) ? 1024 : 0) + ke_;
#pragma unroll
    for (int q = 0; q < 8; ++q)
      waoreg[q] = ldf(Bp + ((w & 3) * 8 + q) * 32);
  }

  u32 ctxwreg[64];   // attention blocks: CtxW[b] held in registers (s=w*8+si, cols lane*16..)
  if (bid < 64) {
    const u32* src = (const u32*)(CtxW + (long)bid * 65536);
#pragma unroll
    for (int si = 0; si < 8; ++si)
#pragma unroll
      for (int i = 0; i < 8; ++i)
        ctxwreg[si * 8 + i] = src[(w * 8 + si) * 512 + lane * 8 + i];
  }

  // ---- main loop: 4 phases/step ----
  const int mt_ = w & 3, kh_ = w >> 2;
  const int arow_ = mt_ * 16 + (lane & 15);
  const int brow_ = lane & 15;

  for (int t = 0; t < 32; ++t) {
    const int cur = t & 1, prev = cur ^ 1;
    const u16* EbfT = Ebf + (long)t * 32768;
    const u16* OFc  = OF  + (long)cur * 65536;
    u16* Hb0c = Hb0 + (long)cur * 65536;
    const u16* Hb0p = Hb0 + (long)prev * 65536;
    u16* Hb1c = Hb1 + (long)cur * 65536;
    const u16* Hb1p = Hb1 + (long)prev * 65536;

    // P1: layer0 gates (K = 512 emb | 1024 feed | 1024 h0prev), 2-way K-split
    {
      f32x4 acc = {0.f, 0.f, 0.f, 0.f};
      if (kh_ == 0) {
        gemmseg(acc, EbfT, arow_, 512, 0,    W0, 2560, brow_, ke_, 0, 16);
        gemmseg(acc, OFc,  arow_, 1024, 512, W0, 2560, brow_, ke_, 16, 40);
      } else {
        gemmseg(acc, OFc,  arow_, 1024, 512,  W0, 2560, brow_, ke_, 40, 48);
        gemmseg(acc, Hb0p, arow_, 1024, 1536, W0, 2560, brow_, ke_, 48, 80);
      }
      scr_store(scr, mt_ * 2 + kh_, acc);
      __syncthreads();
      if (tid < 256) pointwise(bid, scr, p.b0, Cst, Hb0c);
    }
    gsyncF(bar, gen); ++gen;

    // P2: layer1 gates (K = 1024 h0n | 1024 h1prev)
    {
      f32x4 acc = {0.f, 0.f, 0.f, 0.f};
      if (kh_ == 0)
        gemmseg(acc, Hb0c, arow_, 1024, 0,    W1, 2048, brow_, ke_, 0, 32);
      else
        gemmseg(acc, Hb1p, arow_, 1024, 1024, W1, 2048, brow_, ke_, 32, 64);
      scr_store(scr, mt_ * 2 + kh_, acc);
      __syncthreads();
      if (tid < 256) pointwise(bid, scr, p.b1, Cst + 65536, Hb1c);
    }
    gsyncF(bar, gen); ++gen;

    // P3: attention for batch b = bid (first 64 blocks); scores from registers
    if (bid < 64) {
      const int b = bid;
      float* lds_s = scr;
      float* lds_a = scr + 64;
      float h1v[16];
      {
        const u32* u = (const u32*)(Hb1c + (long)b * 1024 + lane * 16);
#pragma unroll
        for (int i = 0; i < 8; ++i) {
          u32 x = u[i];
          h1v[2 * i]     = bf2f((u16)(x & 0xffff));
          h1v[2 * i + 1] = bf2f((u16)(x >> 16));
        }
      }
#pragma unroll
      for (int si = 0; si < 8; ++si) {
        int s = w * 8 + si;
        float acc = 0.f;
#pragma unroll
        for (int i = 0; i < 8; ++i) {
          u32 x = ctxwreg[si * 8 + i];
          acc += h1v[2 * i]     * bf2f((u16)(x & 0xffff));
          acc += h1v[2 * i + 1] * bf2f((u16)(x >> 16));
        }
#pragma unroll
        for (int off = 32; off; off >>= 1) acc += __shfl_down(acc, off, 64);
        if (lane == 0) lds_s[s] = acc;
      }
      __syncthreads();
      if (w == 0) {
        float v = lds_s[lane];
        float mx = v;
#pragma unroll
        for (int off = 32; off; off >>= 1) mx = fmaxf(mx, __shfl_xor(mx, off, 64));
        float e = __expf(v - mx);
        float sm = e;
#pragma unroll
        for (int off = 32; off; off >>= 1) sm += __shfl_xor(sm, off, 64);
        float a = e / sm;
        lds_a[lane] = a;
        p.out[AS_OFF + (long)t * 4096 + b * 64 + lane] = a;
      }
      __syncthreads();
      int k0 = w * 128 + lane * 2;
      const u16* cb = Ctx + (long)b * 65536 + k0;
      float a0 = 0.f, a1 = 0.f;
      for (int s = 0; s < 64; ++s) {
        float as = lds_a[s];
        u32 x = *(const u32*)(cb + (long)s * 1024);
        a0 += as * bf2f((u16)(x & 0xffff));
        a1 += as * bf2f((u16)(x >> 16));
      }
      *(u32*)(Wctx + b * 1024 + k0) = (u32)f2bf(a0) | ((u32)f2bf(a1) << 16);
    }
    gsyncF(bar, gen); ++gen;

    // P4: out = tanh([wctx|h1] @ Wao^T); Wao from registers, XCD-pinned tile
    {
      const u16* Abase = (w >> 2) ? Hb1c : Wctx;
      const u16* Ap = Abase + (long)arowP4 * 1024 + ke_;
      f32x4 acc = {0.f, 0.f, 0.f, 0.f};
#pragma unroll
      for (int q = 0; q < 8; ++q) {
        int kk = (w & 3) * 8 + q;
        acc = mfma16(ldf(Ap + kk * 32), waoreg[q], acc);
      }
      scr_store(scr, w, acc);
      __syncthreads();
      if (tid < 256) {
        int m = tid >> 4, n = tid & 15;
        float v = 0.f;
#pragma unroll
        for (int q = 0; q < 8; ++q) v += scr[q * 272 + m * 17 + n];
        v = tanh_(v);
        int mg = mtP4 * 16 + m, jg = ntP4 * 16 + n;
        p.out[(long)t * 65536 + mg * 1024 + jg] = v;
        OF[(long)((t + 1) & 1) * 65536 + mg * 1024 + jg] = f2bf(v);
      }
    }
    gsyncF(bar, gen); ++gen;
  }

  // ---- epilogue: final states (each block its 4 hidden units) ----
  if (tid < 256) {
    int u = tid >> 6, m = tid & 63, j = bid * 4 + u;
    p.out[HT_OFF + (long)m * 1024 + j]         = bf2f(Hb0[65536 + m * 1024 + j]);   // t=31 -> slot 1
    p.out[HT_OFF + 65536 + (long)m * 1024 + j] = bf2f(Hb1[65536 + m * 1024 + j]);
    p.out[CT_OFF + (long)m * 1024 + j]         = Cst[j * 64 + m];
    p.out[CT_OFF + 65536 + (long)m * 1024 + j] = Cst[65536 + j * 64 + m];
  }

  // ---- deferred copy-attention (64 blocks; reuse weight LDS as ctxWc[b] buffer) ----
  if (bid < 64) {
    const int b = bid;
    u16* cw = (u16*)smem;   // 128KB region (W0+W1 no longer needed)
    __syncthreads();
    {
      const bfrag* src = (const bfrag*)(CtxWc + (long)b * 65536);
      bfrag* dst = (bfrag*)cw;
      for (int i = tid; i < 8192; i += 512) dst[i] = src[i];
    }
    __syncthreads();
    float* lds_s = scr;
    for (int t = 0; t < 32; ++t) {
      float ov[16];
      {
        const float4* op = (const float4*)(p.out + (long)t * 65536 + b * 1024 + lane * 16);
#pragma unroll
        for (int i = 0; i < 4; ++i) {
          float4 v = op[i];
          ov[4 * i] = v.x; ov[4 * i + 1] = v.y; ov[4 * i + 2] = v.z; ov[4 * i + 3] = v.w;
        }
      }
#pragma unroll
      for (int si = 0; si < 8; ++si) {
        int s = w * 8 + si;
        const u32* u = (const u32*)(cw + s * 1024 + lane * 16);
        float acc = 0.f;
#pragma unroll
        for (int i = 0; i < 8; ++i) {
          u32 x = u[i];
          acc += ov[2 * i]     * bf2f((u16)(x & 0xffff));
          acc += ov[2 * i + 1] * bf2f((u16)(x >> 16));
        }
#pragma unroll
        for (int off = 32; off; off >>= 1) acc += __shfl_down(acc, off, 64);
        if (lane == 0) lds_s[s] = acc;
      }
      __syncthreads();
      if (w == 0) {
        float v = lds_s[lane];
        float mx = v;
#pragma unroll
        for (int off = 32; off; off >>= 1) mx = fmaxf(mx, __shfl_xor(mx, off, 64));
        float e = __expf(v - mx);
        float sm = e;
#pragma unroll
        for (int off = 32; off; off >>= 1) sm += __shfl_xor(sm, off, 64);
        p.out[AC_OFF + (long)t * 4096 + b * 64 + lane] = e / sm;
      }
      __syncthreads();
    }
  }
}

// ---------------- host ----------------
extern "C" void kernel_launch(void* const* d_in, const int* in_sizes, int n_in,
                              void* d_out, int out_size, void* d_ws, size_t ws_size,
                              hipStream_t stream) {
  KParams p;
  p.input       = (const int*)d_in[0];
  p.h0          = (const float*)d_in[1];
  p.c0          = (const float*)d_in[2];
  p.context     = (const float*)d_in[3];
  p.init_output = (const float*)d_in[4];
  p.embedding   = (const float*)d_in[5];
  p.W_ih0       = (const float*)d_in[6];
  p.W_hh0       = (const float*)d_in[7];
  p.b0          = (const float*)d_in[8];
  p.W_ih1       = (const float*)d_in[9];
  p.W_hh1       = (const float*)d_in[10];
  p.b1          = (const float*)d_in[11];
  p.attn_in     = (const float*)d_in[12];
  p.attn_out    = (const float*)d_in[13];
  p.copy_in     = (const float*)d_in[14];
  p.out         = (float*)d_out;
  p.ws          = (char*)d_ws;

  hipFuncSetAttribute((const void*)decoder_kernel,
                      hipFuncAttributeMaxDynamicSharedMemorySize, 156160);
  hipMemsetAsync((char*)d_ws + BAR_O, 0, 2048, stream);
  void* args[] = { &p };
  hipLaunchCooperativeKernel((void*)decoder_kernel, dim3(256), dim3(512),
                             args, 156160, stream);
}

// Round 6
// 2085.082 us; speedup vs baseline: 2.8304x; 1.8983x over previous
//
#include <hip/hip_runtime.h>

typedef unsigned short u16;
typedef unsigned int   u32;
typedef __attribute__((ext_vector_type(8))) __bf16 bfrag;   // 8 bf16 = 4 VGPR
typedef __attribute__((ext_vector_type(4))) float  f32x4;
typedef __attribute__((ext_vector_type(4))) u32    u32x4;

#define DEVI static __device__ __forceinline__

// ---- sc0sc1 (LLC-coherent) access macros; vmcnt tied via "+v" on ext-vector/scalar regs ----
#define LD16SC(dst, p) asm volatile("global_load_dwordx4 %0, %1, off sc0 sc1" : "=v"(dst) : "v"(p))
#define LD4SC(dst, p)  asm volatile("global_load_dword %0, %1, off sc0 sc1"   : "=v"(dst) : "v"(p))
#define LD2SC(dst, p)  asm volatile("global_load_ushort %0, %1, off sc0 sc1"  : "=v"(dst) : "v"(p))
#define ST4SC(p, v)    asm volatile("global_store_dword %0, %1, off sc0 sc1"  :: "v"(p), "v"(v) : "memory")
#define ST2SC(p, v)    asm volatile("global_store_short %0, %1, off sc0 sc1"  :: "v"(p), "v"(v) : "memory")
#define TIE4_4(a,b,c,d) asm volatile("s_waitcnt vmcnt(4)" : "+v"(a),"+v"(b),"+v"(c),"+v"(d))
#define TIE4_0(a,b,c,d) asm volatile("s_waitcnt vmcnt(0)" : "+v"(a),"+v"(b),"+v"(c),"+v"(d))
#define TIE2_0(a,b)     asm volatile("s_waitcnt vmcnt(0)" : "+v"(a),"+v"(b))
#define TIE1_0(a)       asm volatile("s_waitcnt vmcnt(0)" : "+v"(a))
#define VMFLUSH()       asm volatile("s_waitcnt vmcnt(0)" ::: "memory")

// ---------------- geometry ----------------
// T=32 B=64 S=64 E=512 H=1024 L=2 (4H=4096)
constexpr long OUT_OFF = 0;         // 32*64*1024
constexpr long HT_OFF  = 2097152;
constexpr long CT_OFF  = 2228224;
constexpr long AS_OFF  = 2359296;
constexpr long AC_OFF  = 2490368;

// ---------------- workspace layout (bytes) ----------------
constexpr long WAO_O   = 0;                   // attn_out_w bf16 [1024][2048] (4MB)
constexpr long WAI_O   = 4194304;             // attn_in_w^T bf16 (2MB)
constexpr long WC_O    = 6291456;             // copy_in_w^T bf16 (2MB)
constexpr long CTX_O   = 8388608;             // ctx (b,s,k) bf16 (8MB)
constexpr long CTXW_O  = 16777216;            // ctx @ Wai   bf16 [(b,s)][j] (8MB)
constexpr long CTXWC_O = 25165824;            // ctx @ Wc    bf16 (8MB)
constexpr long CTXOT_O = 33554432;            // (ctx @ Waoc)^T bf16 [b][j][s] (8MB)
constexpr long EBF_O   = 41943040;            // emb frag-major [t][16kk][4mt][64][8] (2MB)
constexpr long OFF_O   = 44040192;            // out-feed frag [2][131072B]
constexpr long HB0F_O  = 44302336;            // h0 frag [2]
constexpr long HB1F_O  = 44564480;            // h1 frag [2]
constexpr long HB1R_O  = 44826624;            // h1 row-major [2][64][1024] bf16
constexpr long HB0R_O  = 45088768;            // h0 row-major [2]
constexpr long CST_O   = 45350912;            // c state f32 [2][1024 j][64 m] (512KB)
constexpr long ABUF_O  = 45875200;            // a f32 [64][64] (16KB)
constexpr long BAR_O   = 45891584;            // flags[256]

// LDS layout (dynamic, 160256 B)
constexpr int W0LDS_O = 0;        // [16 rows][2560] bf16 swizzled = 81920
constexpr int W1LDS_O = 81920;    // [16 rows][2048] bf16 swizzled = 65536
constexpr int SCR_O   = 147456;   // 8 slots x 272 f32 = 8704
constexpr int SCR2_O  = 156160;   // 4096 B (softmax scratch / a-stage)

struct KParams {
  const int* input; const float* h0; const float* c0; const float* context;
  const float* init_output; const float* embedding;
  const float* W_ih0; const float* W_hh0; const float* b0;
  const float* W_ih1; const float* W_hh1; const float* b1;
  const float* attn_in; const float* attn_out; const float* copy_in;
  float* out; char* ws;
};

// ---------------- small helpers ----------------
DEVI float bf2f(u16 u) { u32 x = ((u32)u) << 16; return __builtin_bit_cast(float, x); }
DEVI u16 f2bf(float f) {
  u32 x = __builtin_bit_cast(u32, f);
  u32 r = x + 0x7fffu + ((x >> 16) & 1u);   // RNE
  return (u16)(r >> 16);
}
DEVI void cvtc(const float* s, u16* d) {
  float4 v = *(const float4*)s;
  uint2 u;
  u.x = (u32)f2bf(v.x) | ((u32)f2bf(v.y) << 16);
  u.y = (u32)f2bf(v.z) | ((u32)f2bf(v.w) << 16);
  *(uint2*)d = u;
}
DEVI float sigm(float x)  { return 1.f / (1.f + __expf(-x)); }
DEVI float tanh_(float x) { return 1.f - 2.f / (__expf(2.f * x) + 1.f); }
DEVI f32x4 mfma16(bfrag a, bfrag b, f32x4 c) {
  return __builtin_amdgcn_mfma_f32_16x16x32_bf16(a, b, c, 0, 0, 0);
}
// frag-major byte offset for element (m,k) of a [64 m][K k] activation
DEVI u32 fragoff(int m, int k) {
  return (u32)((((k >> 5) * 4 + (m >> 4)) * 64 + ((k >> 3) & 3) * 16 + (m & 15)) * 16 + (k & 7) * 2);
}

// ---------------- barriers ----------------
DEVI void pollflags(u32* flags, u32 gen) {
  int t = threadIdx.x;   // < 64
  for (;;) {
    u32 a = __hip_atomic_load(&flags[t],       __ATOMIC_RELAXED, __HIP_MEMORY_SCOPE_AGENT);
    u32 b = __hip_atomic_load(&flags[64 + t],  __ATOMIC_RELAXED, __HIP_MEMORY_SCOPE_AGENT);
    u32 c = __hip_atomic_load(&flags[128 + t], __ATOMIC_RELAXED, __HIP_MEMORY_SCOPE_AGENT);
    u32 d = __hip_atomic_load(&flags[192 + t], __ATOMIC_RELAXED, __HIP_MEMORY_SCOPE_AGENT);
    if (__all((a >= gen) && (b >= gen) && (c >= gen) && (d >= gen))) break;
    __builtin_amdgcn_s_sleep(1);
  }
}
// fenced barrier (setup only)
DEVI void gsync_fence(u32* flags, u32 gen) {
  __syncthreads();
  if (threadIdx.x == 0) {
    __builtin_amdgcn_fence(__ATOMIC_RELEASE, "agent");
    __hip_atomic_store(&flags[blockIdx.x], gen, __ATOMIC_RELAXED, __HIP_MEMORY_SCOPE_AGENT);
  }
  if (threadIdx.x < 64) pollflags(flags, gen);
  if (threadIdx.x == 0) __builtin_amdgcn_fence(__ATOMIC_ACQUIRE, "agent");
  __syncthreads();
}
// fence-free barrier (main loop): sc0sc1 data is LLC-coherent; no cache ops
DEVI void gsync_nf(u32* flags, u32 gen) {
  VMFLUSH();
  __syncthreads();
  if (threadIdx.x == 0)
    __hip_atomic_store(&flags[blockIdx.x], gen, __ATOMIC_RELAXED, __HIP_MEMORY_SCOPE_AGENT);
  if (threadIdx.x < 64) pollflags(flags, gen);
  __syncthreads();
  asm volatile("" ::: "memory");
}

// ---------------- pipelined gate-GEMM segment ----------------
// A: frag-major activation array; B: swizzled LDS weight slice.
template<int N4, bool SC>
DEVI void gseg(f32x4& acc, const char* Af, int kkA0, int mt, int lane,
               const char* W, int wRowK, int kkW0, int brow, int ke) {
  const u32 sw = (u32)((brow & 7) << 4);
  bfrag b0[4], b1[4];
#pragma unroll
  for (int q = 0; q < 4; ++q) {
    const char* p = Af + ((((kkA0 + q) * 4 + mt) * 64 + lane) << 4);
    if constexpr (SC) LD16SC(b0[q], p); else b0[q] = *(const bfrag*)p;
  }
#pragma unroll
  for (int g = 0; g < N4; ++g) {
    if ((g & 1) == 0) {
      if (g + 1 < N4) {
#pragma unroll
        for (int q = 0; q < 4; ++q) {
          const char* p = Af + ((((kkA0 + (g + 1) * 4 + q) * 4 + mt) * 64 + lane) << 4);
          if constexpr (SC) LD16SC(b1[q], p); else b1[q] = *(const bfrag*)p;
        }
        if constexpr (SC) TIE4_4(b0[0], b0[1], b0[2], b0[3]);
      } else {
        if constexpr (SC) TIE4_0(b0[0], b0[1], b0[2], b0[3]);
      }
#pragma unroll
      for (int q = 0; q < 4; ++q) {
        int kkW = kkW0 + g * 4 + q;
        u32 off = ((u32)(brow * wRowK + kkW * 32 + ke) * 2) ^ sw;
        acc = mfma16(b0[q], *(const bfrag*)(W + off), acc);
      }
    } else {
      if (g + 1 < N4) {
#pragma unroll
        for (int q = 0; q < 4; ++q) {
          const char* p = Af + ((((kkA0 + (g + 1) * 4 + q) * 4 + mt) * 64 + lane) << 4);
          if constexpr (SC) LD16SC(b0[q], p); else b0[q] = *(const bfrag*)p;
        }
        if constexpr (SC) TIE4_4(b1[0], b1[1], b1[2], b1[3]);
      } else {
        if constexpr (SC) TIE4_0(b1[0], b1[1], b1[2], b1[3]);
      }
#pragma unroll
      for (int q = 0; q < 4; ++q) {
        int kkW = kkW0 + g * 4 + q;
        u32 off = ((u32)(brow * wRowK + kkW * 32 + ke) * 2) ^ sw;
        acc = mfma16(b1[q], *(const bfrag*)(W + off), acc);
      }
    }
  }
}

DEVI void scr_store(float* scr, int slot, f32x4 acc) {
  const int lane = threadIdx.x & 63;
#pragma unroll
  for (int r = 0; r < 4; ++r)
    scr[slot * 272 + ((lane >> 4) * 4 + r) * 17 + (lane & 15)] = acc[r];
}

// LSTM pointwise: threads 0..255; (u = tid>>6, m = tid&63); sc stores for h
DEVI void pointwise(int bid, const float* scr, const float* bias, float* cst,
                    char* hfrag, char* hrow) {
  const int p = threadIdx.x;
  const int u = p >> 6, m = p & 63, j = bid * 4 + u;
  const int mt = m >> 4, ml = m & 15;
  float g4[4];
#pragma unroll
  for (int g = 0; g < 4; ++g) {
    int n = g * 4 + u;
    g4[g] = scr[(mt * 2) * 272 + ml * 17 + n] + scr[(mt * 2 + 1) * 272 + ml * 17 + n]
          + bias[g * 1024 + j];
  }
  float c = cst[j * 64 + m];
  float cn = sigm(g4[1]) * c + sigm(g4[0]) * tanh_(g4[2]);
  cst[j * 64 + m] = cn;
  u32 hv = (u32)f2bf(sigm(g4[3]) * tanh_(cn));
  ST2SC(hfrag + fragoff(m, j), hv);
  ST2SC(hrow + (u32)(m * 1024 + j) * 2, hv);
}

// setup GEMM: dst[(b,s)][j] = ctx[(b,s),:] . Wrow[j,:]
DEVI void ctxw_gemm(int mt, const u16* Ctx, const u16* Wm, u16* dst) {
  const int tid = threadIdx.x, lane = tid & 63, w = tid >> 6;
  const int arow = mt * 16 + (lane & 15);
  const int ke = (lane >> 4) * 8;
#pragma unroll
  for (int i = 0; i < 8; ++i) {
    int nt = w * 8 + i;
    const u16* A = Ctx + (long)arow * 1024 + ke;
    const u16* B = Wm + (long)(nt * 16 + (lane & 15)) * 1024 + ke;
    f32x4 acc = {0.f, 0.f, 0.f, 0.f};
    for (int kk = 0; kk < 1024; kk += 32)
      acc = mfma16(*(const bfrag*)(A + kk), *(const bfrag*)(B + kk), acc);
#pragma unroll
    for (int r = 0; r < 4; ++r)
      dst[(long)(mt * 16 + (lane >> 4) * 4 + r) * 1024 + nt * 16 + (lane & 15)] = f2bf(acc[r]);
  }
}

// setup GEMM: CtxOT[b][j][s] = ctx[(b,s),:] . Wao[j, 0..1024]
DEVI void ctxo_gemm(int bid, const u16* Ctx, const u16* Wao, u16* dst) {
  const int tid = threadIdx.x, lane = tid & 63, w = tid >> 6;
  const int arow = bid * 16 + (lane & 15);
  const int ke = (lane >> 4) * 8;
  const int b = bid >> 2, s0 = (bid & 3) * 16 + (lane >> 4) * 4;
#pragma unroll
  for (int i = 0; i < 8; ++i) {
    int nt = w * 8 + i;
    int j = nt * 16 + (lane & 15);
    const u16* A = Ctx + (long)arow * 1024 + ke;
    const u16* B = Wao + (long)j * 2048 + ke;
    f32x4 acc = {0.f, 0.f, 0.f, 0.f};
    for (int kk = 0; kk < 1024; kk += 32)
      acc = mfma16(*(const bfrag*)(A + kk), *(const bfrag*)(B + kk), acc);
    uint2 q;
    q.x = (u32)f2bf(acc[0]) | ((u32)f2bf(acc[1]) << 16);
    q.y = (u32)f2bf(acc[2]) | ((u32)f2bf(acc[3]) << 16);
    *(uint2*)(dst + ((long)(b * 1024 + j) * 64 + s0)) = q;
  }
}

// ---------------- the kernel ----------------
__global__ __launch_bounds__(512, 1) void decoder_kernel(KParams p) {
  extern __shared__ char smem[];
  char*  W0   = smem + W0LDS_O;
  char*  W1   = smem + W1LDS_O;
  float* scr  = (float*)(smem + SCR_O);
  float* scr2 = (float*)(smem + SCR2_O);

  char* wsb = p.ws;
  u16* Wao   = (u16*)(wsb + WAO_O);
  u16* Wai   = (u16*)(wsb + WAI_O);
  u16* Wc    = (u16*)(wsb + WC_O);
  u16* Ctx   = (u16*)(wsb + CTX_O);
  u16* CtxW  = (u16*)(wsb + CTXW_O);
  u16* CtxWc = (u16*)(wsb + CTXWC_O);
  u16* CtxOT = (u16*)(wsb + CTXOT_O);
  float* Cst = (float*)(wsb + CST_O);
  u32* bar   = (u32*)(wsb + BAR_O);

  const int bid = blockIdx.x, tid = threadIdx.x;
  const int lane = tid & 63, w = tid >> 6;
  const long gtid = (long)bid * 512 + tid, NT = 256l * 512;
  u32 gen = 1;

  // ---- S0-pre: LDS-tiled transposes of attn_in / copy_in ----
  {
    float* tile = (float*)smem;   // 64 x 69 f32 (inside W0 region, free now)
    for (int pass = 0; pass < 2; ++pass) {
      const float* src = pass ? p.copy_in : p.attn_in;
      u16* dst = pass ? Wc : Wai;
      int tr = bid >> 4, tc = bid & 15;
      {
        int r = tid >> 3, c = (tid & 7) * 8;
        const float4* s4 = (const float4*)(src + (long)(tr * 64 + r) * 1024 + tc * 64 + c);
        float4 a = s4[0], b = s4[1];
        float* tp = tile + r * 69 + c;
        tp[0] = a.x; tp[1] = a.y; tp[2] = a.z; tp[3] = a.w;
        tp[4] = b.x; tp[5] = b.y; tp[6] = b.z; tp[7] = b.w;
      }
      __syncthreads();
      {
        int r2 = tid >> 3, c2 = (tid & 7) * 8;
        u32 q[4];
#pragma unroll
        for (int i = 0; i < 4; ++i) {
          float lo = tile[(c2 + 2 * i) * 69 + r2];
          float hi = tile[(c2 + 2 * i + 1) * 69 + r2];
          q[i] = (u32)f2bf(lo) | ((u32)f2bf(hi) << 16);
        }
        *(uint4*)(dst + (long)(tc * 64 + r2) * 1024 + tr * 64 + c2) = *(uint4*)q;
      }
      __syncthreads();
    }
  }

  // ---- S0a: per-block weight slices -> LDS (stationary all 32 steps) ----
  for (int i = tid; i < 5120; i += 512) {
    int row = i / 320, k = (i % 320) * 8;
    int R = (row >> 2) * 1024 + bid * 4 + (row & 3);
    const float* src = (k < 1536) ? (p.W_ih0 + (long)R * 1536 + k)
                                  : (p.W_hh0 + (long)R * 1024 + (k - 1536));
    float4 a = *(const float4*)src, b = *(const float4*)(src + 4);
    uint4 q;
    q.x = (u32)f2bf(a.x) | ((u32)f2bf(a.y) << 16);
    q.y = (u32)f2bf(a.z) | ((u32)f2bf(a.w) << 16);
    q.z = (u32)f2bf(b.x) | ((u32)f2bf(b.y) << 16);
    q.w = (u32)f2bf(b.z) | ((u32)f2bf(b.w) << 16);
    u32 off = ((u32)(row * 2560 + k) * 2) ^ ((u32)((row & 7) << 4));
    *(uint4*)(W0 + off) = q;
  }
  for (int i = tid; i < 4096; i += 512) {
    int row = i / 256, k = (i % 256) * 8;
    int R = (row >> 2) * 1024 + bid * 4 + (row & 3);
    const float* src = (k < 1024) ? (p.W_ih1 + (long)R * 1024 + k)
                                  : (p.W_hh1 + (long)R * 1024 + (k - 1024));
    float4 a = *(const float4*)src, b = *(const float4*)(src + 4);
    uint4 q;
    q.x = (u32)f2bf(a.x) | ((u32)f2bf(a.y) << 16);
    q.y = (u32)f2bf(a.z) | ((u32)f2bf(a.w) << 16);
    q.z = (u32)f2bf(b.x) | ((u32)f2bf(b.y) << 16);
    q.w = (u32)f2bf(b.z) | ((u32)f2bf(b.w) << 16);
    u32 off = ((u32)(row * 2048 + k) * 2) ^ ((u32)((row & 7) << 4));
    *(uint4*)(W1 + off) = q;
  }

  // ---- S0b: global conversions ----
  for (long i = gtid; i < 524288; i += NT) cvtc(p.attn_out + i * 4, Wao + i * 4);
  for (long i = gtid; i < 1048576; i += NT) {
    long b = i >> 14, s = (i >> 8) & 63, kq = i & 255;
    cvtc(p.context + ((s * 64 + b) * 1024 + kq * 4), Ctx + i * 4);
  }
  for (long i = gtid; i < 262144; i += NT) {     // emb gather -> frag-major
    long row = i >> 7; long t = row >> 6, b = row & 63;
    long k0 = (i & 127) * 4;
    long tok = p.input[row];
    cvtc(p.embedding + tok * 512 + k0,
         (u16*)(wsb + EBF_O + t * 65536 + fragoff((int)b, (int)k0)));
  }
  for (long i = gtid; i < 16384; i += NT) {      // init_output -> OF frag slot 0
    long b = i >> 8, k0 = (i & 255) * 4;
    cvtc(p.init_output + i * 4, (u16*)(wsb + OFF_O + fragoff((int)b, (int)k0)));
  }
  for (long i = gtid; i < 32768; i += NT) {      // h0 -> frag slot 1 (prev at t=0)
    long l = i >> 14, rem = i & 16383, b = rem >> 8, k0 = (rem & 255) * 4;
    cvtc(p.h0 + i * 4,
         (u16*)(wsb + (l ? HB1F_O : HB0F_O) + 131072 + fragoff((int)b, (int)k0)));
  }
  for (long i = gtid; i < 131072; i += NT) {     // Cst[l][j][m] = c0[l][m][j]
    long l = i >> 16, rem = i & 65535, j = rem >> 6, m = rem & 63;
    Cst[i] = p.c0[l * 65536 + m * 1024 + j];
  }

  gsync_fence(bar, gen); ++gen;

  // ---- S1: attention tables ----
  ctxw_gemm(bid, Ctx, Wai, CtxW);
  ctxw_gemm(bid, Ctx, Wc, CtxWc);
  ctxo_gemm(bid, Ctx, Wao, CtxOT);
  gsync_fence(bar, gen); ++gen;

  // ---- P4 geometry (XCD-pinned) + Wao h1-half fragments in registers ----
  const int xcd = bid & 7, idx = bid >> 3;
  const int ntP4 = xcd * 8 + (idx & 7), mtP4 = idx >> 3;
  const int browP4 = ntP4 * 16 + (lane & 15);
  const int ke_ = (lane >> 4) * 8;
  bfrag waoreg[4];
#pragma unroll
  for (int q = 0; q < 4; ++q)
    waoreg[q] = *(const bfrag*)(Wao + (long)browP4 * 2048 + 1024 + (w * 4 + q) * 32 + ke_);

  const int mt_ = w & 3, kh_ = w >> 2;
  const int brow_ = lane & 15;

  for (int t = 0; t < 32; ++t) {
    const int cur = t & 1, prev = cur ^ 1;
    const char* EbfT  = wsb + EBF_O + (long)t * 65536;
    const char* OFc   = wsb + OFF_O  + (long)cur  * 131072;
    char*       Hb0cF = wsb + HB0F_O + (long)cur  * 131072;
    const char* Hb0pF = wsb + HB0F_O + (long)prev * 131072;
    char*       Hb1cF = wsb + HB1F_O + (long)cur  * 131072;
    const char* Hb1pF = wsb + HB1F_O + (long)prev * 131072;
    char*       Hb0cR = wsb + HB0R_O + (long)cur * 131072;
    char*       Hb1cR = wsb + HB1R_O + (long)cur * 131072;

    // ---- P1: layer0 gates ----
    {
      f32x4 acc = {0.f, 0.f, 0.f, 0.f};
      if (kh_ == 0) {
        gseg<4, false>(acc, EbfT, 0, mt_, lane, W0, 2560, 0,  brow_, ke_);
        gseg<6, true >(acc, OFc,  0, mt_, lane, W0, 2560, 16, brow_, ke_);
      } else {
        gseg<2, true>(acc, OFc,   24, mt_, lane, W0, 2560, 40, brow_, ke_);
        gseg<8, true>(acc, Hb0pF, 0,  mt_, lane, W0, 2560, 48, brow_, ke_);
      }
      scr_store(scr, mt_ * 2 + kh_, acc);
      __syncthreads();
      if (tid < 256) pointwise(bid, scr, p.b0, Cst, Hb0cF, Hb0cR);
    }
    gsync_nf(bar, gen); ++gen;

    // ---- P2: layer1 gates ----
    {
      f32x4 acc = {0.f, 0.f, 0.f, 0.f};
      if (kh_ == 0)
        gseg<8, true>(acc, Hb0cF, 0, mt_, lane, W1, 2048, 0,  brow_, ke_);
      else
        gseg<8, true>(acc, Hb1pF, 0, mt_, lane, W1, 2048, 32, brow_, ke_);
      scr_store(scr, mt_ * 2 + kh_, acc);
      __syncthreads();
      if (tid < 256) pointwise(bid, scr, p.b1, Cst + 65536, Hb1cF, Hb1cR);
    }
    gsync_nf(bar, gen); ++gen;

    // ---- P3 (blocks 0..63): scores + softmax -> a ;  then all blocks: P4h ----
    if (bid < 64) {
      const int b = bid;
      float h1v[16];
      {
        const char* hp = Hb1cR + (u32)(b * 1024 + lane * 16) * 2;
        u32x4 u0, u1;
        LD16SC(u0, hp); LD16SC(u1, hp + 16);
        TIE2_0(u0, u1);
        u32 uu[8] = {u0[0], u0[1], u0[2], u0[3], u1[0], u1[1], u1[2], u1[3]};
#pragma unroll
        for (int i = 0; i < 8; ++i) {
          h1v[2 * i]     = bf2f((u16)(uu[i] & 0xffff));
          h1v[2 * i + 1] = bf2f((u16)(uu[i] >> 16));
        }
      }
      const u16* cwb = CtxW + (long)b * 65536;
#pragma unroll
      for (int si = 0; si < 8; ++si) {
        int s = w * 8 + si;
        const u32* u = (const u32*)(cwb + (long)s * 1024 + lane * 16);
        float acc = 0.f;
#pragma unroll
        for (int i = 0; i < 8; ++i) {
          u32 x = u[i];
          acc += h1v[2 * i] * bf2f((u16)(x & 0xffff));
          acc += h1v[2 * i + 1] * bf2f((u16)(x >> 16));
        }
#pragma unroll
        for (int off = 32; off; off >>= 1) acc += __shfl_down(acc, off, 64);
        if (lane == 0) scr2[s] = acc;
      }
      __syncthreads();
      if (w == 0) {
        float v = scr2[lane];
        float mx = v;
#pragma unroll
        for (int off = 32; off; off >>= 1) mx = fmaxf(mx, __shfl_xor(mx, off, 64));
        float e = __expf(v - mx);
        float sm = e;
#pragma unroll
        for (int off = 32; off; off >>= 1) sm += __shfl_xor(sm, off, 64);
        float a = e / sm;
        ST4SC(wsb + ABUF_O + (u32)(b * 64 + lane) * 4, a);
        p.out[AS_OFF + (long)t * 4096 + b * 64 + lane] = a;
      }
    }
    // P4h: h1-half of out-projection (all blocks, 8-way K-split)
    {
      bfrag h0_, h1_, h2_, h3_;
      const char* bp = Hb1cF;
      LD16SC(h0_, bp + ((((w * 4 + 0) * 4 + mtP4) * 64 + lane) << 4));
      LD16SC(h1_, bp + ((((w * 4 + 1) * 4 + mtP4) * 64 + lane) << 4));
      LD16SC(h2_, bp + ((((w * 4 + 2) * 4 + mtP4) * 64 + lane) << 4));
      LD16SC(h3_, bp + ((((w * 4 + 3) * 4 + mtP4) * 64 + lane) << 4));
      TIE4_0(h0_, h1_, h2_, h3_);
      f32x4 a4 = {0.f, 0.f, 0.f, 0.f};
      a4 = mfma16(h0_, waoreg[0], a4);
      a4 = mfma16(h1_, waoreg[1], a4);
      a4 = mfma16(h2_, waoreg[2], a4);
      a4 = mfma16(h3_, waoreg[3], a4);
      scr_store(scr, w, a4);
    }
    gsync_nf(bar, gen); ++gen;

    // ---- P4c: out = tanh(sum_s a_s*CtxO[b,s,:] + h1half); write out + OF frag ----
    {
      // stage a[16 b][64 s] into scr2
#pragma unroll
      for (int it = 0; it < 2; ++it) {
        int idx2 = tid + it * 512;
        int b_l = idx2 >> 6, s = idx2 & 63;
        u32 av;
        LD4SC(av, wsb + ABUF_O + (u32)(((mtP4 * 16 + b_l) * 64 + s)) * 4);
        TIE1_0(av);
        scr2[idx2] = __builtin_bit_cast(float, av);
      }
      __syncthreads();
      const int pair = tid >> 1, half = tid & 1;
      const int m_l = pair >> 4, j_l = pair & 15;
      const int b = mtP4 * 16 + m_l, j = ntP4 * 16 + j_l;
      const u32* cp = (const u32*)(CtxOT + ((long)(b * 1024 + j) * 64 + half * 32));
      const float* al = scr2 + m_l * 64 + half * 32;
      float acc = 0.f;
#pragma unroll
      for (int i = 0; i < 16; ++i) {
        u32 x = cp[i];
        acc += al[2 * i] * bf2f((u16)(x & 0xffff));
        acc += al[2 * i + 1] * bf2f((u16)(x >> 16));
      }
      float v = acc + __shfl_xor(acc, 1, 64);
      if (half == 0) {
        float h1p = 0.f;
#pragma unroll
        for (int q = 0; q < 8; ++q) h1p += scr[q * 272 + m_l * 17 + j_l];
        v = tanh_(v + h1p);
        ST4SC((char*)(p.out + (long)t * 65536 + b * 1024 + j), __builtin_bit_cast(u32, v));
        u32 hv = (u32)f2bf(v);
        ST2SC(wsb + OFF_O + (long)((t + 1) & 1) * 131072 + fragoff(b, j), hv);
      }
    }
    gsync_nf(bar, gen); ++gen;
  }

  // ---- epilogue: final states (block-own 4 hidden units; t=31 -> slot 1) ----
  if (tid < 256) {
    int u = tid >> 6, m = tid & 63, j = bid * 4 + u;
    u32 a0, a1;
    LD2SC(a0, wsb + HB0R_O + 131072 + (u32)(m * 1024 + j) * 2);
    LD2SC(a1, wsb + HB1R_O + 131072 + (u32)(m * 1024 + j) * 2);
    TIE2_0(a0, a1);
    p.out[HT_OFF + (long)m * 1024 + j]         = bf2f((u16)a0);
    p.out[HT_OFF + 65536 + (long)m * 1024 + j] = bf2f((u16)a1);
    p.out[CT_OFF + (long)m * 1024 + j]         = Cst[j * 64 + m];
    p.out[CT_OFF + 65536 + (long)m * 1024 + j] = Cst[65536 + j * 64 + m];
  }

  // ---- deferred copy-attention (blocks 0..63) ----
  if (bid < 64) {
    const int b = bid;
    u16* cw = (u16*)smem;   // reuse W0+W1 region (weights dead)
    __syncthreads();
    {
      const uint4* src = (const uint4*)(CtxWc + (long)b * 65536);
      uint4* dst = (uint4*)cw;
      for (int i = tid; i < 8192; i += 512) dst[i] = src[i];
    }
    __syncthreads();
    float* lds_s = scr;
    for (int t = 0; t < 32; ++t) {
      float ov[16];
      {
        const char* op = (const char*)(p.out + (long)t * 65536 + b * 1024 + lane * 16);
        f32x4 f0, f1, f2, f3;
        LD16SC(f0, op); LD16SC(f1, op + 16); LD16SC(f2, op + 32); LD16SC(f3, op + 48);
        TIE4_0(f0, f1, f2, f3);
#pragma unroll
        for (int i = 0; i < 4; ++i) {
          ov[i]      = f0[i];
          ov[4 + i]  = f1[i];
          ov[8 + i]  = f2[i];
          ov[12 + i] = f3[i];
        }
      }
#pragma unroll
      for (int si = 0; si < 8; ++si) {
        int s = w * 8 + si;
        const u32* u = (const u32*)(cw + s * 1024 + lane * 16);
        float acc = 0.f;
#pragma unroll
        for (int i = 0; i < 8; ++i) {
          u32 x = u[i];
          acc += ov[2 * i] * bf2f((u16)(x & 0xffff));
          acc += ov[2 * i + 1] * bf2f((u16)(x >> 16));
        }
#pragma unroll
        for (int off = 32; off; off >>= 1) acc += __shfl_down(acc, off, 64);
        if (lane == 0) lds_s[s] = acc;
      }
      __syncthreads();
      if (w == 0) {
        float v = lds_s[lane];
        float mx = v;
#pragma unroll
        for (int off = 32; off; off >>= 1) mx = fmaxf(mx, __shfl_xor(mx, off, 64));
        float e = __expf(v - mx);
        float sm = e;
#pragma unroll
        for (int off = 32; off; off >>= 1) sm += __shfl_xor(sm, off, 64);
        p.out[AC_OFF + (long)t * 4096 + b * 64 + lane] = e / sm;
      }
      __syncthreads();
    }
  }
}

// ---------------- host ----------------
extern "C" void kernel_launch(void* const* d_in, const int* in_sizes, int n_in,
                              void* d_out, int out_size, void* d_ws, size_t ws_size,
                              hipStream_t stream) {
  KParams p;
  p.input       = (const int*)d_in[0];
  p.h0          = (const float*)d_in[1];
  p.c0          = (const float*)d_in[2];
  p.context     = (const float*)d_in[3];
  p.init_output = (const float*)d_in[4];
  p.embedding   = (const float*)d_in[5];
  p.W_ih0       = (const float*)d_in[6];
  p.W_hh0       = (const float*)d_in[7];
  p.b0          = (const float*)d_in[8];
  p.W_ih1       = (const float*)d_in[9];
  p.W_hh1       = (const float*)d_in[10];
  p.b1          = (const float*)d_in[11];
  p.attn_in     = (const float*)d_in[12];
  p.attn_out    = (const float*)d_in[13];
  p.copy_in     = (const float*)d_in[14];
  p.out         = (float*)d_out;
  p.ws          = (char*)d_ws;

  (void)hipFuncSetAttribute((const void*)decoder_kernel,
                            hipFuncAttributeMaxDynamicSharedMemorySize, 160256);
  (void)hipMemsetAsync((char*)d_ws + BAR_O, 0, 2048, stream);
  void* args[] = { &p };
  (void)hipLaunchCooperativeKernel((void*)decoder_kernel, dim3(256), dim3(512),
                                   args, 160256, stream);
}

// Round 7
// 2069.198 us; speedup vs baseline: 2.8521x; 1.0077x over previous
//
#include <hip/hip_runtime.h>

typedef unsigned short u16;
typedef unsigned int   u32;
typedef __attribute__((ext_vector_type(8))) __bf16 bfrag;   // 8 bf16 = 4 VGPR
typedef __attribute__((ext_vector_type(4))) float  f32x4;
typedef __attribute__((ext_vector_type(4))) u32    u32x4;
typedef __attribute__((ext_vector_type(2))) u32    u32x2;

#define DEVI static __device__ __forceinline__

// ---- sc0sc1 (LLC-coherent) access macros; vmcnt tied via "+v" on ext-vector/scalar regs ----
#define LD16SC(dst, p) asm volatile("global_load_dwordx4 %0, %1, off sc0 sc1" : "=v"(dst) : "v"(p))
#define LD4SC(dst, p)  asm volatile("global_load_dword %0, %1, off sc0 sc1"   : "=v"(dst) : "v"(p))
#define LD2SC(dst, p)  asm volatile("global_load_ushort %0, %1, off sc0 sc1"  : "=v"(dst) : "v"(p))
#define ST4SC(p, v)    asm volatile("global_store_dword %0, %1, off sc0 sc1"  :: "v"(p), "v"(v) : "memory")
#define ST2SC(p, v)    asm volatile("global_store_short %0, %1, off sc0 sc1"  :: "v"(p), "v"(v) : "memory")
#define ST8SC(p, v)    asm volatile("global_store_dwordx2 %0, %1, off sc0 sc1" :: "v"(p), "v"(v) : "memory")
#define TIE4_4(a,b,c,d) asm volatile("s_waitcnt vmcnt(4)" : "+v"(a),"+v"(b),"+v"(c),"+v"(d))
#define TIE4_0(a,b,c,d) asm volatile("s_waitcnt vmcnt(0)" : "+v"(a),"+v"(b),"+v"(c),"+v"(d))
#define TIE2_0(a,b)     asm volatile("s_waitcnt vmcnt(0)" : "+v"(a),"+v"(b))
#define VMFLUSH()       asm volatile("s_waitcnt vmcnt(0)" ::: "memory")

// ---------------- geometry ----------------
// T=32 B=64 S=64 E=512 H=1024 L=2 (4H=4096)
constexpr long OUT_OFF = 0;         // 32*64*1024
constexpr long HT_OFF  = 2097152;
constexpr long CT_OFF  = 2228224;
constexpr long AS_OFF  = 2359296;
constexpr long AC_OFF  = 2490368;

// ---------------- workspace layout (bytes) ----------------
constexpr long WAO_O   = 0;                   // attn_out_w bf16 [1024][2048] (4MB)
constexpr long WAI_O   = 4194304;             // attn_in_w^T bf16 (2MB)
constexpr long WC_O    = 6291456;             // copy_in_w^T bf16 (2MB)
constexpr long CTX_O   = 8388608;             // ctx (b,s,k) bf16 (8MB)
constexpr long CTXW_O  = 16777216;            // ctx @ Wai   bf16 [(b,s)][j] (8MB)
constexpr long CTXWC_O = 25165824;            // ctx @ Wc    bf16 (8MB)
constexpr long CTXOT_O = 33554432;            // (ctx @ Waoc)^T bf16 [b][j][s] (8MB)
constexpr long EBF_O   = 41943040;            // emb frag-major [t][16kk][4mt][64][8] (2MB)
constexpr long OFF_O   = 44040192;            // out-feed frag [2][131072B]
constexpr long HB0F_O  = 44302336;            // h0 frag [2]
constexpr long HB1F_O  = 44564480;            // h1 frag [2]
constexpr long CST_O   = 45350912;            // c state f32 [2][1024 j][64 m] (512KB)
constexpr long ABUF_O  = 45875200;            // a f32 [64][64] (16KB)
constexpr long BAR_O   = 45891584;            // flags[256]

// LDS layout (dynamic, 160256 B)
constexpr int W0LDS_O = 0;        // [16 rows][2560] bf16 swizzled = 81920
constexpr int W1LDS_O = 81920;    // [16 rows][2048] bf16 swizzled = 65536
constexpr int SCR_O   = 147456;   // 8 slots x 272 f32 = 8704
constexpr int SCR2_O  = 156160;   // 4096 B (softmax scratch / a-stage)

struct KParams {
  const int* input; const float* h0; const float* c0; const float* context;
  const float* init_output; const float* embedding;
  const float* W_ih0; const float* W_hh0; const float* b0;
  const float* W_ih1; const float* W_hh1; const float* b1;
  const float* attn_in; const float* attn_out; const float* copy_in;
  float* out; char* ws;
};

// ---------------- small helpers ----------------
DEVI float bf2f(u16 u) { u32 x = ((u32)u) << 16; return __builtin_bit_cast(float, x); }
DEVI u16 f2bf(float f) {
  u32 x = __builtin_bit_cast(u32, f);
  u32 r = x + 0x7fffu + ((x >> 16) & 1u);   // RNE
  return (u16)(r >> 16);
}
DEVI void cvtc(const float* s, u16* d) {
  float4 v = *(const float4*)s;
  uint2 u;
  u.x = (u32)f2bf(v.x) | ((u32)f2bf(v.y) << 16);
  u.y = (u32)f2bf(v.z) | ((u32)f2bf(v.w) << 16);
  *(uint2*)d = u;
}
DEVI float sigm(float x)  { return 1.f / (1.f + __expf(-x)); }
DEVI float tanh_(float x) { return 1.f - 2.f / (__expf(2.f * x) + 1.f); }
DEVI f32x4 mfma16(bfrag a, bfrag b, f32x4 c) {
  return __builtin_amdgcn_mfma_f32_16x16x32_bf16(a, b, c, 0, 0, 0);
}
// frag-major byte offset for element (m,k) of a [64 m][K k] activation
DEVI u32 fragoff(int m, int k) {
  return (u32)((((k >> 5) * 4 + (m >> 4)) * 64 + ((k >> 3) & 3) * 16 + (m & 15)) * 16 + (k & 7) * 2);
}

// ---------------- barriers (split arrive/wait, all-to-all poll) ----------------
DEVI void pollflags(u32* flags, u32 gen) {
  int t = threadIdx.x;   // < 64
  for (;;) {
    u32 a = __hip_atomic_load(&flags[t],       __ATOMIC_RELAXED, __HIP_MEMORY_SCOPE_AGENT);
    u32 b = __hip_atomic_load(&flags[64 + t],  __ATOMIC_RELAXED, __HIP_MEMORY_SCOPE_AGENT);
    u32 c = __hip_atomic_load(&flags[128 + t], __ATOMIC_RELAXED, __HIP_MEMORY_SCOPE_AGENT);
    u32 d = __hip_atomic_load(&flags[192 + t], __ATOMIC_RELAXED, __HIP_MEMORY_SCOPE_AGENT);
    if (__all((a >= gen) && (b >= gen) && (c >= gen) && (d >= gen))) break;
    __builtin_amdgcn_s_sleep(1);
  }
}
DEVI void barr_arrive(u32* flags, u32 gen) {
  VMFLUSH();               // each wave drains its own vmem before syncthreads
  __syncthreads();
  if (threadIdx.x == 0)
    __hip_atomic_store(&flags[blockIdx.x], gen, __ATOMIC_RELAXED, __HIP_MEMORY_SCOPE_AGENT);
}
DEVI void barr_wait(u32* flags, u32 gen) {
  if (threadIdx.x < 64) pollflags(flags, gen);
  __syncthreads();
  asm volatile("" ::: "memory");
}
// fenced barrier (setup only)
DEVI void gsync_fence(u32* flags, u32 gen) {
  __syncthreads();
  if (threadIdx.x == 0) {
    __builtin_amdgcn_fence(__ATOMIC_RELEASE, "agent");
    __hip_atomic_store(&flags[blockIdx.x], gen, __ATOMIC_RELAXED, __HIP_MEMORY_SCOPE_AGENT);
  }
  if (threadIdx.x < 64) pollflags(flags, gen);
  if (threadIdx.x == 0) __builtin_amdgcn_fence(__ATOMIC_ACQUIRE, "agent");
  __syncthreads();
}

// ---------------- pipelined gate-GEMM segment ----------------
// A: frag-major activation array; B: swizzled LDS weight slice.
template<int N4, bool SC>
DEVI void gseg(f32x4& acc, const char* Af, int kkA0, int mt, int lane,
               const char* W, int wRowK, int kkW0, int brow, int ke) {
  const u32 sw = (u32)((brow & 7) << 4);
  bfrag b0[4], b1[4];
#pragma unroll
  for (int q = 0; q < 4; ++q) {
    const char* p = Af + ((((kkA0 + q) * 4 + mt) * 64 + lane) << 4);
    if constexpr (SC) LD16SC(b0[q], p); else b0[q] = *(const bfrag*)p;
  }
#pragma unroll
  for (int g = 0; g < N4; ++g) {
    if ((g & 1) == 0) {
      if (g + 1 < N4) {
#pragma unroll
        for (int q = 0; q < 4; ++q) {
          const char* p = Af + ((((kkA0 + (g + 1) * 4 + q) * 4 + mt) * 64 + lane) << 4);
          if constexpr (SC) LD16SC(b1[q], p); else b1[q] = *(const bfrag*)p;
        }
        if constexpr (SC) TIE4_4(b0[0], b0[1], b0[2], b0[3]);
      } else {
        if constexpr (SC) TIE4_0(b0[0], b0[1], b0[2], b0[3]);
      }
#pragma unroll
      for (int q = 0; q < 4; ++q) {
        int kkW = kkW0 + g * 4 + q;
        u32 off = ((u32)(brow * wRowK + kkW * 32 + ke) * 2) ^ sw;
        acc = mfma16(b0[q], *(const bfrag*)(W + off), acc);
      }
    } else {
      if (g + 1 < N4) {
#pragma unroll
        for (int q = 0; q < 4; ++q) {
          const char* p = Af + ((((kkA0 + (g + 1) * 4 + q) * 4 + mt) * 64 + lane) << 4);
          if constexpr (SC) LD16SC(b0[q], p); else b0[q] = *(const bfrag*)p;
        }
        if constexpr (SC) TIE4_4(b1[0], b1[1], b1[2], b1[3]);
      } else {
        if constexpr (SC) TIE4_0(b1[0], b1[1], b1[2], b1[3]);
      }
#pragma unroll
      for (int q = 0; q < 4; ++q) {
        int kkW = kkW0 + g * 4 + q;
        u32 off = ((u32)(brow * wRowK + kkW * 32 + ke) * 2) ^ sw;
        acc = mfma16(b1[q], *(const bfrag*)(W + off), acc);
      }
    }
  }
}

DEVI void scr_store(float* scr, int slot, f32x4 acc) {
  const int lane = threadIdx.x & 63;
#pragma unroll
  for (int r = 0; r < 4; ++r)
    scr[slot * 272 + ((lane >> 4) * 4 + r) * 17 + (lane & 15)] = acc[r];
}

// LSTM pointwise: threads 0..63; thread m handles its block's 4 hidden units; one 8B h-store
DEVI void pointwise64(int bid, const float* scr, const float* bias, float* cst, char* hfrag) {
  const int m = threadIdx.x;            // < 64
  const int mt = m >> 4, ml = m & 15;
  u32 hp0 = 0, hp1 = 0;
#pragma unroll
  for (int u = 0; u < 4; ++u) {
    const int j = bid * 4 + u;
    float g0 = scr[(mt*2)*272 + ml*17 + u]      + scr[(mt*2+1)*272 + ml*17 + u]      + bias[j];
    float g1 = scr[(mt*2)*272 + ml*17 + 4 + u]  + scr[(mt*2+1)*272 + ml*17 + 4 + u]  + bias[1024 + j];
    float g2 = scr[(mt*2)*272 + ml*17 + 8 + u]  + scr[(mt*2+1)*272 + ml*17 + 8 + u]  + bias[2048 + j];
    float g3 = scr[(mt*2)*272 + ml*17 + 12 + u] + scr[(mt*2+1)*272 + ml*17 + 12 + u] + bias[3072 + j];
    float c = cst[j * 64 + m];
    float cn = sigm(g1) * c + sigm(g0) * tanh_(g2);
    cst[j * 64 + m] = cn;
    u32 hb = (u32)f2bf(sigm(g3) * tanh_(cn));
    if (u == 0) hp0 = hb; else if (u == 1) hp0 |= hb << 16;
    else if (u == 2) hp1 = hb; else hp1 |= hb << 16;
  }
  u32x2 v; v[0] = hp0; v[1] = hp1;
  ST8SC(hfrag + fragoff(m, bid * 4), v);
}

// setup GEMM: dst[(b,s)][j] = ctx[(b,s),:] . Wrow[j,:]
DEVI void ctxw_gemm(int mt, const u16* Ctx, const u16* Wm, u16* dst) {
  const int tid = threadIdx.x, lane = tid & 63, w = tid >> 6;
  const int arow = mt * 16 + (lane & 15);
  const int ke = (lane >> 4) * 8;
#pragma unroll
  for (int i = 0; i < 8; ++i) {
    int nt = w * 8 + i;
    const u16* A = Ctx + (long)arow * 1024 + ke;
    const u16* B = Wm + (long)(nt * 16 + (lane & 15)) * 1024 + ke;
    f32x4 acc = {0.f, 0.f, 0.f, 0.f};
    for (int kk = 0; kk < 1024; kk += 32)
      acc = mfma16(*(const bfrag*)(A + kk), *(const bfrag*)(B + kk), acc);
#pragma unroll
    for (int r = 0; r < 4; ++r)
      dst[(long)(mt * 16 + (lane >> 4) * 4 + r) * 1024 + nt * 16 + (lane & 15)] = f2bf(acc[r]);
  }
}

// setup GEMM: CtxOT[b][j][s] = ctx[(b,s),:] . Wao[j, 0..1024]
DEVI void ctxo_gemm(int bid, const u16* Ctx, const u16* Wao, u16* dst) {
  const int tid = threadIdx.x, lane = tid & 63, w = tid >> 6;
  const int arow = bid * 16 + (lane & 15);
  const int ke = (lane >> 4) * 8;
  const int b = bid >> 2, s0 = (bid & 3) * 16 + (lane >> 4) * 4;
#pragma unroll
  for (int i = 0; i < 8; ++i) {
    int nt = w * 8 + i;
    int j = nt * 16 + (lane & 15);
    const u16* A = Ctx + (long)arow * 1024 + ke;
    const u16* B = Wao + (long)j * 2048 + ke;
    f32x4 acc = {0.f, 0.f, 0.f, 0.f};
    for (int kk = 0; kk < 1024; kk += 32)
      acc = mfma16(*(const bfrag*)(A + kk), *(const bfrag*)(B + kk), acc);
    uint2 q;
    q.x = (u32)f2bf(acc[0]) | ((u32)f2bf(acc[1]) << 16);
    q.y = (u32)f2bf(acc[2]) | ((u32)f2bf(acc[3]) << 16);
    *(uint2*)(dst + ((long)(b * 1024 + j) * 64 + s0)) = q;
  }
}

// ---------------- the kernel ----------------
__global__ __launch_bounds__(512, 1) void decoder_kernel(KParams p) {
  extern __shared__ char smem[];
  char*  W0   = smem + W0LDS_O;
  char*  W1   = smem + W1LDS_O;
  float* scr  = (float*)(smem + SCR_O);
  float* scr2 = (float*)(smem + SCR2_O);

  char* wsb = p.ws;
  u16* Wao   = (u16*)(wsb + WAO_O);
  u16* Wai   = (u16*)(wsb + WAI_O);
  u16* Wc    = (u16*)(wsb + WC_O);
  u16* Ctx   = (u16*)(wsb + CTX_O);
  u16* CtxW  = (u16*)(wsb + CTXW_O);
  u16* CtxWc = (u16*)(wsb + CTXWC_O);
  u16* CtxOT = (u16*)(wsb + CTXOT_O);
  float* Cst = (float*)(wsb + CST_O);
  u32* bar   = (u32*)(wsb + BAR_O);

  const int bid = blockIdx.x, tid = threadIdx.x;
  const int lane = tid & 63, w = tid >> 6;
  const long gtid = (long)bid * 512 + tid, NT = 256l * 512;
  u32 gen = 1;

  // ---- S0-pre: LDS-tiled transposes of attn_in / copy_in ----
  {
    float* tile = (float*)smem;
    for (int pass = 0; pass < 2; ++pass) {
      const float* src = pass ? p.copy_in : p.attn_in;
      u16* dst = pass ? Wc : Wai;
      int tr = bid >> 4, tc = bid & 15;
      {
        int r = tid >> 3, c = (tid & 7) * 8;
        const float4* s4 = (const float4*)(src + (long)(tr * 64 + r) * 1024 + tc * 64 + c);
        float4 a = s4[0], b = s4[1];
        float* tp = tile + r * 69 + c;
        tp[0] = a.x; tp[1] = a.y; tp[2] = a.z; tp[3] = a.w;
        tp[4] = b.x; tp[5] = b.y; tp[6] = b.z; tp[7] = b.w;
      }
      __syncthreads();
      {
        int r2 = tid >> 3, c2 = (tid & 7) * 8;
        u32 q[4];
#pragma unroll
        for (int i = 0; i < 4; ++i) {
          float lo = tile[(c2 + 2 * i) * 69 + r2];
          float hi = tile[(c2 + 2 * i + 1) * 69 + r2];
          q[i] = (u32)f2bf(lo) | ((u32)f2bf(hi) << 16);
        }
        *(uint4*)(dst + (long)(tc * 64 + r2) * 1024 + tr * 64 + c2) = *(uint4*)q;
      }
      __syncthreads();
    }
  }

  // ---- S0a: per-block weight slices -> LDS (stationary all 32 steps) ----
  for (int i = tid; i < 5120; i += 512) {
    int row = i / 320, k = (i % 320) * 8;
    int R = (row >> 2) * 1024 + bid * 4 + (row & 3);
    const float* src = (k < 1536) ? (p.W_ih0 + (long)R * 1536 + k)
                                  : (p.W_hh0 + (long)R * 1024 + (k - 1536));
    float4 a = *(const float4*)src, b = *(const float4*)(src + 4);
    uint4 q;
    q.x = (u32)f2bf(a.x) | ((u32)f2bf(a.y) << 16);
    q.y = (u32)f2bf(a.z) | ((u32)f2bf(a.w) << 16);
    q.z = (u32)f2bf(b.x) | ((u32)f2bf(b.y) << 16);
    q.w = (u32)f2bf(b.z) | ((u32)f2bf(b.w) << 16);
    u32 off = ((u32)(row * 2560 + k) * 2) ^ ((u32)((row & 7) << 4));
    *(uint4*)(W0 + off) = q;
  }
  for (int i = tid; i < 4096; i += 512) {
    int row = i / 256, k = (i % 256) * 8;
    int R = (row >> 2) * 1024 + bid * 4 + (row & 3);
    const float* src = (k < 1024) ? (p.W_ih1 + (long)R * 1024 + k)
                                  : (p.W_hh1 + (long)R * 1024 + (k - 1024));
    float4 a = *(const float4*)src, b = *(const float4*)(src + 4);
    uint4 q;
    q.x = (u32)f2bf(a.x) | ((u32)f2bf(a.y) << 16);
    q.y = (u32)f2bf(a.z) | ((u32)f2bf(a.w) << 16);
    q.z = (u32)f2bf(b.x) | ((u32)f2bf(b.y) << 16);
    q.w = (u32)f2bf(b.z) | ((u32)f2bf(b.w) << 16);
    u32 off = ((u32)(row * 2048 + k) * 2) ^ ((u32)((row & 7) << 4));
    *(uint4*)(W1 + off) = q;
  }

  // ---- S0b: global conversions ----
  for (long i = gtid; i < 524288; i += NT) cvtc(p.attn_out + i * 4, Wao + i * 4);
  for (long i = gtid; i < 1048576; i += NT) {
    long b = i >> 14, s = (i >> 8) & 63, kq = i & 255;
    cvtc(p.context + ((s * 64 + b) * 1024 + kq * 4), Ctx + i * 4);
  }
  for (long i = gtid; i < 262144; i += NT) {     // emb gather -> frag-major
    long row = i >> 7; long t = row >> 6, b = row & 63;
    long k0 = (i & 127) * 4;
    long tok = p.input[row];
    cvtc(p.embedding + tok * 512 + k0,
         (u16*)(wsb + EBF_O + t * 65536 + fragoff((int)b, (int)k0)));
  }
  for (long i = gtid; i < 16384; i += NT) {      // init_output -> OF frag slot 0
    long b = i >> 8, k0 = (i & 255) * 4;
    cvtc(p.init_output + i * 4, (u16*)(wsb + OFF_O + fragoff((int)b, (int)k0)));
  }
  for (long i = gtid; i < 32768; i += NT) {      // h0 -> frag slot 1 (prev at t=0)
    long l = i >> 14, rem = i & 16383, b = rem >> 8, k0 = (rem & 255) * 4;
    cvtc(p.h0 + i * 4,
         (u16*)(wsb + (l ? HB1F_O : HB0F_O) + 131072 + fragoff((int)b, (int)k0)));
  }
  for (long i = gtid; i < 131072; i += NT) {     // Cst[l][j][m] = c0[l][m][j]
    long l = i >> 16, rem = i & 65535, j = rem >> 6, m = rem & 63;
    Cst[i] = p.c0[l * 65536 + m * 1024 + j];
  }

  gsync_fence(bar, gen); ++gen;

  // ---- S1: attention tables ----
  ctxw_gemm(bid, Ctx, Wai, CtxW);
  ctxw_gemm(bid, Ctx, Wc, CtxWc);
  ctxo_gemm(bid, Ctx, Wao, CtxOT);
  gsync_fence(bar, gen); ++gen;

  // ---- P4 geometry (XCD-pinned) + Wao h1-half fragments in registers ----
  const int xcd = bid & 7, idx = bid >> 3;
  const int ntP4 = xcd * 8 + (idx & 7), mtP4 = idx >> 3;
  const int browP4 = ntP4 * 16 + (lane & 15);
  const int ke_ = (lane >> 4) * 8;
  bfrag waoreg[4];
#pragma unroll
  for (int q = 0; q < 4; ++q)
    waoreg[q] = *(const bfrag*)(Wao + (long)browP4 * 2048 + 1024 + (w * 4 + q) * 32 + ke_);

  const int mt_ = w & 3, kh_ = w >> 2;
  const int brow_ = lane & 15;

  // ---- pre-loop P1(0) lookahead: emb(0) + h0prev(slot1) ----
  f32x4 accP1 = {0.f, 0.f, 0.f, 0.f}, accP2;
  {
    const char* E0  = wsb + EBF_O;
    const char* H0p = wsb + HB0F_O + 131072;
    if (kh_ == 0) {
      gseg<2, false>(accP1, E0,  0,  mt_, lane, W0, 2560, 0,  brow_, ke_);
      gseg<4, true >(accP1, H0p, 0,  mt_, lane, W0, 2560, 48, brow_, ke_);
    } else {
      gseg<2, false>(accP1, E0,  8,  mt_, lane, W0, 2560, 8,  brow_, ke_);
      gseg<4, true >(accP1, H0p, 16, mt_, lane, W0, 2560, 64, brow_, ke_);
    }
  }

  for (int t = 0; t < 32; ++t) {
    const int cur = t & 1, prev = cur ^ 1;
    const char* OFc   = wsb + OFF_O  + (long)cur  * 131072;
    char*       Hb0cF = wsb + HB0F_O + (long)cur  * 131072;
    char*       Hb1cF = wsb + HB1F_O + (long)cur  * 131072;
    const char* Hb1pF = wsb + HB1F_O + (long)prev * 131072;

    // ---- P1 remainder: out-feed segment (OF(t) just became ready) ----
    {
      f32x4 acc = accP1;
      if (kh_ == 0) gseg<4, true>(acc, OFc, 0,  mt_, lane, W0, 2560, 16, brow_, ke_);
      else          gseg<4, true>(acc, OFc, 16, mt_, lane, W0, 2560, 32, brow_, ke_);
      scr_store(scr, mt_ * 2 + kh_, acc);
      __syncthreads();
      if (tid < 64) pointwise64(bid, scr, p.b0, Cst, Hb0cF);
    }
    barr_arrive(bar, gen);
    // P2 lookahead: h1prev segment (h1(t-1), ready since last step)
    accP2 = f32x4{0.f, 0.f, 0.f, 0.f};
    if (kh_ == 0) gseg<4, true>(accP2, Hb1pF, 0,  mt_, lane, W1, 2048, 32, brow_, ke_);
    else          gseg<4, true>(accP2, Hb1pF, 16, mt_, lane, W1, 2048, 48, brow_, ke_);
    barr_wait(bar, gen); ++gen;

    // ---- P2 remainder: h0new segment ----
    {
      f32x4 acc = accP2;
      if (kh_ == 0) gseg<4, true>(acc, Hb0cF, 0,  mt_, lane, W1, 2048, 0,  brow_, ke_);
      else          gseg<4, true>(acc, Hb0cF, 16, mt_, lane, W1, 2048, 16, brow_, ke_);
      scr_store(scr, mt_ * 2 + kh_, acc);
      __syncthreads();
      if (tid < 64) pointwise64(bid, scr, p.b1, Cst + 65536, Hb1cF);
    }
    barr_arrive(bar, gen);
    // P1(t+1) lookahead part A: emb(t+1) + first half of h0p(t)
    accP1 = f32x4{0.f, 0.f, 0.f, 0.f};
    {
      const char* En = wsb + EBF_O + (long)((t + 1) & 31) * 65536;
      if (kh_ == 0) {
        gseg<2, false>(accP1, En,    0,  mt_, lane, W0, 2560, 0,  brow_, ke_);
        gseg<2, true >(accP1, Hb0cF, 0,  mt_, lane, W0, 2560, 48, brow_, ke_);
      } else {
        gseg<2, false>(accP1, En,    8,  mt_, lane, W0, 2560, 8,  brow_, ke_);
        gseg<2, true >(accP1, Hb0cF, 16, mt_, lane, W0, 2560, 64, brow_, ke_);
      }
    }
    barr_wait(bar, gen); ++gen;

    // ---- P3 (blocks 0..63): scores from h1-frag + softmax -> a; all blocks: P4h ----
    if (bid < 64) {
      const int b = bid;
      float h1v[16];
      {
        int k0 = lane * 16;
        u32x4 u0, u1;
        LD16SC(u0, Hb1cF + fragoff(b, k0));
        LD16SC(u1, Hb1cF + fragoff(b, k0 + 8));
        TIE2_0(u0, u1);
        u32 uu[8] = {u0[0], u0[1], u0[2], u0[3], u1[0], u1[1], u1[2], u1[3]};
#pragma unroll
        for (int i = 0; i < 8; ++i) {
          h1v[2 * i]     = bf2f((u16)(uu[i] & 0xffff));
          h1v[2 * i + 1] = bf2f((u16)(uu[i] >> 16));
        }
      }
      const u16* cwb = CtxW + (long)b * 65536;
#pragma unroll
      for (int si = 0; si < 8; ++si) {
        int s = w * 8 + si;
        const u32* u = (const u32*)(cwb + (long)s * 1024 + lane * 16);
        float acc = 0.f;
#pragma unroll
        for (int i = 0; i < 8; ++i) {
          u32 x = u[i];
          acc += h1v[2 * i] * bf2f((u16)(x & 0xffff));
          acc += h1v[2 * i + 1] * bf2f((u16)(x >> 16));
        }
#pragma unroll
        for (int off = 32; off; off >>= 1) acc += __shfl_down(acc, off, 64);
        if (lane == 0) scr2[s] = acc;
      }
      __syncthreads();
      if (w == 0) {
        float v = scr2[lane];
        float mx = v;
#pragma unroll
        for (int off = 32; off; off >>= 1) mx = fmaxf(mx, __shfl_xor(mx, off, 64));
        float e = __expf(v - mx);
        float sm = e;
#pragma unroll
        for (int off = 32; off; off >>= 1) sm += __shfl_xor(sm, off, 64);
        float a = e / sm;
        ST4SC(wsb + ABUF_O + (u32)(b * 64 + lane) * 4, a);
        p.out[AS_OFF + (long)t * 4096 + b * 64 + lane] = a;
      }
    }
    // P4h: h1-half of out-projection (all blocks, 8-way K-split)
    {
      bfrag h0_, h1_, h2_, h3_;
      const char* bp = Hb1cF;
      LD16SC(h0_, bp + ((((w * 4 + 0) * 4 + mtP4) * 64 + lane) << 4));
      LD16SC(h1_, bp + ((((w * 4 + 1) * 4 + mtP4) * 64 + lane) << 4));
      LD16SC(h2_, bp + ((((w * 4 + 2) * 4 + mtP4) * 64 + lane) << 4));
      LD16SC(h3_, bp + ((((w * 4 + 3) * 4 + mtP4) * 64 + lane) << 4));
      TIE4_0(h0_, h1_, h2_, h3_);
      f32x4 a4 = {0.f, 0.f, 0.f, 0.f};
      a4 = mfma16(h0_, waoreg[0], a4);
      a4 = mfma16(h1_, waoreg[1], a4);
      a4 = mfma16(h2_, waoreg[2], a4);
      a4 = mfma16(h3_, waoreg[3], a4);
      scr_store(scr, w, a4);
    }
    barr_arrive(bar, gen);
    // P1(t+1) lookahead part B: second half of h0p(t)
    if (kh_ == 0) gseg<2, true>(accP1, Hb0cF, 8,  mt_, lane, W0, 2560, 56, brow_, ke_);
    else          gseg<2, true>(accP1, Hb0cF, 24, mt_, lane, W0, 2560, 72, brow_, ke_);
    barr_wait(bar, gen); ++gen;

    // ---- P4c: out = tanh(sum_s a_s*CtxO[b,s,:] + h1half); write out + OF frag ----
    {
      u32 av0, av1;
      {
        int b0i = tid >> 6, s0i = tid & 63;
        int b1i = (tid + 512) >> 6, s1i = tid & 63;
        LD4SC(av0, wsb + ABUF_O + (u32)(((mtP4 * 16 + b0i) * 64 + s0i)) * 4);
        LD4SC(av1, wsb + ABUF_O + (u32)(((mtP4 * 16 + b1i) * 64 + s1i)) * 4);
        TIE2_0(av0, av1);
        scr2[tid] = __builtin_bit_cast(float, av0);
        scr2[tid + 512] = __builtin_bit_cast(float, av1);
      }
      __syncthreads();
      const int pair = tid >> 1, half = tid & 1;
      const int m_l = pair >> 4, j_l = pair & 15;
      const int b = mtP4 * 16 + m_l, j = ntP4 * 16 + j_l;
      const u32* cp = (const u32*)(CtxOT + ((long)(b * 1024 + j) * 64 + half * 32));
      const float* al = scr2 + m_l * 64 + half * 32;
      float acc = 0.f;
#pragma unroll
      for (int i = 0; i < 16; ++i) {
        u32 x = cp[i];
        acc += al[2 * i] * bf2f((u16)(x & 0xffff));
        acc += al[2 * i + 1] * bf2f((u16)(x >> 16));
      }
      float v = acc + __shfl_xor(acc, 1, 64);
      if (half == 0) {
        float h1p = 0.f;
#pragma unroll
        for (int q = 0; q < 8; ++q) h1p += scr[q * 272 + m_l * 17 + j_l];
        v = tanh_(v + h1p);
        ST4SC((char*)(p.out + (long)t * 65536 + b * 1024 + j), __builtin_bit_cast(u32, v));
        u32 hv = (u32)f2bf(v);
        ST2SC(wsb + OFF_O + (long)((t + 1) & 1) * 131072 + fragoff(b, j), hv);
      }
    }
    barr_arrive(bar, gen);
    barr_wait(bar, gen); ++gen;
  }

  // ---- epilogue: final states (t=31 -> slot 1; read h from frag) ----
  if (tid < 256) {
    int u = tid >> 6, m = tid & 63, j = bid * 4 + u;
    u32 a0, a1;
    LD2SC(a0, wsb + HB0F_O + 131072 + fragoff(m, j));
    LD2SC(a1, wsb + HB1F_O + 131072 + fragoff(m, j));
    TIE2_0(a0, a1);
    p.out[HT_OFF + (long)m * 1024 + j]         = bf2f((u16)a0);
    p.out[HT_OFF + 65536 + (long)m * 1024 + j] = bf2f((u16)a1);
    p.out[CT_OFF + (long)m * 1024 + j]         = Cst[j * 64 + m];
    p.out[CT_OFF + 65536 + (long)m * 1024 + j] = Cst[65536 + j * 64 + m];
  }

  // ---- deferred copy-attention (blocks 0..63) ----
  if (bid < 64) {
    const int b = bid;
    u16* cw = (u16*)smem;   // reuse W0+W1 region (weights dead)
    __syncthreads();
    {
      const uint4* src = (const uint4*)(CtxWc + (long)b * 65536);
      uint4* dst = (uint4*)cw;
      for (int i = tid; i < 8192; i += 512) dst[i] = src[i];
    }
    __syncthreads();
    float* lds_s = scr;
    for (int t = 0; t < 32; ++t) {
      float ov[16];
      {
        const char* op = (const char*)(p.out + (long)t * 65536 + b * 1024 + lane * 16);
        f32x4 f0, f1, f2, f3;
        LD16SC(f0, op); LD16SC(f1, op + 16); LD16SC(f2, op + 32); LD16SC(f3, op + 48);
        TIE4_0(f0, f1, f2, f3);
#pragma unroll
        for (int i = 0; i < 4; ++i) {
          ov[i]      = f0[i];
          ov[4 + i]  = f1[i];
          ov[8 + i]  = f2[i];
          ov[12 + i] = f3[i];
        }
      }
#pragma unroll
      for (int si = 0; si < 8; ++si) {
        int s = w * 8 + si;
        const u32* u = (const u32*)(cw + s * 1024 + lane * 16);
        float acc = 0.f;
#pragma unroll
        for (int i = 0; i < 8; ++i) {
          u32 x = u[i];
          acc += ov[2 * i] * bf2f((u16)(x & 0xffff));
          acc += ov[2 * i + 1] * bf2f((u16)(x >> 16));
        }
#pragma unroll
        for (int off = 32; off; off >>= 1) acc += __shfl_down(acc, off, 64);
        if (lane == 0) lds_s[s] = acc;
      }
      __syncthreads();
      if (w == 0) {
        float v = lds_s[lane];
        float mx = v;
#pragma unroll
        for (int off = 32; off; off >>= 1) mx = fmaxf(mx, __shfl_xor(mx, off, 64));
        float e = __expf(v - mx);
        float sm = e;
#pragma unroll
        for (int off = 32; off; off >>= 1) sm += __shfl_xor(sm, off, 64);
        p.out[AC_OFF + (long)t * 4096 + b * 64 + lane] = e / sm;
      }
      __syncthreads();
    }
  }
}

// ---------------- host ----------------
extern "C" void kernel_launch(void* const* d_in, const int* in_sizes, int n_in,
                              void* d_out, int out_size, void* d_ws, size_t ws_size,
                              hipStream_t stream) {
  KParams p;
  p.input       = (const int*)d_in[0];
  p.h0          = (const float*)d_in[1];
  p.c0          = (const float*)d_in[2];
  p.context     = (const float*)d_in[3];
  p.init_output = (const float*)d_in[4];
  p.embedding   = (const float*)d_in[5];
  p.W_ih0       = (const float*)d_in[6];
  p.W_hh0       = (const float*)d_in[7];
  p.b0          = (const float*)d_in[8];
  p.W_ih1       = (const float*)d_in[9];
  p.W_hh1       = (const float*)d_in[10];
  p.b1          = (const float*)d_in[11];
  p.attn_in     = (const float*)d_in[12];
  p.attn_out    = (const float*)d_in[13];
  p.copy_in     = (const float*)d_in[14];
  p.out         = (float*)d_out;
  p.ws          = (char*)d_ws;

  (void)hipFuncSetAttribute((const void*)decoder_kernel,
                            hipFuncAttributeMaxDynamicSharedMemorySize, 160256);
  (void)hipMemsetAsync((char*)d_ws + BAR_O, 0, 2048, stream);
  void* args[] = { &p };
  (void)hipLaunchCooperativeKernel((void*)decoder_kernel, dim3(256), dim3(512),
                                   args, 160256, stream);
}

// Round 8
// 1885.148 us; speedup vs baseline: 3.1306x; 1.0976x over previous
//
#include <hip/hip_runtime.h>

typedef unsigned short u16;
typedef unsigned int   u32;
typedef __attribute__((ext_vector_type(8))) __bf16 bfrag;   // 8 bf16 = 4 VGPR
typedef __attribute__((ext_vector_type(4))) float  f32x4;
typedef __attribute__((ext_vector_type(2))) u32    u32x2;

#define DEVI static __device__ __forceinline__

// ---- sc0sc1 STORES (write-through to LLC). Loads are normal cached loads;
// ---- coherence = sc store + buffer_inv (acquire fence) at each grid barrier.
#define ST4SC(p, v)    asm volatile("global_store_dword %0, %1, off sc0 sc1"  :: "v"(p), "v"(v) : "memory")
#define ST2SC(p, v)    asm volatile("global_store_short %0, %1, off sc0 sc1"  :: "v"(p), "v"(v) : "memory")
#define ST8SC(p, v)    asm volatile("global_store_dwordx2 %0, %1, off sc0 sc1" :: "v"(p), "v"(v) : "memory")
#define VMFLUSH()      asm volatile("s_waitcnt vmcnt(0)" ::: "memory")

// ---------------- geometry ----------------
// T=32 B=64 S=64 E=512 H=1024 L=2 (4H=4096)
constexpr long OUT_OFF = 0;         // 32*64*1024
constexpr long HT_OFF  = 2097152;
constexpr long CT_OFF  = 2228224;
constexpr long AS_OFF  = 2359296;
constexpr long AC_OFF  = 2490368;

// ---------------- workspace layout (bytes) ----------------
constexpr long WAO_O   = 0;                   // attn_out_w bf16 [1024][2048] (4MB)
constexpr long WAI_O   = 4194304;             // attn_in_w^T bf16 (2MB)
constexpr long WC_O    = 6291456;             // copy_in_w^T bf16 (2MB)
constexpr long CTX_O   = 8388608;             // ctx (b,s,k) bf16 (8MB)
constexpr long CTXW_O  = 16777216;            // ctx @ Wai   bf16 [(b,s)][j] (8MB)
constexpr long CTXWC_O = 25165824;            // ctx @ Wc    bf16 (8MB)
constexpr long CTXOT_O = 33554432;            // (ctx @ Waoc)^T bf16 [b][j][s] (8MB)
constexpr long EBF_O   = 41943040;            // emb frag-major [t][16kk][4mt][64][8] (2MB)
constexpr long OFF_O   = 44040192;            // out-feed frag [2][131072B]
constexpr long HB0F_O  = 44302336;            // h0 frag [2]
constexpr long HB1F_O  = 44564480;            // h1 frag [2]
constexpr long ABUF_O  = 45875200;            // a f32 [64][64] (16KB)
constexpr long BAR_O   = 45891584;            // flags[256]

// LDS layout (dynamic, 160256 B)
constexpr int W0LDS_O = 0;        // [16 rows][2560] bf16 swizzled = 81920
constexpr int W1LDS_O = 81920;    // [16 rows][2048] bf16 swizzled = 65536
constexpr int SCR_O   = 147456;   // 8 slots x 272 f32 = 8704
constexpr int SCR2_O  = 156160;   // 4096 B (softmax scratch / a-stage)

struct KParams {
  const int* input; const float* h0; const float* c0; const float* context;
  const float* init_output; const float* embedding;
  const float* W_ih0; const float* W_hh0; const float* b0;
  const float* W_ih1; const float* W_hh1; const float* b1;
  const float* attn_in; const float* attn_out; const float* copy_in;
  float* out; char* ws;
};

// ---------------- small helpers ----------------
DEVI float bf2f(u16 u) { u32 x = ((u32)u) << 16; return __builtin_bit_cast(float, x); }
DEVI u16 f2bf(float f) {
  u32 x = __builtin_bit_cast(u32, f);
  u32 r = x + 0x7fffu + ((x >> 16) & 1u);   // RNE
  return (u16)(r >> 16);
}
DEVI void cvtc(const float* s, u16* d) {
  float4 v = *(const float4*)s;
  uint2 u;
  u.x = (u32)f2bf(v.x) | ((u32)f2bf(v.y) << 16);
  u.y = (u32)f2bf(v.z) | ((u32)f2bf(v.w) << 16);
  *(uint2*)d = u;
}
DEVI float sigm(float x)  { return 1.f / (1.f + __expf(-x)); }
DEVI float tanh_(float x) { return 1.f - 2.f / (__expf(2.f * x) + 1.f); }
DEVI f32x4 mfma16(bfrag a, bfrag b, f32x4 c) {
  return __builtin_amdgcn_mfma_f32_16x16x32_bf16(a, b, c, 0, 0, 0);
}
// frag-major byte offset for element (m,k) of a [64 m][K k] activation
DEVI u32 fragoff(int m, int k) {
  return (u32)((((k >> 5) * 4 + (m >> 4)) * 64 + ((k >> 3) & 3) * 16 + (m & 15)) * 16 + (k & 7) * 2);
}

// ---------------- barriers (split arrive/wait; wait does acquire-inv) ----------------
DEVI void pollflags(u32* flags, u32 gen) {
  int t = threadIdx.x;   // < 64
  for (;;) {
    u32 a = __hip_atomic_load(&flags[t],       __ATOMIC_RELAXED, __HIP_MEMORY_SCOPE_AGENT);
    u32 b = __hip_atomic_load(&flags[64 + t],  __ATOMIC_RELAXED, __HIP_MEMORY_SCOPE_AGENT);
    u32 c = __hip_atomic_load(&flags[128 + t], __ATOMIC_RELAXED, __HIP_MEMORY_SCOPE_AGENT);
    u32 d = __hip_atomic_load(&flags[192 + t], __ATOMIC_RELAXED, __HIP_MEMORY_SCOPE_AGENT);
    if (__all((a >= gen) && (b >= gen) && (c >= gen) && (d >= gen))) break;
    __builtin_amdgcn_s_sleep(1);
  }
}
DEVI void barr_arrive(u32* flags, u32 gen) {
  VMFLUSH();               // drain sc stores to LLC before signaling
  __syncthreads();
  if (threadIdx.x == 0)
    __hip_atomic_store(&flags[blockIdx.x], gen, __ATOMIC_RELAXED, __HIP_MEMORY_SCOPE_AGENT);
}
DEVI void barr_wait(u32* flags, u32 gen) {
  if (threadIdx.x < 64) pollflags(flags, gen);
  __syncthreads();
  if (threadIdx.x == 0)
    __builtin_amdgcn_fence(__ATOMIC_ACQUIRE, "agent");   // buffer_inv: drop stale L1/L2
  __syncthreads();
  asm volatile("" ::: "memory");
}
// fenced barrier (setup only)
DEVI void gsync_fence(u32* flags, u32 gen) {
  __syncthreads();
  if (threadIdx.x == 0) {
    __builtin_amdgcn_fence(__ATOMIC_RELEASE, "agent");
    __hip_atomic_store(&flags[blockIdx.x], gen, __ATOMIC_RELAXED, __HIP_MEMORY_SCOPE_AGENT);
  }
  if (threadIdx.x < 64) pollflags(flags, gen);
  if (threadIdx.x == 0) __builtin_amdgcn_fence(__ATOMIC_ACQUIRE, "agent");
  __syncthreads();
}

// ---------------- gate-GEMM segment: normal cached loads, compiler-pipelined ----------------
template<int N4>
DEVI void gseg(f32x4& acc, const char* Af, int kkA0, int mt, int lane,
               const char* W, int wRowK, int kkW0, int brow, int ke) {
  const u32 sw = (u32)((brow & 7) << 4);
#pragma unroll
  for (int g = 0; g < N4; ++g) {
#pragma unroll
    for (int q = 0; q < 4; ++q) {
      const char* pa = Af + ((((kkA0 + g * 4 + q) * 4 + mt) * 64 + lane) << 4);
      bfrag av = *(const bfrag*)pa;
      int kkW = kkW0 + g * 4 + q;
      u32 off = ((u32)(brow * wRowK + kkW * 32 + ke) * 2) ^ sw;
      acc = mfma16(av, *(const bfrag*)(W + off), acc);
    }
  }
}

DEVI void scr_store(float* scr, int slot, f32x4 acc) {
  const int lane = threadIdx.x & 63;
#pragma unroll
  for (int r = 0; r < 4; ++r)
    scr[slot * 272 + ((lane >> 4) * 4 + r) * 17 + (lane & 15)] = acc[r];
}

// LSTM pointwise: threads 0..63; c-state lives in registers (cst[4]); one 8B sc h-store
DEVI void pointwise64(int bid, const float* scr, const float* bias, float (&cst)[4], char* hfrag) {
  const int m = threadIdx.x;            // < 64
  const int mt = m >> 4, ml = m & 15;
  u32 hp0 = 0, hp1 = 0;
#pragma unroll
  for (int u = 0; u < 4; ++u) {
    const int j = bid * 4 + u;
    float g0 = scr[(mt*2)*272 + ml*17 + u]      + scr[(mt*2+1)*272 + ml*17 + u]      + bias[j];
    float g1 = scr[(mt*2)*272 + ml*17 + 4 + u]  + scr[(mt*2+1)*272 + ml*17 + 4 + u]  + bias[1024 + j];
    float g2 = scr[(mt*2)*272 + ml*17 + 8 + u]  + scr[(mt*2+1)*272 + ml*17 + 8 + u]  + bias[2048 + j];
    float g3 = scr[(mt*2)*272 + ml*17 + 12 + u] + scr[(mt*2+1)*272 + ml*17 + 12 + u] + bias[3072 + j];
    float cn = sigm(g1) * cst[u] + sigm(g0) * tanh_(g2);
    cst[u] = cn;
    u32 hb = (u32)f2bf(sigm(g3) * tanh_(cn));
    if (u == 0) hp0 = hb; else if (u == 1) hp0 |= hb << 16;
    else if (u == 2) hp1 = hb; else hp1 |= hb << 16;
  }
  u32x2 v; v[0] = hp0; v[1] = hp1;
  ST8SC(hfrag + fragoff(m, bid * 4), v);
}

// setup GEMM: dst[(b,s)][j] = ctx[(b,s),:] . Wrow[j,:]
DEVI void ctxw_gemm(int mt, const u16* Ctx, const u16* Wm, u16* dst) {
  const int tid = threadIdx.x, lane = tid & 63, w = tid >> 6;
  const int arow = mt * 16 + (lane & 15);
  const int ke = (lane >> 4) * 8;
#pragma unroll
  for (int i = 0; i < 8; ++i) {
    int nt = w * 8 + i;
    const u16* A = Ctx + (long)arow * 1024 + ke;
    const u16* B = Wm + (long)(nt * 16 + (lane & 15)) * 1024 + ke;
    f32x4 acc = {0.f, 0.f, 0.f, 0.f};
    for (int kk = 0; kk < 1024; kk += 32)
      acc = mfma16(*(const bfrag*)(A + kk), *(const bfrag*)(B + kk), acc);
#pragma unroll
    for (int r = 0; r < 4; ++r)
      dst[(long)(mt * 16 + (lane >> 4) * 4 + r) * 1024 + nt * 16 + (lane & 15)] = f2bf(acc[r]);
  }
}

// setup GEMM: CtxOT[b][j][s] = ctx[(b,s),:] . Wao[j, 0..1024]
DEVI void ctxo_gemm(int bid, const u16* Ctx, const u16* Wao, u16* dst) {
  const int tid = threadIdx.x, lane = tid & 63, w = tid >> 6;
  const int arow = bid * 16 + (lane & 15);
  const int ke = (lane >> 4) * 8;
  const int b = bid >> 2, s0 = (bid & 3) * 16 + (lane >> 4) * 4;
#pragma unroll
  for (int i = 0; i < 8; ++i) {
    int nt = w * 8 + i;
    int j = nt * 16 + (lane & 15);
    const u16* A = Ctx + (long)arow * 1024 + ke;
    const u16* B = Wao + (long)j * 2048 + ke;
    f32x4 acc = {0.f, 0.f, 0.f, 0.f};
    for (int kk = 0; kk < 1024; kk += 32)
      acc = mfma16(*(const bfrag*)(A + kk), *(const bfrag*)(B + kk), acc);
    uint2 q;
    q.x = (u32)f2bf(acc[0]) | ((u32)f2bf(acc[1]) << 16);
    q.y = (u32)f2bf(acc[2]) | ((u32)f2bf(acc[3]) << 16);
    *(uint2*)(dst + ((long)(b * 1024 + j) * 64 + s0)) = q;
  }
}

// ---------------- the kernel ----------------
__global__ __launch_bounds__(512, 1) void decoder_kernel(KParams p) {
  extern __shared__ char smem[];
  char*  W0   = smem + W0LDS_O;
  char*  W1   = smem + W1LDS_O;
  float* scr  = (float*)(smem + SCR_O);
  float* scr2 = (float*)(smem + SCR2_O);

  char* wsb = p.ws;
  u16* Wao   = (u16*)(wsb + WAO_O);
  u16* Wai   = (u16*)(wsb + WAI_O);
  u16* Wc    = (u16*)(wsb + WC_O);
  u16* Ctx   = (u16*)(wsb + CTX_O);
  u16* CtxW  = (u16*)(wsb + CTXW_O);
  u16* CtxWc = (u16*)(wsb + CTXWC_O);
  u16* CtxOT = (u16*)(wsb + CTXOT_O);
  u32* bar   = (u32*)(wsb + BAR_O);

  const int bid = blockIdx.x, tid = threadIdx.x;
  const int lane = tid & 63, w = tid >> 6;
  const long gtid = (long)bid * 512 + tid, NT = 256l * 512;
  u32 gen = 1;

  // ---- S0-pre: LDS-tiled transposes of attn_in / copy_in ----
  {
    float* tile = (float*)smem;
    for (int pass = 0; pass < 2; ++pass) {
      const float* src = pass ? p.copy_in : p.attn_in;
      u16* dst = pass ? Wc : Wai;
      int tr = bid >> 4, tc = bid & 15;
      {
        int r = tid >> 3, c = (tid & 7) * 8;
        const float4* s4 = (const float4*)(src + (long)(tr * 64 + r) * 1024 + tc * 64 + c);
        float4 a = s4[0], b = s4[1];
        float* tp = tile + r * 69 + c;
        tp[0] = a.x; tp[1] = a.y; tp[2] = a.z; tp[3] = a.w;
        tp[4] = b.x; tp[5] = b.y; tp[6] = b.z; tp[7] = b.w;
      }
      __syncthreads();
      {
        int r2 = tid >> 3, c2 = (tid & 7) * 8;
        u32 q[4];
#pragma unroll
        for (int i = 0; i < 4; ++i) {
          float lo = tile[(c2 + 2 * i) * 69 + r2];
          float hi = tile[(c2 + 2 * i + 1) * 69 + r2];
          q[i] = (u32)f2bf(lo) | ((u32)f2bf(hi) << 16);
        }
        *(uint4*)(dst + (long)(tc * 64 + r2) * 1024 + tr * 64 + c2) = *(uint4*)q;
      }
      __syncthreads();
    }
  }

  // ---- S0a: per-block weight slices -> LDS (stationary all 32 steps) ----
  for (int i = tid; i < 5120; i += 512) {
    int row = i / 320, k = (i % 320) * 8;
    int R = (row >> 2) * 1024 + bid * 4 + (row & 3);
    const float* src = (k < 1536) ? (p.W_ih0 + (long)R * 1536 + k)
                                  : (p.W_hh0 + (long)R * 1024 + (k - 1536));
    float4 a = *(const float4*)src, b = *(const float4*)(src + 4);
    uint4 q;
    q.x = (u32)f2bf(a.x) | ((u32)f2bf(a.y) << 16);
    q.y = (u32)f2bf(a.z) | ((u32)f2bf(a.w) << 16);
    q.z = (u32)f2bf(b.x) | ((u32)f2bf(b.y) << 16);
    q.w = (u32)f2bf(b.z) | ((u32)f2bf(b.w) << 16);
    u32 off = ((u32)(row * 2560 + k) * 2) ^ ((u32)((row & 7) << 4));
    *(uint4*)(W0 + off) = q;
  }
  for (int i = tid; i < 4096; i += 512) {
    int row = i / 256, k = (i % 256) * 8;
    int R = (row >> 2) * 1024 + bid * 4 + (row & 3);
    const float* src = (k < 1024) ? (p.W_ih1 + (long)R * 1024 + k)
                                  : (p.W_hh1 + (long)R * 1024 + (k - 1024));
    float4 a = *(const float4*)src, b = *(const float4*)(src + 4);
    uint4 q;
    q.x = (u32)f2bf(a.x) | ((u32)f2bf(a.y) << 16);
    q.y = (u32)f2bf(a.z) | ((u32)f2bf(a.w) << 16);
    q.z = (u32)f2bf(b.x) | ((u32)f2bf(b.y) << 16);
    q.w = (u32)f2bf(b.z) | ((u32)f2bf(b.w) << 16);
    u32 off = ((u32)(row * 2048 + k) * 2) ^ ((u32)((row & 7) << 4));
    *(uint4*)(W1 + off) = q;
  }

  // ---- S0b: global conversions ----
  for (long i = gtid; i < 524288; i += NT) cvtc(p.attn_out + i * 4, Wao + i * 4);
  for (long i = gtid; i < 1048576; i += NT) {
    long b = i >> 14, s = (i >> 8) & 63, kq = i & 255;
    cvtc(p.context + ((s * 64 + b) * 1024 + kq * 4), Ctx + i * 4);
  }
  for (long i = gtid; i < 262144; i += NT) {     // emb gather -> frag-major
    long row = i >> 7; long t = row >> 6, b = row & 63;
    long k0 = (i & 127) * 4;
    long tok = p.input[row];
    cvtc(p.embedding + tok * 512 + k0,
         (u16*)(wsb + EBF_O + t * 65536 + fragoff((int)b, (int)k0)));
  }
  for (long i = gtid; i < 16384; i += NT) {      // init_output -> OF frag slot 0
    long b = i >> 8, k0 = (i & 255) * 4;
    cvtc(p.init_output + i * 4, (u16*)(wsb + OFF_O + fragoff((int)b, (int)k0)));
  }
  for (long i = gtid; i < 32768; i += NT) {      // h0 -> frag slot 1 (prev at t=0)
    long l = i >> 14, rem = i & 16383, b = rem >> 8, k0 = (rem & 255) * 4;
    cvtc(p.h0 + i * 4,
         (u16*)(wsb + (l ? HB1F_O : HB0F_O) + 131072 + fragoff((int)b, (int)k0)));
  }

  // ---- c-state -> registers (threads 0..63; thread m owns (m, j=bid*4+u)) ----
  float cR0[4] = {0.f, 0.f, 0.f, 0.f}, cR1[4] = {0.f, 0.f, 0.f, 0.f};
  if (tid < 64) {
#pragma unroll
    for (int u = 0; u < 4; ++u) {
      cR0[u] = p.c0[(long)tid * 1024 + bid * 4 + u];
      cR1[u] = p.c0[65536 + (long)tid * 1024 + bid * 4 + u];
    }
  }

  gsync_fence(bar, gen); ++gen;

  // ---- S1: attention tables ----
  ctxw_gemm(bid, Ctx, Wai, CtxW);
  ctxw_gemm(bid, Ctx, Wc, CtxWc);
  ctxo_gemm(bid, Ctx, Wao, CtxOT);
  gsync_fence(bar, gen); ++gen;

  // ---- P4 geometry (XCD-pinned) + Wao h1-half fragments in registers ----
  const int xcd = bid & 7, idx = bid >> 3;
  const int ntP4 = xcd * 8 + (idx & 7), mtP4 = idx >> 3;
  const int browP4 = ntP4 * 16 + (lane & 15);
  const int ke_ = (lane >> 4) * 8;
  bfrag waoreg[4];
#pragma unroll
  for (int q = 0; q < 4; ++q)
    waoreg[q] = *(const bfrag*)(Wao + (long)browP4 * 2048 + 1024 + (w * 4 + q) * 32 + ke_);

  const int mt_ = w & 3, kh_ = w >> 2;
  const int brow_ = lane & 15;

  // ---- pre-loop P1(0) lookahead: emb(0) + h0prev(slot1) ----
  f32x4 accP1 = {0.f, 0.f, 0.f, 0.f}, accP2;
  {
    const char* E0  = wsb + EBF_O;
    const char* H0p = wsb + HB0F_O + 131072;
    if (kh_ == 0) {
      gseg<2>(accP1, E0,  0,  mt_, lane, W0, 2560, 0,  brow_, ke_);
      gseg<4>(accP1, H0p, 0,  mt_, lane, W0, 2560, 48, brow_, ke_);
    } else {
      gseg<2>(accP1, E0,  8,  mt_, lane, W0, 2560, 8,  brow_, ke_);
      gseg<4>(accP1, H0p, 16, mt_, lane, W0, 2560, 64, brow_, ke_);
    }
  }

  for (int t = 0; t < 32; ++t) {
    const int cur = t & 1, prev = cur ^ 1;
    const char* OFc   = wsb + OFF_O  + (long)cur  * 131072;
    char*       Hb0cF = wsb + HB0F_O + (long)cur  * 131072;
    char*       Hb1cF = wsb + HB1F_O + (long)cur  * 131072;
    const char* Hb1pF = wsb + HB1F_O + (long)prev * 131072;

    // ---- P1 remainder: out-feed segment (OF(t) fresh after last barrier) ----
    {
      f32x4 acc = accP1;
      if (kh_ == 0) gseg<4>(acc, OFc, 0,  mt_, lane, W0, 2560, 16, brow_, ke_);
      else          gseg<4>(acc, OFc, 16, mt_, lane, W0, 2560, 32, brow_, ke_);
      scr_store(scr, mt_ * 2 + kh_, acc);
      __syncthreads();
      if (tid < 64) pointwise64(bid, scr, p.b0, cR0, Hb0cF);
    }
    barr_arrive(bar, gen);
    // P2 lookahead: h1prev segment (h1(t-1), stable since last step)
    accP2 = f32x4{0.f, 0.f, 0.f, 0.f};
    if (kh_ == 0) gseg<4>(accP2, Hb1pF, 0,  mt_, lane, W1, 2048, 32, brow_, ke_);
    else          gseg<4>(accP2, Hb1pF, 16, mt_, lane, W1, 2048, 48, brow_, ke_);
    barr_wait(bar, gen); ++gen;

    // ---- P2 remainder: h0new segment ----
    {
      f32x4 acc = accP2;
      if (kh_ == 0) gseg<4>(acc, Hb0cF, 0,  mt_, lane, W1, 2048, 0,  brow_, ke_);
      else          gseg<4>(acc, Hb0cF, 16, mt_, lane, W1, 2048, 16, brow_, ke_);
      scr_store(scr, mt_ * 2 + kh_, acc);
      __syncthreads();
      if (tid < 64) pointwise64(bid, scr, p.b1, cR1, Hb1cF);
    }
    barr_arrive(bar, gen);
    // P1(t+1) lookahead part A: emb(t+1) + first half of h0p(t)
    accP1 = f32x4{0.f, 0.f, 0.f, 0.f};
    {
      const char* En = wsb + EBF_O + (long)((t + 1) & 31) * 65536;
      if (kh_ == 0) {
        gseg<2>(accP1, En,    0,  mt_, lane, W0, 2560, 0,  brow_, ke_);
        gseg<2>(accP1, Hb0cF, 0,  mt_, lane, W0, 2560, 48, brow_, ke_);
      } else {
        gseg<2>(accP1, En,    8,  mt_, lane, W0, 2560, 8,  brow_, ke_);
        gseg<2>(accP1, Hb0cF, 16, mt_, lane, W0, 2560, 64, brow_, ke_);
      }
    }
    barr_wait(bar, gen); ++gen;

    // ---- P3 (blocks 0..63): scores + softmax -> a; all blocks: P4h ----
    if (bid < 64) {
      const int b = bid;
      float h1v[16];
      {
        int k0 = lane * 16;
        const u32* hp0 = (const u32*)(Hb1cF + fragoff(b, k0));
        const u32* hp1 = (const u32*)(Hb1cF + fragoff(b, k0 + 8));
        u32 uu[8] = {hp0[0], hp0[1], hp0[2], hp0[3], hp1[0], hp1[1], hp1[2], hp1[3]};
#pragma unroll
        for (int i = 0; i < 8; ++i) {
          h1v[2 * i]     = bf2f((u16)(uu[i] & 0xffff));
          h1v[2 * i + 1] = bf2f((u16)(uu[i] >> 16));
        }
      }
      const u16* cwb = CtxW + (long)b * 65536;
#pragma unroll
      for (int si = 0; si < 8; ++si) {
        int s = w * 8 + si;
        const u32* u = (const u32*)(cwb + (long)s * 1024 + lane * 16);
        float acc = 0.f;
#pragma unroll
        for (int i = 0; i < 8; ++i) {
          u32 x = u[i];
          acc += h1v[2 * i] * bf2f((u16)(x & 0xffff));
          acc += h1v[2 * i + 1] * bf2f((u16)(x >> 16));
        }
#pragma unroll
        for (int off = 32; off; off >>= 1) acc += __shfl_down(acc, off, 64);
        if (lane == 0) scr2[s] = acc;
      }
      __syncthreads();
      if (w == 0) {
        float v = scr2[lane];
        float mx = v;
#pragma unroll
        for (int off = 32; off; off >>= 1) mx = fmaxf(mx, __shfl_xor(mx, off, 64));
        float e = __expf(v - mx);
        float sm = e;
#pragma unroll
        for (int off = 32; off; off >>= 1) sm += __shfl_xor(sm, off, 64);
        float a = e / sm;
        ST4SC(wsb + ABUF_O + (u32)(b * 64 + lane) * 4, __builtin_bit_cast(u32, a));
        ST4SC((char*)(p.out + AS_OFF + (long)t * 4096 + b * 64 + lane), __builtin_bit_cast(u32, a));
      }
    }
    // P4h: h1-half of out-projection (all blocks, 8-way K-split)
    {
      const char* bp = Hb1cF;
      bfrag h0_ = *(const bfrag*)(bp + ((((w * 4 + 0) * 4 + mtP4) * 64 + lane) << 4));
      bfrag h1_ = *(const bfrag*)(bp + ((((w * 4 + 1) * 4 + mtP4) * 64 + lane) << 4));
      bfrag h2_ = *(const bfrag*)(bp + ((((w * 4 + 2) * 4 + mtP4) * 64 + lane) << 4));
      bfrag h3_ = *(const bfrag*)(bp + ((((w * 4 + 3) * 4 + mtP4) * 64 + lane) << 4));
      f32x4 a4 = {0.f, 0.f, 0.f, 0.f};
      a4 = mfma16(h0_, waoreg[0], a4);
      a4 = mfma16(h1_, waoreg[1], a4);
      a4 = mfma16(h2_, waoreg[2], a4);
      a4 = mfma16(h3_, waoreg[3], a4);
      scr_store(scr, w, a4);
    }
    barr_arrive(bar, gen);
    // P1(t+1) lookahead part B: second half of h0p(t)
    if (kh_ == 0) gseg<2>(accP1, Hb0cF, 8,  mt_, lane, W0, 2560, 56, brow_, ke_);
    else          gseg<2>(accP1, Hb0cF, 24, mt_, lane, W0, 2560, 72, brow_, ke_);
    barr_wait(bar, gen); ++gen;

    // ---- P4c: out = tanh(sum_s a_s*CtxO[b,s,:] + h1half); write out + OF frag ----
    {
      {
        int b0i = tid >> 6, s0i = tid & 63;
        int b1i = (tid + 512) >> 6;
        scr2[tid]       = *(const float*)(wsb + ABUF_O + (u32)(((mtP4 * 16 + b0i) * 64 + s0i)) * 4);
        scr2[tid + 512] = *(const float*)(wsb + ABUF_O + (u32)(((mtP4 * 16 + b1i) * 64 + s0i)) * 4);
      }
      __syncthreads();
      const int pair = tid >> 1, half = tid & 1;
      const int m_l = pair >> 4, j_l = pair & 15;
      const int b = mtP4 * 16 + m_l, j = ntP4 * 16 + j_l;
      const u32* cp = (const u32*)(CtxOT + ((long)(b * 1024 + j) * 64 + half * 32));
      const float* al = scr2 + m_l * 64 + half * 32;
      float acc = 0.f;
#pragma unroll
      for (int i = 0; i < 16; ++i) {
        u32 x = cp[i];
        acc += al[2 * i] * bf2f((u16)(x & 0xffff));
        acc += al[2 * i + 1] * bf2f((u16)(x >> 16));
      }
      float v = acc + __shfl_xor(acc, 1, 64);
      if (half == 0) {
        float h1p = 0.f;
#pragma unroll
        for (int q = 0; q < 8; ++q) h1p += scr[q * 272 + m_l * 17 + j_l];
        v = tanh_(v + h1p);
        ST4SC((char*)(p.out + (long)t * 65536 + b * 1024 + j), __builtin_bit_cast(u32, v));
        u32 hv = (u32)f2bf(v);
        ST2SC(wsb + OFF_O + (long)((t + 1) & 1) * 131072 + fragoff(b, j), hv);
      }
    }
    barr_arrive(bar, gen);
    barr_wait(bar, gen); ++gen;
  }

  // ---- epilogue: final states (t=31 -> slot 1; h from frag, c from registers) ----
  if (tid < 64) {
#pragma unroll
    for (int u = 0; u < 4; ++u) {
      int j = bid * 4 + u;
      p.out[CT_OFF + (long)tid * 1024 + j]         = cR0[u];
      p.out[CT_OFF + 65536 + (long)tid * 1024 + j] = cR1[u];
    }
  }
  if (tid < 256) {
    int u = tid >> 6, m = tid & 63, j = bid * 4 + u;
    u16 a0 = *(const u16*)(wsb + HB0F_O + 131072 + fragoff(m, j));
    u16 a1 = *(const u16*)(wsb + HB1F_O + 131072 + fragoff(m, j));
    p.out[HT_OFF + (long)m * 1024 + j]         = bf2f(a0);
    p.out[HT_OFF + 65536 + (long)m * 1024 + j] = bf2f(a1);
  }

  // ---- deferred copy-attention (blocks 0..63) ----
  if (bid < 64) {
    const int b = bid;
    u16* cw = (u16*)smem;   // reuse W0+W1 region (weights dead)
    __syncthreads();
    {
      const uint4* src = (const uint4*)(CtxWc + (long)b * 65536);
      uint4* dst = (uint4*)cw;
      for (int i = tid; i < 8192; i += 512) dst[i] = src[i];
    }
    __syncthreads();
    float* lds_s = scr;
    for (int t = 0; t < 32; ++t) {
      float ov[16];
      {
        const float4* op = (const float4*)(p.out + (long)t * 65536 + b * 1024 + lane * 16);
#pragma unroll
        for (int i = 0; i < 4; ++i) {
          float4 v = op[i];
          ov[4 * i] = v.x; ov[4 * i + 1] = v.y; ov[4 * i + 2] = v.z; ov[4 * i + 3] = v.w;
        }
      }
#pragma unroll
      for (int si = 0; si < 8; ++si) {
        int s = w * 8 + si;
        const u32* u = (const u32*)(cw + s * 1024 + lane * 16);
        float acc = 0.f;
#pragma unroll
        for (int i = 0; i < 8; ++i) {
          u32 x = u[i];
          acc += ov[2 * i] * bf2f((u16)(x & 0xffff));
          acc += ov[2 * i + 1] * bf2f((u16)(x >> 16));
        }
#pragma unroll
        for (int off = 32; off; off >>= 1) acc += __shfl_down(acc, off, 64);
        if (lane == 0) lds_s[s] = acc;
      }
      __syncthreads();
      if (w == 0) {
        float v = lds_s[lane];
        float mx = v;
#pragma unroll
        for (int off = 32; off; off >>= 1) mx = fmaxf(mx, __shfl_xor(mx, off, 64));
        float e = __expf(v - mx);
        float sm = e;
#pragma unroll
        for (int off = 32; off; off >>= 1) sm += __shfl_xor(sm, off, 64);
        p.out[AC_OFF + (long)t * 4096 + b * 64 + lane] = e / sm;
      }
      __syncthreads();
    }
  }
}

// ---------------- host ----------------
extern "C" void kernel_launch(void* const* d_in, const int* in_sizes, int n_in,
                              void* d_out, int out_size, void* d_ws, size_t ws_size,
                              hipStream_t stream) {
  KParams p;
  p.input       = (const int*)d_in[0];
  p.h0          = (const float*)d_in[1];
  p.c0          = (const float*)d_in[2];
  p.context     = (const float*)d_in[3];
  p.init_output = (const float*)d_in[4];
  p.embedding   = (const float*)d_in[5];
  p.W_ih0       = (const float*)d_in[6];
  p.W_hh0       = (const float*)d_in[7];
  p.b0          = (const float*)d_in[8];
  p.W_ih1       = (const float*)d_in[9];
  p.W_hh1       = (const float*)d_in[10];
  p.b1          = (const float*)d_in[11];
  p.attn_in     = (const float*)d_in[12];
  p.attn_out    = (const float*)d_in[13];
  p.copy_in     = (const float*)d_in[14];
  p.out         = (float*)d_out;
  p.ws          = (char*)d_ws;

  (void)hipFuncSetAttribute((const void*)decoder_kernel,
                            hipFuncAttributeMaxDynamicSharedMemorySize, 160256);
  (void)hipMemsetAsync((char*)d_ws + BAR_O, 0, 2048, stream);
  void* args[] = { &p };
  (void)hipLaunchCooperativeKernel((void*)decoder_kernel, dim3(256), dim3(512),
                                   args, 160256, stream);
}

// Round 9
// 1678.805 us; speedup vs baseline: 3.5154x; 1.1229x over previous
//
#include <hip/hip_runtime.h>

typedef unsigned short u16;
typedef unsigned int   u32;
typedef __attribute__((ext_vector_type(8))) __bf16 bfrag;   // 8 bf16 = 4 VGPR
typedef __attribute__((ext_vector_type(4))) float  f32x4;
typedef __attribute__((ext_vector_type(2))) u32    u32x2;
typedef __attribute__((ext_vector_type(4))) u32    u32x4;

#define DEVI static __device__ __forceinline__

// ---- ALL cross-visible global writes are sc0sc1 (write-through to LLC).
// ---- ALL reads are plain cached loads. Correctness: no global address is
// ---- written-after-cached-read within a launch (per-step slot rotation),
// ---- so no fences / cache invalidations are needed anywhere.
#define ST2SC(p, v)    asm volatile("global_store_short %0, %1, off sc0 sc1"   :: "v"(p), "v"(v) : "memory")
#define ST4SC(p, v)    asm volatile("global_store_dword %0, %1, off sc0 sc1"   :: "v"(p), "v"(v) : "memory")
#define ST8SC(p, v)    asm volatile("global_store_dwordx2 %0, %1, off sc0 sc1" :: "v"(p), "v"(v) : "memory")
#define ST16SC(p, v)   asm volatile("global_store_dwordx4 %0, %1, off sc0 sc1" :: "v"(p), "v"(v) : "memory")
#define VMFLUSH()      asm volatile("s_waitcnt vmcnt(0)" ::: "memory")

// ---------------- geometry ----------------
// T=32 B=64 S=64 E=512 H=1024 L=2 (4H=4096)
constexpr long OUT_OFF = 0;         // 32*64*1024
constexpr long HT_OFF  = 2097152;
constexpr long CT_OFF  = 2228224;
constexpr long AS_OFF  = 2359296;
constexpr long AC_OFF  = 2490368;

// ---------------- workspace layout (bytes) ----------------
// WAO dead after prologue (waoreg);  CTX dead after S1  ->  overlaid by slots.
constexpr long WAO_O   = 0;          // attn_out bf16 [1024][2048] (4MB)
constexpr long CTX_O   = 4194304;    // ctx (b,s,k) bf16 (8MB)
constexpr long OFR_O   = 0;          // OF slots 1..32  [0, 4MB)
constexpr long H0R_O   = 4194304;    // H0 slots 1..32  [4MB, 8MB)
constexpr long H1R_O   = 8388608;    // H1 slots 1..32  [8MB, 12MB)
constexpr long WAI_O   = 12582912;   // attn_in^T bf16 (2MB)
constexpr long WC_O    = 14680064;   // copy_in^T bf16 (2MB)
constexpr long CTXW_O  = 16777216;   // ctx @ Wai (8MB)
constexpr long CTXWC_O = 25165824;   // ctx @ Wc  (8MB)
constexpr long CTXOT_O = 33554432;   // (ctx @ Waoc)^T [b][j][s] (8MB)
constexpr long EBF_O   = 41943040;   // emb frag-major [t][...] (2MB)
constexpr long OF0_O   = 44040192;   // OF slot 0 (128KB)
constexpr long H00_O   = 44171264;   // H0 slot 0
constexpr long H10_O   = 44302336;   // H1 slot 0
constexpr long AB_O    = 44433408;   // a f32 [32 t][64 b][64 s]... 32*16KB = 512KB
constexpr long BAR_O   = 44957696;   // flags[256]

// LDS layout (dynamic, 160256 B)
constexpr int W0LDS_O = 0;        // [16 rows][2560] bf16 swizzled = 81920
constexpr int W1LDS_O = 81920;    // [16 rows][2048] bf16 swizzled = 65536
constexpr int SCR_O   = 147456;   // 8 slots x 272 f32 = 8704
constexpr int SCR2_O  = 156160;   // 4096 B

struct KParams {
  const int* input; const float* h0; const float* c0; const float* context;
  const float* init_output; const float* embedding;
  const float* W_ih0; const float* W_hh0; const float* b0;
  const float* W_ih1; const float* W_hh1; const float* b1;
  const float* attn_in; const float* attn_out; const float* copy_in;
  float* out; char* ws;
};

// ---------------- small helpers ----------------
DEVI float bf2f(u16 u) { u32 x = ((u32)u) << 16; return __builtin_bit_cast(float, x); }
DEVI u16 f2bf(float f) {
  u32 x = __builtin_bit_cast(u32, f);
  u32 r = x + 0x7fffu + ((x >> 16) & 1u);   // RNE
  return (u16)(r >> 16);
}
DEVI void cvtc_sc(const float* s, char* d) {   // 4 f32 -> 4 bf16, sc store
  float4 v = *(const float4*)s;
  u32x2 u;
  u[0] = (u32)f2bf(v.x) | ((u32)f2bf(v.y) << 16);
  u[1] = (u32)f2bf(v.z) | ((u32)f2bf(v.w) << 16);
  ST8SC(d, u);
}
DEVI float sigm(float x)  { return 1.f / (1.f + __expf(-x)); }
DEVI float tanh_(float x) { return 1.f - 2.f / (__expf(2.f * x) + 1.f); }
DEVI f32x4 mfma16(bfrag a, bfrag b, f32x4 c) {
  return __builtin_amdgcn_mfma_f32_16x16x32_bf16(a, b, c, 0, 0, 0);
}
// frag-major byte offset for element (m,k) of a [64 m][K k] activation
DEVI u32 fragoff(int m, int k) {
  return (u32)((((k >> 5) * 4 + (m >> 4)) * 64 + ((k >> 3) & 3) * 16 + (m & 15)) * 16 + (k & 7) * 2);
}
// per-step slot addressing (slot 0 = initial state, slot t+1 = written at step t)
DEVI char* of_slot(char* w, int s) { return w + (s ? OFR_O + (long)(s - 1) * 131072 : OF0_O); }
DEVI char* h0_slot(char* w, int s) { return w + (s ? H0R_O + (long)(s - 1) * 131072 : H00_O); }
DEVI char* h1_slot(char* w, int s) { return w + (s ? H1R_O + (long)(s - 1) * 131072 : H10_O); }

// ---------------- barrier: flag store + all-to-all poll (no cache ops) ----------------
DEVI void pollflags(u32* flags, u32 gen) {
  int t = threadIdx.x;   // < 64
  for (;;) {
    u32 a = __hip_atomic_load(&flags[t],       __ATOMIC_RELAXED, __HIP_MEMORY_SCOPE_AGENT);
    u32 b = __hip_atomic_load(&flags[64 + t],  __ATOMIC_RELAXED, __HIP_MEMORY_SCOPE_AGENT);
    u32 c = __hip_atomic_load(&flags[128 + t], __ATOMIC_RELAXED, __HIP_MEMORY_SCOPE_AGENT);
    u32 d = __hip_atomic_load(&flags[192 + t], __ATOMIC_RELAXED, __HIP_MEMORY_SCOPE_AGENT);
    if (__all((a >= gen) && (b >= gen) && (c >= gen) && (d >= gen))) break;
    __builtin_amdgcn_s_sleep(1);
  }
}
DEVI void barr_arrive(u32* flags, u32 gen) {
  VMFLUSH();               // drain sc stores to LLC before signaling
  __syncthreads();
  if (threadIdx.x == 0)
    __hip_atomic_store(&flags[blockIdx.x], gen, __ATOMIC_RELAXED, __HIP_MEMORY_SCOPE_AGENT);
}
DEVI void barr_wait(u32* flags, u32 gen) {
  if (threadIdx.x < 64) pollflags(flags, gen);
  __syncthreads();
  asm volatile("" ::: "memory");
}

// ---------------- gate-GEMM segment: cached loads, compiler-pipelined ----------------
template<int N4>
DEVI void gseg(f32x4& acc, const char* Af, int kkA0, int mt, int lane,
               const char* W, int wRowK, int kkW0, int brow, int ke) {
  const u32 sw = (u32)((brow & 7) << 4);
#pragma unroll
  for (int g = 0; g < N4; ++g) {
#pragma unroll
    for (int q = 0; q < 4; ++q) {
      const char* pa = Af + ((((kkA0 + g * 4 + q) * 4 + mt) * 64 + lane) << 4);
      bfrag av = *(const bfrag*)pa;
      int kkW = kkW0 + g * 4 + q;
      u32 off = ((u32)(brow * wRowK + kkW * 32 + ke) * 2) ^ sw;
      acc = mfma16(av, *(const bfrag*)(W + off), acc);
    }
  }
}

DEVI void scr_store(float* scr, int slot, f32x4 acc) {
  const int lane = threadIdx.x & 63;
#pragma unroll
  for (int r = 0; r < 4; ++r)
    scr[slot * 272 + ((lane >> 4) * 4 + r) * 17 + (lane & 15)] = acc[r];
}

// LSTM pointwise: threads 0..63; c-state in registers; one 8B sc h-store
DEVI void pointwise64(int bid, const float* scr, const float* bias, float (&cst)[4], char* hfrag) {
  const int m = threadIdx.x;            // < 64
  const int mt = m >> 4, ml = m & 15;
  u32 hp0 = 0, hp1 = 0;
#pragma unroll
  for (int u = 0; u < 4; ++u) {
    const int j = bid * 4 + u;
    float g0 = scr[(mt*2)*272 + ml*17 + u]      + scr[(mt*2+1)*272 + ml*17 + u]      + bias[j];
    float g1 = scr[(mt*2)*272 + ml*17 + 4 + u]  + scr[(mt*2+1)*272 + ml*17 + 4 + u]  + bias[1024 + j];
    float g2 = scr[(mt*2)*272 + ml*17 + 8 + u]  + scr[(mt*2+1)*272 + ml*17 + 8 + u]  + bias[2048 + j];
    float g3 = scr[(mt*2)*272 + ml*17 + 12 + u] + scr[(mt*2+1)*272 + ml*17 + 12 + u] + bias[3072 + j];
    float cn = sigm(g1) * cst[u] + sigm(g0) * tanh_(g2);
    cst[u] = cn;
    u32 hb = (u32)f2bf(sigm(g3) * tanh_(cn));
    if (u == 0) hp0 = hb; else if (u == 1) hp0 |= hb << 16;
    else if (u == 2) hp1 = hb; else hp1 |= hb << 16;
  }
  u32x2 v; v[0] = hp0; v[1] = hp1;
  ST8SC(hfrag + fragoff(m, bid * 4), v);
}

// setup GEMM: dst[(b,s)][j] = ctx[(b,s),:] . Wrow[j,:]   (sc stores)
DEVI void ctxw_gemm(int mt, const u16* Ctx, const u16* Wm, u16* dst) {
  const int tid = threadIdx.x, lane = tid & 63, w = tid >> 6;
  const int arow = mt * 16 + (lane & 15);
  const int ke = (lane >> 4) * 8;
#pragma unroll
  for (int i = 0; i < 8; ++i) {
    int nt = w * 8 + i;
    const u16* A = Ctx + (long)arow * 1024 + ke;
    const u16* B = Wm + (long)(nt * 16 + (lane & 15)) * 1024 + ke;
    f32x4 acc = {0.f, 0.f, 0.f, 0.f};
    for (int kk = 0; kk < 1024; kk += 32)
      acc = mfma16(*(const bfrag*)(A + kk), *(const bfrag*)(B + kk), acc);
#pragma unroll
    for (int r = 0; r < 4; ++r)
      ST2SC((char*)(dst + (long)(mt * 16 + (lane >> 4) * 4 + r) * 1024 + nt * 16 + (lane & 15)),
            (u32)f2bf(acc[r]));
  }
}

// setup GEMM: CtxOT[b][j][s] = ctx[(b,s),:] . Wao[j, 0..1024]   (sc stores)
DEVI void ctxo_gemm(int bid, const u16* Ctx, const u16* Wao, u16* dst) {
  const int tid = threadIdx.x, lane = tid & 63, w = tid >> 6;
  const int arow = bid * 16 + (lane & 15);
  const int ke = (lane >> 4) * 8;
  const int b = bid >> 2, s0 = (bid & 3) * 16 + (lane >> 4) * 4;
#pragma unroll
  for (int i = 0; i < 8; ++i) {
    int nt = w * 8 + i;
    int j = nt * 16 + (lane & 15);
    const u16* A = Ctx + (long)arow * 1024 + ke;
    const u16* B = Wao + (long)j * 2048 + ke;
    f32x4 acc = {0.f, 0.f, 0.f, 0.f};
    for (int kk = 0; kk < 1024; kk += 32)
      acc = mfma16(*(const bfrag*)(A + kk), *(const bfrag*)(B + kk), acc);
    u32x2 q;
    q[0] = (u32)f2bf(acc[0]) | ((u32)f2bf(acc[1]) << 16);
    q[1] = (u32)f2bf(acc[2]) | ((u32)f2bf(acc[3]) << 16);
    ST8SC((char*)(dst + ((long)(b * 1024 + j) * 64 + s0)), q);
  }
}

// ---------------- the kernel ----------------
__global__ __launch_bounds__(512, 1) void decoder_kernel(KParams p) {
  extern __shared__ char smem[];
  char*  W0   = smem + W0LDS_O;
  char*  W1   = smem + W1LDS_O;
  float* scr  = (float*)(smem + SCR_O);
  float* scr2 = (float*)(smem + SCR2_O);

  char* wsb = p.ws;
  u16* Wao   = (u16*)(wsb + WAO_O);
  u16* Wai   = (u16*)(wsb + WAI_O);
  u16* Wc    = (u16*)(wsb + WC_O);
  u16* Ctx   = (u16*)(wsb + CTX_O);
  u16* CtxW  = (u16*)(wsb + CTXW_O);
  u16* CtxWc = (u16*)(wsb + CTXWC_O);
  u16* CtxOT = (u16*)(wsb + CTXOT_O);
  u32* bar   = (u32*)(wsb + BAR_O);

  const int bid = blockIdx.x, tid = threadIdx.x;
  const int lane = tid & 63, w = tid >> 6;
  const long gtid = (long)bid * 512 + tid, NT = 256l * 512;
  u32 gen = 1;

  // ---- S0-pre: LDS-tiled transposes of attn_in / copy_in (sc out) ----
  {
    float* tile = (float*)smem;
    for (int pass = 0; pass < 2; ++pass) {
      const float* src = pass ? p.copy_in : p.attn_in;
      u16* dst = pass ? Wc : Wai;
      int tr = bid >> 4, tc = bid & 15;
      {
        int r = tid >> 3, c = (tid & 7) * 8;
        const float4* s4 = (const float4*)(src + (long)(tr * 64 + r) * 1024 + tc * 64 + c);
        float4 a = s4[0], b = s4[1];
        float* tp = tile + r * 69 + c;
        tp[0] = a.x; tp[1] = a.y; tp[2] = a.z; tp[3] = a.w;
        tp[4] = b.x; tp[5] = b.y; tp[6] = b.z; tp[7] = b.w;
      }
      __syncthreads();
      {
        int r2 = tid >> 3, c2 = (tid & 7) * 8;
        u32x4 q;
#pragma unroll
        for (int i = 0; i < 4; ++i) {
          float lo = tile[(c2 + 2 * i) * 69 + r2];
          float hi = tile[(c2 + 2 * i + 1) * 69 + r2];
          q[i] = (u32)f2bf(lo) | ((u32)f2bf(hi) << 16);
        }
        ST16SC((char*)(dst + (long)(tc * 64 + r2) * 1024 + tr * 64 + c2), q);
      }
      __syncthreads();
    }
  }

  // ---- S0a: per-block weight slices -> LDS (stationary all 32 steps) ----
  for (int i = tid; i < 5120; i += 512) {
    int row = i / 320, k = (i % 320) * 8;
    int R = (row >> 2) * 1024 + bid * 4 + (row & 3);
    const float* src = (k < 1536) ? (p.W_ih0 + (long)R * 1536 + k)
                                  : (p.W_hh0 + (long)R * 1024 + (k - 1536));
    float4 a = *(const float4*)src, b = *(const float4*)(src + 4);
    uint4 q;
    q.x = (u32)f2bf(a.x) | ((u32)f2bf(a.y) << 16);
    q.y = (u32)f2bf(a.z) | ((u32)f2bf(a.w) << 16);
    q.z = (u32)f2bf(b.x) | ((u32)f2bf(b.y) << 16);
    q.w = (u32)f2bf(b.z) | ((u32)f2bf(b.w) << 16);
    u32 off = ((u32)(row * 2560 + k) * 2) ^ ((u32)((row & 7) << 4));
    *(uint4*)(W0 + off) = q;
  }
  for (int i = tid; i < 4096; i += 512) {
    int row = i / 256, k = (i % 256) * 8;
    int R = (row >> 2) * 1024 + bid * 4 + (row & 3);
    const float* src = (k < 1024) ? (p.W_ih1 + (long)R * 1024 + k)
                                  : (p.W_hh1 + (long)R * 1024 + (k - 1024));
    float4 a = *(const float4*)src, b = *(const float4*)(src + 4);
    uint4 q;
    q.x = (u32)f2bf(a.x) | ((u32)f2bf(a.y) << 16);
    q.y = (u32)f2bf(a.z) | ((u32)f2bf(a.w) << 16);
    q.z = (u32)f2bf(b.x) | ((u32)f2bf(b.y) << 16);
    q.w = (u32)f2bf(b.z) | ((u32)f2bf(b.w) << 16);
    u32 off = ((u32)(row * 2048 + k) * 2) ^ ((u32)((row & 7) << 4));
    *(uint4*)(W1 + off) = q;
  }

  // ---- S0b: global conversions (all sc stores) ----
  for (long i = gtid; i < 524288; i += NT) cvtc_sc(p.attn_out + i * 4, (char*)(Wao + i * 4));
  for (long i = gtid; i < 1048576; i += NT) {
    long b = i >> 14, s = (i >> 8) & 63, kq = i & 255;
    cvtc_sc(p.context + ((s * 64 + b) * 1024 + kq * 4), (char*)(Ctx + i * 4));
  }
  for (long i = gtid; i < 262144; i += NT) {     // emb gather -> frag-major
    long row = i >> 7; long t = row >> 6, b = row & 63;
    long k0 = (i & 127) * 4;
    long tok = p.input[row];
    cvtc_sc(p.embedding + tok * 512 + k0, wsb + EBF_O + t * 65536 + fragoff((int)b, (int)k0));
  }
  for (long i = gtid; i < 16384; i += NT) {      // init_output -> OF slot 0
    long b = i >> 8, k0 = (i & 255) * 4;
    cvtc_sc(p.init_output + i * 4, of_slot(wsb, 0) + fragoff((int)b, (int)k0));
  }
  for (long i = gtid; i < 32768; i += NT) {      // h0 -> h slots 0
    long l = i >> 14, rem = i & 16383, b = rem >> 8, k0 = (rem & 255) * 4;
    cvtc_sc(p.h0 + i * 4, (l ? h1_slot(wsb, 0) : h0_slot(wsb, 0)) + fragoff((int)b, (int)k0));
  }

  // ---- c-state -> registers (threads 0..63; thread m owns (m, j=bid*4+u)) ----
  float cR0[4] = {0.f, 0.f, 0.f, 0.f}, cR1[4] = {0.f, 0.f, 0.f, 0.f};
  if (tid < 64) {
#pragma unroll
    for (int u = 0; u < 4; ++u) {
      cR0[u] = p.c0[(long)tid * 1024 + bid * 4 + u];
      cR1[u] = p.c0[65536 + (long)tid * 1024 + bid * 4 + u];
    }
  }

  barr_arrive(bar, gen); barr_wait(bar, gen); ++gen;

  // ---- S1: attention tables ----
  ctxw_gemm(bid, Ctx, Wai, CtxW);
  ctxw_gemm(bid, Ctx, Wc, CtxWc);
  ctxo_gemm(bid, Ctx, Wao, CtxOT);
  barr_arrive(bar, gen); barr_wait(bar, gen); ++gen;

  // ---- P4 geometry (XCD-pinned) + Wao h1-half fragments in registers ----
  // (after this point WAO and CTX regions are dead -> reused as rotation slots)
  const int xcd = bid & 7, idx = bid >> 3;
  const int ntP4 = xcd * 8 + (idx & 7), mtP4 = idx >> 3;
  const int browP4 = ntP4 * 16 + (lane & 15);
  const int ke_ = (lane >> 4) * 8;
  bfrag waoreg[4];
#pragma unroll
  for (int q = 0; q < 4; ++q)
    waoreg[q] = *(const bfrag*)(Wao + (long)browP4 * 2048 + 1024 + (w * 4 + q) * 32 + ke_);

  const int mt_ = w & 3, kh_ = w >> 2;
  const int brow_ = lane & 15;

  // ---- pre-loop P1(0) lookahead: emb(0) + h0 slot 0 ----
  f32x4 accP1 = {0.f, 0.f, 0.f, 0.f}, accP2;
  {
    const char* E0  = wsb + EBF_O;
    const char* H0p = h0_slot(wsb, 0);
    if (kh_ == 0) {
      gseg<2>(accP1, E0,  0,  mt_, lane, W0, 2560, 0,  brow_, ke_);
      gseg<4>(accP1, H0p, 0,  mt_, lane, W0, 2560, 48, brow_, ke_);
    } else {
      gseg<2>(accP1, E0,  8,  mt_, lane, W0, 2560, 8,  brow_, ke_);
      gseg<4>(accP1, H0p, 16, mt_, lane, W0, 2560, 64, brow_, ke_);
    }
  }

  for (int t = 0; t < 32; ++t) {
    const char* OFc   = of_slot(wsb, t);
    char*       Hb0cF = h0_slot(wsb, t + 1);
    char*       Hb1cF = h1_slot(wsb, t + 1);
    const char* Hb1pF = h1_slot(wsb, t);
    char*       ABt   = wsb + AB_O + (long)t * 16384;

    // ---- P1 remainder: out-feed segment ----
    {
      f32x4 acc = accP1;
      if (kh_ == 0) gseg<4>(acc, OFc, 0,  mt_, lane, W0, 2560, 16, brow_, ke_);
      else          gseg<4>(acc, OFc, 16, mt_, lane, W0, 2560, 32, brow_, ke_);
      scr_store(scr, mt_ * 2 + kh_, acc);
      __syncthreads();
      if (tid < 64) pointwise64(bid, scr, p.b0, cR0, Hb0cF);
    }
    barr_arrive(bar, gen);
    // P2 lookahead: h1prev segment
    accP2 = f32x4{0.f, 0.f, 0.f, 0.f};
    if (kh_ == 0) gseg<4>(accP2, Hb1pF, 0,  mt_, lane, W1, 2048, 32, brow_, ke_);
    else          gseg<4>(accP2, Hb1pF, 16, mt_, lane, W1, 2048, 48, brow_, ke_);
    barr_wait(bar, gen); ++gen;

    // ---- P2 remainder: h0new segment ----
    {
      f32x4 acc = accP2;
      if (kh_ == 0) gseg<4>(acc, Hb0cF, 0,  mt_, lane, W1, 2048, 0,  brow_, ke_);
      else          gseg<4>(acc, Hb0cF, 16, mt_, lane, W1, 2048, 16, brow_, ke_);
      scr_store(scr, mt_ * 2 + kh_, acc);
      __syncthreads();
      if (tid < 64) pointwise64(bid, scr, p.b1, cR1, Hb1cF);
    }
    barr_arrive(bar, gen);
    // P1(t+1) lookahead part A: emb(t+1) + first half of h0(t+1)
    accP1 = f32x4{0.f, 0.f, 0.f, 0.f};
    {
      const char* En = wsb + EBF_O + (long)((t + 1) & 31) * 65536;
      if (kh_ == 0) {
        gseg<2>(accP1, En,    0,  mt_, lane, W0, 2560, 0,  brow_, ke_);
        gseg<2>(accP1, Hb0cF, 0,  mt_, lane, W0, 2560, 48, brow_, ke_);
      } else {
        gseg<2>(accP1, En,    8,  mt_, lane, W0, 2560, 8,  brow_, ke_);
        gseg<2>(accP1, Hb0cF, 16, mt_, lane, W0, 2560, 64, brow_, ke_);
      }
    }
    barr_wait(bar, gen); ++gen;

    // ---- P3 (blocks 0..63): scores + softmax -> a(t); all blocks: P4h ----
    if (bid < 64) {
      const int b = bid;
      float h1v[16];
      {
        int k0 = lane * 16;
        const u32* hp0 = (const u32*)(Hb1cF + fragoff(b, k0));
        const u32* hp1 = (const u32*)(Hb1cF + fragoff(b, k0 + 8));
        u32 uu[8] = {hp0[0], hp0[1], hp0[2], hp0[3], hp1[0], hp1[1], hp1[2], hp1[3]};
#pragma unroll
        for (int i = 0; i < 8; ++i) {
          h1v[2 * i]     = bf2f((u16)(uu[i] & 0xffff));
          h1v[2 * i + 1] = bf2f((u16)(uu[i] >> 16));
        }
      }
      const u16* cwb = CtxW + (long)b * 65536;
#pragma unroll
      for (int si = 0; si < 8; ++si) {
        int s = w * 8 + si;
        const u32* u = (const u32*)(cwb + (long)s * 1024 + lane * 16);
        float acc = 0.f;
#pragma unroll
        for (int i = 0; i < 8; ++i) {
          u32 x = u[i];
          acc += h1v[2 * i] * bf2f((u16)(x & 0xffff));
          acc += h1v[2 * i + 1] * bf2f((u16)(x >> 16));
        }
#pragma unroll
        for (int off = 32; off; off >>= 1) acc += __shfl_down(acc, off, 64);
        if (lane == 0) scr2[s] = acc;
      }
      __syncthreads();
      if (w == 0) {
        float v = scr2[lane];
        float mx = v;
#pragma unroll
        for (int off = 32; off; off >>= 1) mx = fmaxf(mx, __shfl_xor(mx, off, 64));
        float e = __expf(v - mx);
        float sm = e;
#pragma unroll
        for (int off = 32; off; off >>= 1) sm += __shfl_xor(sm, off, 64);
        float a = e / sm;
        ST4SC(ABt + (u32)(b * 64 + lane) * 4, __builtin_bit_cast(u32, a));
        ST4SC((char*)(p.out + AS_OFF + (long)t * 4096 + b * 64 + lane), __builtin_bit_cast(u32, a));
      }
    }
    // P4h: h1-half of out-projection (all blocks, 8-way K-split)
    {
      const char* bp = Hb1cF;
      bfrag h0_ = *(const bfrag*)(bp + ((((w * 4 + 0) * 4 + mtP4) * 64 + lane) << 4));
      bfrag h1_ = *(const bfrag*)(bp + ((((w * 4 + 1) * 4 + mtP4) * 64 + lane) << 4));
      bfrag h2_ = *(const bfrag*)(bp + ((((w * 4 + 2) * 4 + mtP4) * 64 + lane) << 4));
      bfrag h3_ = *(const bfrag*)(bp + ((((w * 4 + 3) * 4 + mtP4) * 64 + lane) << 4));
      f32x4 a4 = {0.f, 0.f, 0.f, 0.f};
      a4 = mfma16(h0_, waoreg[0], a4);
      a4 = mfma16(h1_, waoreg[1], a4);
      a4 = mfma16(h2_, waoreg[2], a4);
      a4 = mfma16(h3_, waoreg[3], a4);
      scr_store(scr, w, a4);
    }
    barr_arrive(bar, gen);
    // P1(t+1) lookahead part B: second half of h0(t+1)
    if (kh_ == 0) gseg<2>(accP1, Hb0cF, 8,  mt_, lane, W0, 2560, 56, brow_, ke_);
    else          gseg<2>(accP1, Hb0cF, 24, mt_, lane, W0, 2560, 72, brow_, ke_);
    barr_wait(bar, gen); ++gen;

    // ---- P4c: out = tanh(sum_s a_s*CtxO[b,s,:] + h1half); write out + OF(t+1) ----
    {
      {
        int b0i = tid >> 6, s0i = tid & 63;
        int b1i = (tid + 512) >> 6;
        scr2[tid]       = *(const float*)(ABt + (u32)(((mtP4 * 16 + b0i) * 64 + s0i)) * 4);
        scr2[tid + 512] = *(const float*)(ABt + (u32)(((mtP4 * 16 + b1i) * 64 + s0i)) * 4);
      }
      __syncthreads();
      const int pair = tid >> 1, half = tid & 1;
      const int m_l = pair >> 4, j_l = pair & 15;
      const int b = mtP4 * 16 + m_l, j = ntP4 * 16 + j_l;
      const u32* cp = (const u32*)(CtxOT + ((long)(b * 1024 + j) * 64 + half * 32));
      const float* al = scr2 + m_l * 64 + half * 32;
      float acc = 0.f;
#pragma unroll
      for (int i = 0; i < 16; ++i) {
        u32 x = cp[i];
        acc += al[2 * i] * bf2f((u16)(x & 0xffff));
        acc += al[2 * i + 1] * bf2f((u16)(x >> 16));
      }
      float v = acc + __shfl_xor(acc, 1, 64);
      if (half == 0) {
        float h1p = 0.f;
#pragma unroll
        for (int q = 0; q < 8; ++q) h1p += scr[q * 272 + m_l * 17 + j_l];
        v = tanh_(v + h1p);
        ST4SC((char*)(p.out + (long)t * 65536 + b * 1024 + j), __builtin_bit_cast(u32, v));
        u32 hv = (u32)f2bf(v);
        ST2SC(of_slot(wsb, t + 1) + fragoff(b, j), hv);
      }
    }
    barr_arrive(bar, gen);
    barr_wait(bar, gen); ++gen;
  }

  // ---- epilogue: final states (slot 32; h from frag, c from registers) ----
  if (tid < 64) {
#pragma unroll
    for (int u = 0; u < 4; ++u) {
      int j = bid * 4 + u;
      p.out[CT_OFF + (long)tid * 1024 + j]         = cR0[u];
      p.out[CT_OFF + 65536 + (long)tid * 1024 + j] = cR1[u];
    }
  }
  if (tid < 256) {
    int u = tid >> 6, m = tid & 63, j = bid * 4 + u;
    u16 a0 = *(const u16*)(h0_slot(wsb, 32) + fragoff(m, j));
    u16 a1 = *(const u16*)(h1_slot(wsb, 32) + fragoff(m, j));
    p.out[HT_OFF + (long)m * 1024 + j]         = bf2f(a0);
    p.out[HT_OFF + 65536 + (long)m * 1024 + j] = bf2f(a1);
  }

  // ---- deferred copy-attention (blocks 0..63) ----
  if (bid < 64) {
    const int b = bid;
    u16* cw = (u16*)smem;   // reuse W0+W1 region (weights dead)
    __syncthreads();
    {
      const uint4* src = (const uint4*)(CtxWc + (long)b * 65536);
      uint4* dst = (uint4*)cw;
      for (int i = tid; i < 8192; i += 512) dst[i] = src[i];
    }
    __syncthreads();
    float* lds_s = scr;
    for (int t = 0; t < 32; ++t) {
      float ov[16];
      {
        const float4* op = (const float4*)(p.out + (long)t * 65536 + b * 1024 + lane * 16);
#pragma unroll
        for (int i = 0; i < 4; ++i) {
          float4 v = op[i];
          ov[4 * i] = v.x; ov[4 * i + 1] = v.y; ov[4 * i + 2] = v.z; ov[4 * i + 3] = v.w;
        }
      }
#pragma unroll
      for (int si = 0; si < 8; ++si) {
        int s = w * 8 + si;
        const u32* u = (const u32*)(cw + s * 1024 + lane * 16);
        float acc = 0.f;
#pragma unroll
        for (int i = 0; i < 8; ++i) {
          u32 x = u[i];
          acc += ov[2 * i] * bf2f((u16)(x & 0xffff));
          acc += ov[2 * i + 1] * bf2f((u16)(x >> 16));
        }
#pragma unroll
        for (int off = 32; off; off >>= 1) acc += __shfl_down(acc, off, 64);
        if (lane == 0) lds_s[s] = acc;
      }
      __syncthreads();
      if (w == 0) {
        float v = lds_s[lane];
        float mx = v;
#pragma unroll
        for (int off = 32; off; off >>= 1) mx = fmaxf(mx, __shfl_xor(mx, off, 64));
        float e = __expf(v - mx);
        float sm = e;
#pragma unroll
        for (int off = 32; off; off >>= 1) sm += __shfl_xor(sm, off, 64);
        p.out[AC_OFF + (long)t * 4096 + b * 64 + lane] = e / sm;
      }
      __syncthreads();
    }
  }
}

// ---------------- host ----------------
extern "C" void kernel_launch(void* const* d_in, const int* in_sizes, int n_in,
                              void* d_out, int out_size, void* d_ws, size_t ws_size,
                              hipStream_t stream) {
  KParams p;
  p.input       = (const int*)d_in[0];
  p.h0          = (const float*)d_in[1];
  p.c0          = (const float*)d_in[2];
  p.context     = (const float*)d_in[3];
  p.init_output = (const float*)d_in[4];
  p.embedding   = (const float*)d_in[5];
  p.W_ih0       = (const float*)d_in[6];
  p.W_hh0       = (const float*)d_in[7];
  p.b0          = (const float*)d_in[8];
  p.W_ih1       = (const float*)d_in[9];
  p.W_hh1       = (const float*)d_in[10];
  p.b1          = (const float*)d_in[11];
  p.attn_in     = (const float*)d_in[12];
  p.attn_out    = (const float*)d_in[13];
  p.copy_in     = (const float*)d_in[14];
  p.out         = (float*)d_out;
  p.ws          = (char*)d_ws;

  (void)hipFuncSetAttribute((const void*)decoder_kernel,
                            hipFuncAttributeMaxDynamicSharedMemorySize, 160256);
  (void)hipMemsetAsync((char*)d_ws + BAR_O, 0, 2048, stream);
  void* args[] = { &p };
  (void)hipLaunchCooperativeKernel((void*)decoder_kernel, dim3(256), dim3(512),
                                   args, 160256, stream);
}

// Round 10
// 1631.011 us; speedup vs baseline: 3.6184x; 1.0293x over previous
//
#include <hip/hip_runtime.h>

typedef unsigned short u16;
typedef unsigned int   u32;
typedef __attribute__((ext_vector_type(8))) __bf16 bfrag;   // 8 bf16 = 4 VGPR
typedef __attribute__((ext_vector_type(4))) float  f32x4;
typedef __attribute__((ext_vector_type(2))) u32    u32x2;
typedef __attribute__((ext_vector_type(4))) u32    u32x4;

#define DEVI static __device__ __forceinline__

// ---- ALL cross-visible global writes are sc0sc1 (write-through to LLC).
// ---- ALL reads are plain cached loads. Correctness: no global address is
// ---- written-after-cached-read within a launch (per-step slot rotation),
// ---- so no fences / cache invalidations are needed anywhere.
#define ST2SC(p, v)    asm volatile("global_store_short %0, %1, off sc0 sc1"   :: "v"(p), "v"(v) : "memory")
#define ST4SC(p, v)    asm volatile("global_store_dword %0, %1, off sc0 sc1"   :: "v"(p), "v"(v) : "memory")
#define ST8SC(p, v)    asm volatile("global_store_dwordx2 %0, %1, off sc0 sc1" :: "v"(p), "v"(v) : "memory")
#define ST16SC(p, v)   asm volatile("global_store_dwordx4 %0, %1, off sc0 sc1" :: "v"(p), "v"(v) : "memory")
#define VMFLUSH()      asm volatile("s_waitcnt vmcnt(0)" ::: "memory")

// ---------------- geometry ----------------
// T=32 B=64 S=64 E=512 H=1024 L=2 (4H=4096)
constexpr long OUT_OFF = 0;         // 32*64*1024
constexpr long HT_OFF  = 2097152;
constexpr long CT_OFF  = 2228224;
constexpr long AS_OFF  = 2359296;
constexpr long AC_OFF  = 2490368;

// ---------------- workspace layout (bytes) ----------------
// WAO dead after prologue (waoreg);  CTX dead after S1  ->  overlaid by slots.
constexpr long WAO_O   = 0;          // attn_out bf16 [1024][2048] (4MB)
constexpr long CTX_O   = 4194304;    // ctx (b,s,k) bf16 (8MB)
constexpr long OFR_O   = 0;          // OF slots 1..32  [0, 4MB)
constexpr long H0R_O   = 4194304;    // H0 slots 1..32  [4MB, 8MB)
constexpr long H1R_O   = 8388608;    // H1 slots 1..32  [8MB, 12MB)
constexpr long WAI_O   = 12582912;   // attn_in^T bf16 (2MB)
constexpr long WC_O    = 14680064;   // copy_in^T bf16 (2MB)
constexpr long CTXW_O  = 16777216;   // ctx @ Wai (8MB)
constexpr long CTXWC_O = 25165824;   // ctx @ Wc  (8MB)
constexpr long CTXOT_O = 33554432;   // (ctx @ Waoc)^T [b][j][s] (8MB)
constexpr long EBF_O   = 41943040;   // emb frag-major [t][...] (2MB)
constexpr long OF0_O   = 44040192;   // OF slot 0 (128KB)
constexpr long H00_O   = 44171264;   // H0 slot 0
constexpr long H10_O   = 44302336;   // H1 slot 0
constexpr long AB_O    = 44433408;   // a f32 [32 t][64 b][64 s] = 512KB
constexpr long AFLAG_O = 44957696;   // per-step a-ready flags [32 t][64 b] u32 = 8KB
constexpr long BAR_O   = 44965888;   // flags[256] + bcast word

// LDS layout (dynamic, 160256 B)
constexpr int W0LDS_O = 0;        // [16 rows][2560] bf16 swizzled = 81920
constexpr int W1LDS_O = 81920;    // [16 rows][2048] bf16 swizzled = 65536
constexpr int SCR_O   = 147456;   // 8 slots x 272 f32 = 8704
constexpr int SCR2_O  = 156160;   // 4096 B

struct KParams {
  const int* input; const float* h0; const float* c0; const float* context;
  const float* init_output; const float* embedding;
  const float* W_ih0; const float* W_hh0; const float* b0;
  const float* W_ih1; const float* W_hh1; const float* b1;
  const float* attn_in; const float* attn_out; const float* copy_in;
  float* out; char* ws;
};

// ---------------- small helpers ----------------
DEVI float bf2f(u16 u) { u32 x = ((u32)u) << 16; return __builtin_bit_cast(float, x); }
DEVI u16 f2bf(float f) {
  u32 x = __builtin_bit_cast(u32, f);
  u32 r = x + 0x7fffu + ((x >> 16) & 1u);   // RNE
  return (u16)(r >> 16);
}
DEVI void cvtc_sc(const float* s, char* d) {   // 4 f32 -> 4 bf16, sc store
  float4 v = *(const float4*)s;
  u32x2 u;
  u[0] = (u32)f2bf(v.x) | ((u32)f2bf(v.y) << 16);
  u[1] = (u32)f2bf(v.z) | ((u32)f2bf(v.w) << 16);
  ST8SC(d, u);
}
DEVI float sigm(float x)  { return 1.f / (1.f + __expf(-x)); }
DEVI float tanh_(float x) { return 1.f - 2.f / (__expf(2.f * x) + 1.f); }
DEVI f32x4 mfma16(bfrag a, bfrag b, f32x4 c) {
  return __builtin_amdgcn_mfma_f32_16x16x32_bf16(a, b, c, 0, 0, 0);
}
// frag-major byte offset for element (m,k) of a [64 m][K k] activation
DEVI u32 fragoff(int m, int k) {
  return (u32)((((k >> 5) * 4 + (m >> 4)) * 64 + ((k >> 3) & 3) * 16 + (m & 15)) * 16 + (k & 7) * 2);
}
// per-step slot addressing (slot 0 = initial state, slot t+1 = written at step t)
DEVI char* of_slot(char* w, int s) { return w + (s ? OFR_O + (long)(s - 1) * 131072 : OF0_O); }
DEVI char* h0_slot(char* w, int s) { return w + (s ? H0R_O + (long)(s - 1) * 131072 : H00_O); }
DEVI char* h1_slot(char* w, int s) { return w + (s ? H1R_O + (long)(s - 1) * 131072 : H10_O); }

// ---------------- barriers ----------------
// arrive: flag store per block.  wait: aggregator block (128) polls all flags
// then broadcasts one generation word; everyone else polls that single line.
DEVI void pollflags(u32* flags, u32 gen) {
  int t = threadIdx.x;   // < 64
  for (;;) {
    u32 a = __hip_atomic_load(&flags[t],       __ATOMIC_RELAXED, __HIP_MEMORY_SCOPE_AGENT);
    u32 b = __hip_atomic_load(&flags[64 + t],  __ATOMIC_RELAXED, __HIP_MEMORY_SCOPE_AGENT);
    u32 c = __hip_atomic_load(&flags[128 + t], __ATOMIC_RELAXED, __HIP_MEMORY_SCOPE_AGENT);
    u32 d = __hip_atomic_load(&flags[192 + t], __ATOMIC_RELAXED, __HIP_MEMORY_SCOPE_AGENT);
    if (__all((a >= gen) && (b >= gen) && (c >= gen) && (d >= gen))) break;
    __builtin_amdgcn_s_sleep(1);
  }
}
DEVI void barr_arrive(u32* flags, u32 gen) {
  VMFLUSH();               // drain sc stores to LLC before signaling
  __syncthreads();
  if (threadIdx.x == 0)
    __hip_atomic_store(&flags[blockIdx.x], gen, __ATOMIC_RELAXED, __HIP_MEMORY_SCOPE_AGENT);
}
DEVI void barr_wait(u32* flags, u32 gen) {
  u32* bc = flags + 320;   // broadcast word, own cache line
  if (blockIdx.x == 128) {
    if (threadIdx.x < 64) pollflags(flags, gen);
    __syncthreads();
    if (threadIdx.x == 0)
      __hip_atomic_store(bc, gen, __ATOMIC_RELAXED, __HIP_MEMORY_SCOPE_AGENT);
  } else {
    if (threadIdx.x == 0) {
      while (__hip_atomic_load(bc, __ATOMIC_RELAXED, __HIP_MEMORY_SCOPE_AGENT) < gen)
        __builtin_amdgcn_s_sleep(1);
    }
  }
  __syncthreads();
  asm volatile("" ::: "memory");
}
// fenced barrier (setup only; all-to-all is fine twice)
DEVI void gsync_fence(u32* flags, u32 gen) {
  __syncthreads();
  if (threadIdx.x == 0) {
    __builtin_amdgcn_fence(__ATOMIC_RELEASE, "agent");
    __hip_atomic_store(&flags[blockIdx.x], gen, __ATOMIC_RELAXED, __HIP_MEMORY_SCOPE_AGENT);
  }
  if (threadIdx.x < 64) pollflags(flags, gen);
  if (threadIdx.x == 0) __builtin_amdgcn_fence(__ATOMIC_ACQUIRE, "agent");
  __syncthreads();
}

// ---------------- gate-GEMM segment: cached loads, compiler-pipelined ----------------
template<int N4>
DEVI void gseg(f32x4& acc, const char* Af, int kkA0, int mt, int lane,
               const char* W, int wRowK, int kkW0, int brow, int ke) {
  const u32 sw = (u32)((brow & 7) << 4);
#pragma unroll
  for (int g = 0; g < N4; ++g) {
#pragma unroll
    for (int q = 0; q < 4; ++q) {
      const char* pa = Af + ((((kkA0 + g * 4 + q) * 4 + mt) * 64 + lane) << 4);
      bfrag av = *(const bfrag*)pa;
      int kkW = kkW0 + g * 4 + q;
      u32 off = ((u32)(brow * wRowK + kkW * 32 + ke) * 2) ^ sw;
      acc = mfma16(av, *(const bfrag*)(W + off), acc);
    }
  }
}

DEVI void scr_store(float* scr, int slot, f32x4 acc) {
  const int lane = threadIdx.x & 63;
#pragma unroll
  for (int r = 0; r < 4; ++r)
    scr[slot * 272 + ((lane >> 4) * 4 + r) * 17 + (lane & 15)] = acc[r];
}

// LSTM pointwise: threads 0..63; c-state in registers; one 8B sc h-store
DEVI void pointwise64(int bid, const float* scr, const float* bias, float (&cst)[4], char* hfrag) {
  const int m = threadIdx.x;            // < 64
  const int mt = m >> 4, ml = m & 15;
  u32 hp0 = 0, hp1 = 0;
#pragma unroll
  for (int u = 0; u < 4; ++u) {
    const int j = bid * 4 + u;
    float g0 = scr[(mt*2)*272 + ml*17 + u]      + scr[(mt*2+1)*272 + ml*17 + u]      + bias[j];
    float g1 = scr[(mt*2)*272 + ml*17 + 4 + u]  + scr[(mt*2+1)*272 + ml*17 + 4 + u]  + bias[1024 + j];
    float g2 = scr[(mt*2)*272 + ml*17 + 8 + u]  + scr[(mt*2+1)*272 + ml*17 + 8 + u]  + bias[2048 + j];
    float g3 = scr[(mt*2)*272 + ml*17 + 12 + u] + scr[(mt*2+1)*272 + ml*17 + 12 + u] + bias[3072 + j];
    float cn = sigm(g1) * cst[u] + sigm(g0) * tanh_(g2);
    cst[u] = cn;
    u32 hb = (u32)f2bf(sigm(g3) * tanh_(cn));
    if (u == 0) hp0 = hb; else if (u == 1) hp0 |= hb << 16;
    else if (u == 2) hp1 = hb; else hp1 |= hb << 16;
  }
  u32x2 v; v[0] = hp0; v[1] = hp1;
  ST8SC(hfrag + fragoff(m, bid * 4), v);
}

// setup GEMM: dst[(b,s)][j] = ctx[(b,s),:] . Wrow[j,:]   (sc stores)
DEVI void ctxw_gemm(int mt, const u16* Ctx, const u16* Wm, u16* dst) {
  const int tid = threadIdx.x, lane = tid & 63, w = tid >> 6;
  const int arow = mt * 16 + (lane & 15);
  const int ke = (lane >> 4) * 8;
#pragma unroll
  for (int i = 0; i < 8; ++i) {
    int nt = w * 8 + i;
    const u16* A = Ctx + (long)arow * 1024 + ke;
    const u16* B = Wm + (long)(nt * 16 + (lane & 15)) * 1024 + ke;
    f32x4 acc = {0.f, 0.f, 0.f, 0.f};
    for (int kk = 0; kk < 1024; kk += 32)
      acc = mfma16(*(const bfrag*)(A + kk), *(const bfrag*)(B + kk), acc);
#pragma unroll
    for (int r = 0; r < 4; ++r)
      ST2SC((char*)(dst + (long)(mt * 16 + (lane >> 4) * 4 + r) * 1024 + nt * 16 + (lane & 15)),
            (u32)f2bf(acc[r]));
  }
}

// setup GEMM: CtxOT[b][j][s] = ctx[(b,s),:] . Wao[j, 0..1024]   (sc stores)
DEVI void ctxo_gemm(int bid, const u16* Ctx, const u16* Wao, u16* dst) {
  const int tid = threadIdx.x, lane = tid & 63, w = tid >> 6;
  const int arow = bid * 16 + (lane & 15);
  const int ke = (lane >> 4) * 8;
  const int b = bid >> 2, s0 = (bid & 3) * 16 + (lane >> 4) * 4;
#pragma unroll
  for (int i = 0; i < 8; ++i) {
    int nt = w * 8 + i;
    int j = nt * 16 + (lane & 15);
    const u16* A = Ctx + (long)arow * 1024 + ke;
    const u16* B = Wao + (long)j * 2048 + ke;
    f32x4 acc = {0.f, 0.f, 0.f, 0.f};
    for (int kk = 0; kk < 1024; kk += 32)
      acc = mfma16(*(const bfrag*)(A + kk), *(const bfrag*)(B + kk), acc);
    u32x2 q;
    q[0] = (u32)f2bf(acc[0]) | ((u32)f2bf(acc[1]) << 16);
    q[1] = (u32)f2bf(acc[2]) | ((u32)f2bf(acc[3]) << 16);
    ST8SC((char*)(dst + ((long)(b * 1024 + j) * 64 + s0)), q);
  }
}

// ---------------- the kernel ----------------
__global__ __launch_bounds__(512, 1) void decoder_kernel(KParams p) {
  extern __shared__ char smem[];
  char*  W0   = smem + W0LDS_O;
  char*  W1   = smem + W1LDS_O;
  float* scr  = (float*)(smem + SCR_O);
  float* scr2 = (float*)(smem + SCR2_O);

  char* wsb = p.ws;
  u16* Wao   = (u16*)(wsb + WAO_O);
  u16* Wai   = (u16*)(wsb + WAI_O);
  u16* Wc    = (u16*)(wsb + WC_O);
  u16* Ctx   = (u16*)(wsb + CTX_O);
  u16* CtxW  = (u16*)(wsb + CTXW_O);
  u16* CtxWc = (u16*)(wsb + CTXWC_O);
  u16* CtxOT = (u16*)(wsb + CTXOT_O);
  u32* bar   = (u32*)(wsb + BAR_O);

  const int bid = blockIdx.x, tid = threadIdx.x;
  const int lane = tid & 63, w = tid >> 6;
  const long gtid = (long)bid * 512 + tid, NT = 256l * 512;
  u32 gen = 1;

  // ---- S0-pre: LDS-tiled transposes of attn_in / copy_in (sc out) ----
  {
    float* tile = (float*)smem;
    for (int pass = 0; pass < 2; ++pass) {
      const float* src = pass ? p.copy_in : p.attn_in;
      u16* dst = pass ? Wc : Wai;
      int tr = bid >> 4, tc = bid & 15;
      {
        int r = tid >> 3, c = (tid & 7) * 8;
        const float4* s4 = (const float4*)(src + (long)(tr * 64 + r) * 1024 + tc * 64 + c);
        float4 a = s4[0], b = s4[1];
        float* tp = tile + r * 69 + c;
        tp[0] = a.x; tp[1] = a.y; tp[2] = a.z; tp[3] = a.w;
        tp[4] = b.x; tp[5] = b.y; tp[6] = b.z; tp[7] = b.w;
      }
      __syncthreads();
      {
        int r2 = tid >> 3, c2 = (tid & 7) * 8;
        u32x4 q;
#pragma unroll
        for (int i = 0; i < 4; ++i) {
          float lo = tile[(c2 + 2 * i) * 69 + r2];
          float hi = tile[(c2 + 2 * i + 1) * 69 + r2];
          q[i] = (u32)f2bf(lo) | ((u32)f2bf(hi) << 16);
        }
        ST16SC((char*)(dst + (long)(tc * 64 + r2) * 1024 + tr * 64 + c2), q);
      }
      __syncthreads();
    }
  }

  // ---- S0a: per-block weight slices -> LDS (stationary all 32 steps) ----
  for (int i = tid; i < 5120; i += 512) {
    int row = i / 320, k = (i % 320) * 8;
    int R = (row >> 2) * 1024 + bid * 4 + (row & 3);
    const float* src = (k < 1536) ? (p.W_ih0 + (long)R * 1536 + k)
                                  : (p.W_hh0 + (long)R * 1024 + (k - 1536));
    float4 a = *(const float4*)src, b = *(const float4*)(src + 4);
    uint4 q;
    q.x = (u32)f2bf(a.x) | ((u32)f2bf(a.y) << 16);
    q.y = (u32)f2bf(a.z) | ((u32)f2bf(a.w) << 16);
    q.z = (u32)f2bf(b.x) | ((u32)f2bf(b.y) << 16);
    q.w = (u32)f2bf(b.z) | ((u32)f2bf(b.w) << 16);
    u32 off = ((u32)(row * 2560 + k) * 2) ^ ((u32)((row & 7) << 4));
    *(uint4*)(W0 + off) = q;
  }
  for (int i = tid; i < 4096; i += 512) {
    int row = i / 256, k = (i % 256) * 8;
    int R = (row >> 2) * 1024 + bid * 4 + (row & 3);
    const float* src = (k < 1024) ? (p.W_ih1 + (long)R * 1024 + k)
                                  : (p.W_hh1 + (long)R * 1024 + (k - 1024));
    float4 a = *(const float4*)src, b = *(const float4*)(src + 4);
    uint4 q;
    q.x = (u32)f2bf(a.x) | ((u32)f2bf(a.y) << 16);
    q.y = (u32)f2bf(a.z) | ((u32)f2bf(a.w) << 16);
    q.z = (u32)f2bf(b.x) | ((u32)f2bf(b.y) << 16);
    q.w = (u32)f2bf(b.z) | ((u32)f2bf(b.w) << 16);
    u32 off = ((u32)(row * 2048 + k) * 2) ^ ((u32)((row & 7) << 4));
    *(uint4*)(W1 + off) = q;
  }

  // ---- S0b: global conversions (all sc stores) ----
  for (long i = gtid; i < 524288; i += NT) cvtc_sc(p.attn_out + i * 4, (char*)(Wao + i * 4));
  for (long i = gtid; i < 1048576; i += NT) {
    long b = i >> 14, s = (i >> 8) & 63, kq = i & 255;
    cvtc_sc(p.context + ((s * 64 + b) * 1024 + kq * 4), (char*)(Ctx + i * 4));
  }
  for (long i = gtid; i < 262144; i += NT) {     // emb gather -> frag-major
    long row = i >> 7; long t = row >> 6, b = row & 63;
    long k0 = (i & 127) * 4;
    long tok = p.input[row];
    cvtc_sc(p.embedding + tok * 512 + k0, wsb + EBF_O + t * 65536 + fragoff((int)b, (int)k0));
  }
  for (long i = gtid; i < 16384; i += NT) {      // init_output -> OF slot 0
    long b = i >> 8, k0 = (i & 255) * 4;
    cvtc_sc(p.init_output + i * 4, of_slot(wsb, 0) + fragoff((int)b, (int)k0));
  }
  for (long i = gtid; i < 32768; i += NT) {      // h0 -> h slots 0
    long l = i >> 14, rem = i & 16383, b = rem >> 8, k0 = (rem & 255) * 4;
    cvtc_sc(p.h0 + i * 4, (l ? h1_slot(wsb, 0) : h0_slot(wsb, 0)) + fragoff((int)b, (int)k0));
  }

  // ---- c-state -> registers (threads 0..63; thread m owns (m, j=bid*4+u)) ----
  float cR0[4] = {0.f, 0.f, 0.f, 0.f}, cR1[4] = {0.f, 0.f, 0.f, 0.f};
  if (tid < 64) {
#pragma unroll
    for (int u = 0; u < 4; ++u) {
      cR0[u] = p.c0[(long)tid * 1024 + bid * 4 + u];
      cR1[u] = p.c0[65536 + (long)tid * 1024 + bid * 4 + u];
    }
  }

  gsync_fence(bar, gen); ++gen;

  // ---- S1: attention tables ----
  ctxw_gemm(bid, Ctx, Wai, CtxW);
  ctxw_gemm(bid, Ctx, Wc, CtxWc);
  ctxo_gemm(bid, Ctx, Wao, CtxOT);
  gsync_fence(bar, gen); ++gen;

  // ---- P4 geometry (XCD-pinned) + Wao h1-half fragments in registers ----
  const int xcd = bid & 7, idx = bid >> 3;
  const int ntP4 = xcd * 8 + (idx & 7), mtP4 = idx >> 3;
  const int browP4 = ntP4 * 16 + (lane & 15);
  const int ke_ = (lane >> 4) * 8;
  bfrag waoreg[4];
#pragma unroll
  for (int q = 0; q < 4; ++q)
    waoreg[q] = *(const bfrag*)(Wao + (long)browP4 * 2048 + 1024 + (w * 4 + q) * 32 + ke_);

  const int mt_ = w & 3, kh_ = w >> 2;
  const int brow_ = lane & 15;

  // ---- pre-loop P1(0) lookahead: emb(0) + h0 slot 0 ----
  f32x4 accP1 = {0.f, 0.f, 0.f, 0.f}, accP2;
  {
    const char* E0  = wsb + EBF_O;
    const char* H0p = h0_slot(wsb, 0);
    if (kh_ == 0) {
      gseg<2>(accP1, E0,  0,  mt_, lane, W0, 2560, 0,  brow_, ke_);
      gseg<4>(accP1, H0p, 0,  mt_, lane, W0, 2560, 48, brow_, ke_);
    } else {
      gseg<2>(accP1, E0,  8,  mt_, lane, W0, 2560, 8,  brow_, ke_);
      gseg<4>(accP1, H0p, 16, mt_, lane, W0, 2560, 64, brow_, ke_);
    }
  }

  for (int t = 0; t < 32; ++t) {
    const char* OFc   = of_slot(wsb, t);
    char*       Hb0cF = h0_slot(wsb, t + 1);
    char*       Hb1cF = h1_slot(wsb, t + 1);
    const char* Hb1pF = h1_slot(wsb, t);
    char*       ABt   = wsb + AB_O + (long)t * 16384;

    // ---- P1 remainder: out-feed segment ----
    {
      f32x4 acc = accP1;
      if (kh_ == 0) gseg<4>(acc, OFc, 0,  mt_, lane, W0, 2560, 16, brow_, ke_);
      else          gseg<4>(acc, OFc, 16, mt_, lane, W0, 2560, 32, brow_, ke_);
      scr_store(scr, mt_ * 2 + kh_, acc);
      __syncthreads();
      if (tid < 64) pointwise64(bid, scr, p.b0, cR0, Hb0cF);
    }
    barr_arrive(bar, gen);
    // P2 lookahead: h1prev segment
    accP2 = f32x4{0.f, 0.f, 0.f, 0.f};
    if (kh_ == 0) gseg<4>(accP2, Hb1pF, 0,  mt_, lane, W1, 2048, 32, brow_, ke_);
    else          gseg<4>(accP2, Hb1pF, 16, mt_, lane, W1, 2048, 48, brow_, ke_);
    barr_wait(bar, gen); ++gen;

    // ---- P2 remainder: h0new segment ----
    {
      f32x4 acc = accP2;
      if (kh_ == 0) gseg<4>(acc, Hb0cF, 0,  mt_, lane, W1, 2048, 0,  brow_, ke_);
      else          gseg<4>(acc, Hb0cF, 16, mt_, lane, W1, 2048, 16, brow_, ke_);
      scr_store(scr, mt_ * 2 + kh_, acc);
      __syncthreads();
      if (tid < 64) pointwise64(bid, scr, p.b1, cR1, Hb1cF);
    }
    barr_arrive(bar, gen);
    // P1(t+1) lookahead part A: emb(t+1) + first half of h0(t+1)
    accP1 = f32x4{0.f, 0.f, 0.f, 0.f};
    {
      const char* En = wsb + EBF_O + (long)((t + 1) & 31) * 65536;
      if (kh_ == 0) {
        gseg<2>(accP1, En,    0,  mt_, lane, W0, 2560, 0,  brow_, ke_);
        gseg<2>(accP1, Hb0cF, 0,  mt_, lane, W0, 2560, 48, brow_, ke_);
      } else {
        gseg<2>(accP1, En,    8,  mt_, lane, W0, 2560, 8,  brow_, ke_);
        gseg<2>(accP1, Hb0cF, 16, mt_, lane, W0, 2560, 64, brow_, ke_);
      }
    }
    barr_wait(bar, gen); ++gen;

    // ---- P3 (blocks 0..63): scores + softmax -> a(t) + per-batch ready flag ----
    if (bid < 64) {
      const int b = bid;
      float h1v[16];
      {
        int k0 = lane * 16;
        const u32* hp0 = (const u32*)(Hb1cF + fragoff(b, k0));
        const u32* hp1 = (const u32*)(Hb1cF + fragoff(b, k0 + 8));
        u32 uu[8] = {hp0[0], hp0[1], hp0[2], hp0[3], hp1[0], hp1[1], hp1[2], hp1[3]};
#pragma unroll
        for (int i = 0; i < 8; ++i) {
          h1v[2 * i]     = bf2f((u16)(uu[i] & 0xffff));
          h1v[2 * i + 1] = bf2f((u16)(uu[i] >> 16));
        }
      }
      const u16* cwb = CtxW + (long)b * 65536;
#pragma unroll
      for (int si = 0; si < 8; ++si) {
        int s = w * 8 + si;
        const u32* u = (const u32*)(cwb + (long)s * 1024 + lane * 16);
        float acc = 0.f;
#pragma unroll
        for (int i = 0; i < 8; ++i) {
          u32 x = u[i];
          acc += h1v[2 * i] * bf2f((u16)(x & 0xffff));
          acc += h1v[2 * i + 1] * bf2f((u16)(x >> 16));
        }
#pragma unroll
        for (int off = 32; off; off >>= 1) acc += __shfl_down(acc, off, 64);
        if (lane == 0) scr2[s] = acc;
      }
      __syncthreads();
      if (w == 0) {
        float v = scr2[lane];
        float mx = v;
#pragma unroll
        for (int off = 32; off; off >>= 1) mx = fmaxf(mx, __shfl_xor(mx, off, 64));
        float e = __expf(v - mx);
        float sm = e;
#pragma unroll
        for (int off = 32; off; off >>= 1) sm += __shfl_xor(sm, off, 64);
        float a = e / sm;
        ST4SC(ABt + (u32)(b * 64 + lane) * 4, __builtin_bit_cast(u32, a));
        ST4SC((char*)(p.out + AS_OFF + (long)t * 4096 + b * 64 + lane), __builtin_bit_cast(u32, a));
        VMFLUSH();   // a-values at LLC before ready flag
        if (lane == 0)
          ST4SC(wsb + AFLAG_O + ((u32)t * 64 + b) * 4, 1u);
      }
    }
    // P4h: h1-half of out-projection (all blocks, 8-way K-split)
    {
      const char* bp = Hb1cF;
      bfrag h0_ = *(const bfrag*)(bp + ((((w * 4 + 0) * 4 + mtP4) * 64 + lane) << 4));
      bfrag h1_ = *(const bfrag*)(bp + ((((w * 4 + 1) * 4 + mtP4) * 64 + lane) << 4));
      bfrag h2_ = *(const bfrag*)(bp + ((((w * 4 + 2) * 4 + mtP4) * 64 + lane) << 4));
      bfrag h3_ = *(const bfrag*)(bp + ((((w * 4 + 3) * 4 + mtP4) * 64 + lane) << 4));
      f32x4 a4 = {0.f, 0.f, 0.f, 0.f};
      a4 = mfma16(h0_, waoreg[0], a4);
      a4 = mfma16(h1_, waoreg[1], a4);
      a4 = mfma16(h2_, waoreg[2], a4);
      a4 = mfma16(h3_, waoreg[3], a4);
      scr_store(scr, w, a4);
    }

    // ---- P4c: poll a-ready flags (one 64B line), then cached a loads ----
    {
      if (tid < 16) {
        const u32* fp = (const u32*)(wsb + AFLAG_O + ((u32)t * 64 + mtP4 * 16 + tid) * 4);
        while (__hip_atomic_load(fp, __ATOMIC_RELAXED, __HIP_MEMORY_SCOPE_AGENT) == 0)
          __builtin_amdgcn_s_sleep(1);
      }
      __syncthreads();
      {
        int b0i = tid >> 6, s0i = tid & 63;
        int b1i = (tid + 512) >> 6;
        scr2[tid]       = *(const float*)(ABt + (u32)(((mtP4 * 16 + b0i) * 64 + s0i)) * 4);
        scr2[tid + 512] = *(const float*)(ABt + (u32)(((mtP4 * 16 + b1i) * 64 + s0i)) * 4);
      }
      __syncthreads();
      const int pair = tid >> 1, half = tid & 1;
      const int m_l = pair >> 4, j_l = pair & 15;
      const int b = mtP4 * 16 + m_l, j = ntP4 * 16 + j_l;
      const u32* cp = (const u32*)(CtxOT + ((long)(b * 1024 + j) * 64 + half * 32));
      const float* al = scr2 + m_l * 64 + half * 32;
      float acc = 0.f;
#pragma unroll
      for (int i = 0; i < 16; ++i) {
        u32 x = cp[i];
        acc += al[2 * i] * bf2f((u16)(x & 0xffff));
        acc += al[2 * i + 1] * bf2f((u16)(x >> 16));
      }
      float v = acc + __shfl_xor(acc, 1, 64);
      if (half == 0) {
        float h1p = 0.f;
#pragma unroll
        for (int q = 0; q < 8; ++q) h1p += scr[q * 272 + m_l * 17 + j_l];
        v = tanh_(v + h1p);
        ST4SC((char*)(p.out + (long)t * 65536 + b * 1024 + j), __builtin_bit_cast(u32, v));
        u32 hv = (u32)f2bf(v);
        ST2SC(of_slot(wsb, t + 1) + fragoff(b, j), hv);
      }
    }
    barr_arrive(bar, gen);
    // P1(t+1) lookahead part B: second half of h0(t+1)
    if (kh_ == 0) gseg<2>(accP1, Hb0cF, 8,  mt_, lane, W0, 2560, 56, brow_, ke_);
    else          gseg<2>(accP1, Hb0cF, 24, mt_, lane, W0, 2560, 72, brow_, ke_);
    barr_wait(bar, gen); ++gen;
  }

  // ---- epilogue: final states (slot 32; h from frag, c from registers) ----
  if (tid < 64) {
#pragma unroll
    for (int u = 0; u < 4; ++u) {
      int j = bid * 4 + u;
      p.out[CT_OFF + (long)tid * 1024 + j]         = cR0[u];
      p.out[CT_OFF + 65536 + (long)tid * 1024 + j] = cR1[u];
    }
  }
  if (tid < 256) {
    int u = tid >> 6, m = tid & 63, j = bid * 4 + u;
    u16 a0 = *(const u16*)(h0_slot(wsb, 32) + fragoff(m, j));
    u16 a1 = *(const u16*)(h1_slot(wsb, 32) + fragoff(m, j));
    p.out[HT_OFF + (long)m * 1024 + j]         = bf2f(a0);
    p.out[HT_OFF + 65536 + (long)m * 1024 + j] = bf2f(a1);
  }

  // ---- deferred copy-attention (blocks 0..63) ----
  if (bid < 64) {
    const int b = bid;
    u16* cw = (u16*)smem;   // reuse W0+W1 region (weights dead)
    __syncthreads();
    {
      const uint4* src = (const uint4*)(CtxWc + (long)b * 65536);
      uint4* dst = (uint4*)cw;
      for (int i = tid; i < 8192; i += 512) dst[i] = src[i];
    }
    __syncthreads();
    float* lds_s = scr;
    for (int t = 0; t < 32; ++t) {
      float ov[16];
      {
        const float4* op = (const float4*)(p.out + (long)t * 65536 + b * 1024 + lane * 16);
#pragma unroll
        for (int i = 0; i < 4; ++i) {
          float4 v = op[i];
          ov[4 * i] = v.x; ov[4 * i + 1] = v.y; ov[4 * i + 2] = v.z; ov[4 * i + 3] = v.w;
        }
      }
#pragma unroll
      for (int si = 0; si < 8; ++si) {
        int s = w * 8 + si;
        const u32* u = (const u32*)(cw + s * 1024 + lane * 16);
        float acc = 0.f;
#pragma unroll
        for (int i = 0; i < 8; ++i) {
          u32 x = u[i];
          acc += ov[2 * i] * bf2f((u16)(x & 0xffff));
          acc += ov[2 * i + 1] * bf2f((u16)(x >> 16));
        }
#pragma unroll
        for (int off = 32; off; off >>= 1) acc += __shfl_down(acc, off, 64);
        if (lane == 0) lds_s[s] = acc;
      }
      __syncthreads();
      if (w == 0) {
        float v = lds_s[lane];
        float mx = v;
#pragma unroll
        for (int off = 32; off; off >>= 1) mx = fmaxf(mx, __shfl_xor(mx, off, 64));
        float e = __expf(v - mx);
        float sm = e;
#pragma unroll
        for (int off = 32; off; off >>= 1) sm += __shfl_xor(sm, off, 64);
        p.out[AC_OFF + (long)t * 4096 + b * 64 + lane] = e / sm;
      }
      __syncthreads();
    }
  }
}

// ---------------- host ----------------
extern "C" void kernel_launch(void* const* d_in, const int* in_sizes, int n_in,
                              void* d_out, int out_size, void* d_ws, size_t ws_size,
                              hipStream_t stream) {
  KParams p;
  p.input       = (const int*)d_in[0];
  p.h0          = (const float*)d_in[1];
  p.c0          = (const float*)d_in[2];
  p.context     = (const float*)d_in[3];
  p.init_output = (const float*)d_in[4];
  p.embedding   = (const float*)d_in[5];
  p.W_ih0       = (const float*)d_in[6];
  p.W_hh0       = (const float*)d_in[7];
  p.b0          = (const float*)d_in[8];
  p.W_ih1       = (const float*)d_in[9];
  p.W_hh1       = (const float*)d_in[10];
  p.b1          = (const float*)d_in[11];
  p.attn_in     = (const float*)d_in[12];
  p.attn_out    = (const float*)d_in[13];
  p.copy_in     = (const float*)d_in[14];
  p.out         = (float*)d_out;
  p.ws          = (char*)d_ws;

  (void)hipFuncSetAttribute((const void*)decoder_kernel,
                            hipFuncAttributeMaxDynamicSharedMemorySize, 160256);
  // zero: a-buffer (512KB) + a-ready flags (8KB) + barrier flags/bcast (2KB)
  (void)hipMemsetAsync((char*)d_ws + AB_O, 0, 534528, stream);
  void* args[] = { &p };
  (void)hipLaunchCooperativeKernel((void*)decoder_kernel, dim3(256), dim3(512),
                                   args, 160256, stream);
}

// Round 11
// 1534.419 us; speedup vs baseline: 3.8462x; 1.0630x over previous
//
#include <hip/hip_runtime.h>

typedef unsigned short u16;
typedef unsigned int   u32;
typedef __attribute__((ext_vector_type(8))) __bf16 bfrag;   // 8 bf16 = 4 VGPR
typedef __attribute__((ext_vector_type(4))) float  f32x4;
typedef __attribute__((ext_vector_type(2))) u32    u32x2;
typedef __attribute__((ext_vector_type(4))) u32    u32x4;

#define DEVI static __device__ __forceinline__

// ---- ALL cross-visible global writes are sc0sc1 (write-through to LLC).
// ---- ALL reads are plain cached loads. Correctness: no global address is
// ---- written-after-cached-read within a launch (per-step slot rotation),
// ---- so no fences / cache invalidations are needed anywhere.
#define ST2SC(p, v)    asm volatile("global_store_short %0, %1, off sc0 sc1"   :: "v"(p), "v"(v) : "memory")
#define ST4SC(p, v)    asm volatile("global_store_dword %0, %1, off sc0 sc1"   :: "v"(p), "v"(v) : "memory")
#define ST8SC(p, v)    asm volatile("global_store_dwordx2 %0, %1, off sc0 sc1" :: "v"(p), "v"(v) : "memory")
#define ST16SC(p, v)   asm volatile("global_store_dwordx4 %0, %1, off sc0 sc1" :: "v"(p), "v"(v) : "memory")
#define VMFLUSH()      asm volatile("s_waitcnt vmcnt(0)" ::: "memory")

// ---------------- geometry ----------------
// T=32 B=64 S=64 E=512 H=1024 L=2 (4H=4096)
constexpr long OUT_OFF = 0;         // 32*64*1024
constexpr long HT_OFF  = 2097152;
constexpr long CT_OFF  = 2228224;
constexpr long AS_OFF  = 2359296;
constexpr long AC_OFF  = 2490368;

// ---------------- workspace layout (bytes) ----------------
// WAO dead after prologue (waoreg);  CTX dead after S1  ->  overlaid by slots.
constexpr long WAO_O   = 0;          // attn_out bf16 [1024][2048] (4MB)
constexpr long CTX_O   = 4194304;    // ctx (b,s,k) bf16 (8MB)
constexpr long OFR_O   = 0;          // OF slots 1..32  [0, 4MB)
constexpr long H0R_O   = 4194304;    // H0 slots 1..32  [4MB, 8MB)
constexpr long H1R_O   = 8388608;    // H1 slots 1..32  [8MB, 12MB)
constexpr long WAI_O   = 12582912;   // attn_in^T bf16 (2MB)
constexpr long WC_O    = 14680064;   // copy_in^T bf16 (2MB)
constexpr long CTXW_O  = 16777216;   // ctx @ Wai (8MB)
constexpr long CTXWC_O = 25165824;   // ctx @ Wc  (8MB)
constexpr long CTXOT_O = 33554432;   // (ctx @ Waoc)^T [b][j][s] (8MB)
constexpr long EBF_O   = 41943040;   // emb frag-major [t][...] (2MB)
constexpr long OF0_O   = 44040192;   // OF slot 0 (128KB)
constexpr long H00_O   = 44171264;   // H0 slot 0
constexpr long H10_O   = 44302336;   // H1 slot 0
constexpr long AB_O    = 44433408;   // a f32 [32 t][64 b][64 s] = 512KB
constexpr long AFLAG_O = 44957696;   // per-step a-ready flags [32 t][64 b] u32 = 8KB
constexpr long BAR_O   = 44965888;   // flags[256] + bcast word

// LDS layout (dynamic, 160256 B)
constexpr int W0LDS_O = 0;        // [16 rows][2560] bf16 swizzled = 81920
constexpr int W1LDS_O = 81920;    // [16 rows][2048] bf16 swizzled = 65536
constexpr int SCR_O   = 147456;   // 8 slots x 272 f32 = 8704
constexpr int SCR2_O  = 156160;   // 4096 B

struct KParams {
  const int* input; const float* h0; const float* c0; const float* context;
  const float* init_output; const float* embedding;
  const float* W_ih0; const float* W_hh0; const float* b0;
  const float* W_ih1; const float* W_hh1; const float* b1;
  const float* attn_in; const float* attn_out; const float* copy_in;
  float* out; char* ws;
};

// ---------------- small helpers ----------------
DEVI float bf2f(u16 u) { u32 x = ((u32)u) << 16; return __builtin_bit_cast(float, x); }
DEVI u16 f2bf(float f) {
  u32 x = __builtin_bit_cast(u32, f);
  u32 r = x + 0x7fffu + ((x >> 16) & 1u);   // RNE
  return (u16)(r >> 16);
}
DEVI void cvtc_sc(const float* s, char* d) {   // 4 f32 -> 4 bf16, sc store
  float4 v = *(const float4*)s;
  u32x2 u;
  u[0] = (u32)f2bf(v.x) | ((u32)f2bf(v.y) << 16);
  u[1] = (u32)f2bf(v.z) | ((u32)f2bf(v.w) << 16);
  ST8SC(d, u);
}
DEVI float sigm(float x)  { return 1.f / (1.f + __expf(-x)); }
DEVI float tanh_(float x) { return 1.f - 2.f / (__expf(2.f * x) + 1.f); }
DEVI f32x4 mfma16(bfrag a, bfrag b, f32x4 c) {
  return __builtin_amdgcn_mfma_f32_16x16x32_bf16(a, b, c, 0, 0, 0);
}
// frag-major byte offset for element (m,k) of a [64 m][K k] activation
DEVI u32 fragoff(int m, int k) {
  return (u32)((((k >> 5) * 4 + (m >> 4)) * 64 + ((k >> 3) & 3) * 16 + (m & 15)) * 16 + (k & 7) * 2);
}
// per-step slot addressing (slot 0 = initial state, slot t+1 = written at step t)
DEVI char* of_slot(char* w, int s) { return w + (s ? OFR_O + (long)(s - 1) * 131072 : OF0_O); }
DEVI char* h0_slot(char* w, int s) { return w + (s ? H0R_O + (long)(s - 1) * 131072 : H00_O); }
DEVI char* h1_slot(char* w, int s) { return w + (s ? H1R_O + (long)(s - 1) * 131072 : H10_O); }

// ---------------- barriers ----------------
// arrive: flag store per block.  wait: aggregator block (128) polls all flags
// then broadcasts one generation word; everyone else polls that single line.
DEVI void pollflags(u32* flags, u32 gen) {
  int t = threadIdx.x;   // < 64
  for (;;) {
    u32 a = __hip_atomic_load(&flags[t],       __ATOMIC_RELAXED, __HIP_MEMORY_SCOPE_AGENT);
    u32 b = __hip_atomic_load(&flags[64 + t],  __ATOMIC_RELAXED, __HIP_MEMORY_SCOPE_AGENT);
    u32 c = __hip_atomic_load(&flags[128 + t], __ATOMIC_RELAXED, __HIP_MEMORY_SCOPE_AGENT);
    u32 d = __hip_atomic_load(&flags[192 + t], __ATOMIC_RELAXED, __HIP_MEMORY_SCOPE_AGENT);
    if (__all((a >= gen) && (b >= gen) && (c >= gen) && (d >= gen))) break;
  }
}
DEVI void barr_arrive(u32* flags, u32 gen) {
  VMFLUSH();               // drain sc stores to LLC before signaling
  __syncthreads();
  if (threadIdx.x == 0)
    __hip_atomic_store(&flags[blockIdx.x], gen, __ATOMIC_RELAXED, __HIP_MEMORY_SCOPE_AGENT);
}
DEVI void barr_wait(u32* flags, u32 gen) {
  u32* bc = flags + 320;   // broadcast word, own cache line
  if (blockIdx.x == 128) {
    if (threadIdx.x < 64) pollflags(flags, gen);
    __syncthreads();
    if (threadIdx.x == 0)
      __hip_atomic_store(bc, gen, __ATOMIC_RELAXED, __HIP_MEMORY_SCOPE_AGENT);
  } else {
    if (threadIdx.x == 0) {
      while (__hip_atomic_load(bc, __ATOMIC_RELAXED, __HIP_MEMORY_SCOPE_AGENT) < gen) {}
    }
  }
  __syncthreads();
  asm volatile("" ::: "memory");
}
// fenced barrier (setup only; all-to-all is fine twice)
DEVI void gsync_fence(u32* flags, u32 gen) {
  __syncthreads();
  if (threadIdx.x == 0) {
    __builtin_amdgcn_fence(__ATOMIC_RELEASE, "agent");
    __hip_atomic_store(&flags[blockIdx.x], gen, __ATOMIC_RELAXED, __HIP_MEMORY_SCOPE_AGENT);
  }
  if (threadIdx.x < 64) pollflags(flags, gen);
  if (threadIdx.x == 0) __builtin_amdgcn_fence(__ATOMIC_ACQUIRE, "agent");
  __syncthreads();
}

// ---------------- gate-GEMM segment: cached loads, compiler-pipelined ----------------
template<int N4>
DEVI void gseg(f32x4& acc, const char* Af, int kkA0, int mt, int lane,
               const char* W, int wRowK, int kkW0, int brow, int ke) {
  const u32 sw = (u32)((brow & 7) << 4);
#pragma unroll
  for (int g = 0; g < N4; ++g) {
#pragma unroll
    for (int q = 0; q < 4; ++q) {
      const char* pa = Af + ((((kkA0 + g * 4 + q) * 4 + mt) * 64 + lane) << 4);
      bfrag av = *(const bfrag*)pa;
      int kkW = kkW0 + g * 4 + q;
      u32 off = ((u32)(brow * wRowK + kkW * 32 + ke) * 2) ^ sw;
      acc = mfma16(av, *(const bfrag*)(W + off), acc);
    }
  }
}

DEVI void scr_store(float* scr, int slot, f32x4 acc) {
  const int lane = threadIdx.x & 63;
#pragma unroll
  for (int r = 0; r < 4; ++r)
    scr[slot * 272 + ((lane >> 4) * 4 + r) * 17 + (lane & 15)] = acc[r];
}

// LSTM pointwise: threads 0..63; c-state in registers; one 8B sc h-store
DEVI void pointwise64(int bid, const float* scr, const float* bias, float (&cst)[4], char* hfrag) {
  const int m = threadIdx.x;            // < 64
  const int mt = m >> 4, ml = m & 15;
  u32 hp0 = 0, hp1 = 0;
#pragma unroll
  for (int u = 0; u < 4; ++u) {
    const int j = bid * 4 + u;
    float g0 = scr[(mt*2)*272 + ml*17 + u]      + scr[(mt*2+1)*272 + ml*17 + u]      + bias[j];
    float g1 = scr[(mt*2)*272 + ml*17 + 4 + u]  + scr[(mt*2+1)*272 + ml*17 + 4 + u]  + bias[1024 + j];
    float g2 = scr[(mt*2)*272 + ml*17 + 8 + u]  + scr[(mt*2+1)*272 + ml*17 + 8 + u]  + bias[2048 + j];
    float g3 = scr[(mt*2)*272 + ml*17 + 12 + u] + scr[(mt*2+1)*272 + ml*17 + 12 + u] + bias[3072 + j];
    float cn = sigm(g1) * cst[u] + sigm(g0) * tanh_(g2);
    cst[u] = cn;
    u32 hb = (u32)f2bf(sigm(g3) * tanh_(cn));
    if (u == 0) hp0 = hb; else if (u == 1) hp0 |= hb << 16;
    else if (u == 2) hp1 = hb; else hp1 |= hb << 16;
  }
  u32x2 v; v[0] = hp0; v[1] = hp1;
  ST8SC(hfrag + fragoff(m, bid * 4), v);
}

// copy-attention for one (batch, step): scores from global CtxWc, softmax, AC out
DEVI void copyattn_step(int b, int tau, const u16* CtxWc, const float* outp,
                        float* xch, float* dout) {
  const int tid = threadIdx.x, lane = tid & 63, w = tid >> 6;
  float ov[16];
  {
    const float4* op = (const float4*)(outp + (long)tau * 65536 + b * 1024 + lane * 16);
#pragma unroll
    for (int i = 0; i < 4; ++i) {
      float4 v = op[i];
      ov[4 * i] = v.x; ov[4 * i + 1] = v.y; ov[4 * i + 2] = v.z; ov[4 * i + 3] = v.w;
    }
  }
  const u16* cwb = CtxWc + (long)b * 65536;
#pragma unroll
  for (int si = 0; si < 8; ++si) {
    int s = w * 8 + si;
    const u32* u = (const u32*)(cwb + (long)s * 1024 + lane * 16);
    float acc = 0.f;
#pragma unroll
    for (int i = 0; i < 8; ++i) {
      u32 x = u[i];
      acc += ov[2 * i] * bf2f((u16)(x & 0xffff));
      acc += ov[2 * i + 1] * bf2f((u16)(x >> 16));
    }
#pragma unroll
    for (int off = 32; off; off >>= 1) acc += __shfl_down(acc, off, 64);
    if (lane == 0) xch[s] = acc;
  }
  __syncthreads();
  if (w == 0) {
    float v = xch[lane];
    float mx = v;
#pragma unroll
    for (int off = 32; off; off >>= 1) mx = fmaxf(mx, __shfl_xor(mx, off, 64));
    float e = __expf(v - mx);
    float sm = e;
#pragma unroll
    for (int off = 32; off; off >>= 1) sm += __shfl_xor(sm, off, 64);
    dout[AC_OFF + (long)tau * 4096 + b * 64 + lane] = e / sm;
  }
  // caller must __syncthreads() before reusing xch (P4c does)
}

// setup GEMM: dst[(b,s)][j] = ctx[(b,s),:] . Wrow[j,:]   (sc stores)
DEVI void ctxw_gemm(int mt, const u16* Ctx, const u16* Wm, u16* dst) {
  const int tid = threadIdx.x, lane = tid & 63, w = tid >> 6;
  const int arow = mt * 16 + (lane & 15);
  const int ke = (lane >> 4) * 8;
#pragma unroll
  for (int i = 0; i < 8; ++i) {
    int nt = w * 8 + i;
    const u16* A = Ctx + (long)arow * 1024 + ke;
    const u16* B = Wm + (long)(nt * 16 + (lane & 15)) * 1024 + ke;
    f32x4 acc = {0.f, 0.f, 0.f, 0.f};
    for (int kk = 0; kk < 1024; kk += 32)
      acc = mfma16(*(const bfrag*)(A + kk), *(const bfrag*)(B + kk), acc);
#pragma unroll
    for (int r = 0; r < 4; ++r)
      ST2SC((char*)(dst + (long)(mt * 16 + (lane >> 4) * 4 + r) * 1024 + nt * 16 + (lane & 15)),
            (u32)f2bf(acc[r]));
  }
}

// setup GEMM: CtxOT[b][j][s] = ctx[(b,s),:] . Wao[j, 0..1024]   (sc stores)
DEVI void ctxo_gemm(int bid, const u16* Ctx, const u16* Wao, u16* dst) {
  const int tid = threadIdx.x, lane = tid & 63, w = tid >> 6;
  const int arow = bid * 16 + (lane & 15);
  const int ke = (lane >> 4) * 8;
  const int b = bid >> 2, s0 = (bid & 3) * 16 + (lane >> 4) * 4;
#pragma unroll
  for (int i = 0; i < 8; ++i) {
    int nt = w * 8 + i;
    int j = nt * 16 + (lane & 15);
    const u16* A = Ctx + (long)arow * 1024 + ke;
    const u16* B = Wao + (long)j * 2048 + ke;
    f32x4 acc = {0.f, 0.f, 0.f, 0.f};
    for (int kk = 0; kk < 1024; kk += 32)
      acc = mfma16(*(const bfrag*)(A + kk), *(const bfrag*)(B + kk), acc);
    u32x2 q;
    q[0] = (u32)f2bf(acc[0]) | ((u32)f2bf(acc[1]) << 16);
    q[1] = (u32)f2bf(acc[2]) | ((u32)f2bf(acc[3]) << 16);
    ST8SC((char*)(dst + ((long)(b * 1024 + j) * 64 + s0)), q);
  }
}

// ---------------- the kernel ----------------
__global__ __launch_bounds__(512, 1) void decoder_kernel(KParams p) {
  extern __shared__ char smem[];
  char*  W0   = smem + W0LDS_O;
  char*  W1   = smem + W1LDS_O;
  float* scr  = (float*)(smem + SCR_O);
  float* scr2 = (float*)(smem + SCR2_O);

  char* wsb = p.ws;
  u16* Wao   = (u16*)(wsb + WAO_O);
  u16* Wai   = (u16*)(wsb + WAI_O);
  u16* Wc    = (u16*)(wsb + WC_O);
  u16* Ctx   = (u16*)(wsb + CTX_O);
  u16* CtxW  = (u16*)(wsb + CTXW_O);
  u16* CtxWc = (u16*)(wsb + CTXWC_O);
  u16* CtxOT = (u16*)(wsb + CTXOT_O);
  u32* bar   = (u32*)(wsb + BAR_O);

  const int bid = blockIdx.x, tid = threadIdx.x;
  const int lane = tid & 63, w = tid >> 6;
  const long gtid = (long)bid * 512 + tid, NT = 256l * 512;
  u32 gen = 1;

  // ---- S0-pre: LDS-tiled transposes of attn_in / copy_in (sc out) ----
  {
    float* tile = (float*)smem;
    for (int pass = 0; pass < 2; ++pass) {
      const float* src = pass ? p.copy_in : p.attn_in;
      u16* dst = pass ? Wc : Wai;
      int tr = bid >> 4, tc = bid & 15;
      {
        int r = tid >> 3, c = (tid & 7) * 8;
        const float4* s4 = (const float4*)(src + (long)(tr * 64 + r) * 1024 + tc * 64 + c);
        float4 a = s4[0], b = s4[1];
        float* tp = tile + r * 69 + c;
        tp[0] = a.x; tp[1] = a.y; tp[2] = a.z; tp[3] = a.w;
        tp[4] = b.x; tp[5] = b.y; tp[6] = b.z; tp[7] = b.w;
      }
      __syncthreads();
      {
        int r2 = tid >> 3, c2 = (tid & 7) * 8;
        u32x4 q;
#pragma unroll
        for (int i = 0; i < 4; ++i) {
          float lo = tile[(c2 + 2 * i) * 69 + r2];
          float hi = tile[(c2 + 2 * i + 1) * 69 + r2];
          q[i] = (u32)f2bf(lo) | ((u32)f2bf(hi) << 16);
        }
        ST16SC((char*)(dst + (long)(tc * 64 + r2) * 1024 + tr * 64 + c2), q);
      }
      __syncthreads();
    }
  }

  // ---- S0a: per-block weight slices -> LDS (stationary all 32 steps) ----
  for (int i = tid; i < 5120; i += 512) {
    int row = i / 320, k = (i % 320) * 8;
    int R = (row >> 2) * 1024 + bid * 4 + (row & 3);
    const float* src = (k < 1536) ? (p.W_ih0 + (long)R * 1536 + k)
                                  : (p.W_hh0 + (long)R * 1024 + (k - 1536));
    float4 a = *(const float4*)src, b = *(const float4*)(src + 4);
    uint4 q;
    q.x = (u32)f2bf(a.x) | ((u32)f2bf(a.y) << 16);
    q.y = (u32)f2bf(a.z) | ((u32)f2bf(a.w) << 16);
    q.z = (u32)f2bf(b.x) | ((u32)f2bf(b.y) << 16);
    q.w = (u32)f2bf(b.z) | ((u32)f2bf(b.w) << 16);
    u32 off = ((u32)(row * 2560 + k) * 2) ^ ((u32)((row & 7) << 4));
    *(uint4*)(W0 + off) = q;
  }
  for (int i = tid; i < 4096; i += 512) {
    int row = i / 256, k = (i % 256) * 8;
    int R = (row >> 2) * 1024 + bid * 4 + (row & 3);
    const float* src = (k < 1024) ? (p.W_ih1 + (long)R * 1024 + k)
                                  : (p.W_hh1 + (long)R * 1024 + (k - 1024));
    float4 a = *(const float4*)src, b = *(const float4*)(src + 4);
    uint4 q;
    q.x = (u32)f2bf(a.x) | ((u32)f2bf(a.y) << 16);
    q.y = (u32)f2bf(a.z) | ((u32)f2bf(a.w) << 16);
    q.z = (u32)f2bf(b.x) | ((u32)f2bf(b.y) << 16);
    q.w = (u32)f2bf(b.z) | ((u32)f2bf(b.w) << 16);
    u32 off = ((u32)(row * 2048 + k) * 2) ^ ((u32)((row & 7) << 4));
    *(uint4*)(W1 + off) = q;
  }

  // ---- S0b: global conversions (all sc stores) ----
  for (long i = gtid; i < 524288; i += NT) cvtc_sc(p.attn_out + i * 4, (char*)(Wao + i * 4));
  for (long i = gtid; i < 1048576; i += NT) {
    long b = i >> 14, s = (i >> 8) & 63, kq = i & 255;
    cvtc_sc(p.context + ((s * 64 + b) * 1024 + kq * 4), (char*)(Ctx + i * 4));
  }
  for (long i = gtid; i < 262144; i += NT) {     // emb gather -> frag-major
    long row = i >> 7; long t = row >> 6, b = row & 63;
    long k0 = (i & 127) * 4;
    long tok = p.input[row];
    cvtc_sc(p.embedding + tok * 512 + k0, wsb + EBF_O + t * 65536 + fragoff((int)b, (int)k0));
  }
  for (long i = gtid; i < 16384; i += NT) {      // init_output -> OF slot 0
    long b = i >> 8, k0 = (i & 255) * 4;
    cvtc_sc(p.init_output + i * 4, of_slot(wsb, 0) + fragoff((int)b, (int)k0));
  }
  for (long i = gtid; i < 32768; i += NT) {      // h0 -> h slots 0
    long l = i >> 14, rem = i & 16383, b = rem >> 8, k0 = (rem & 255) * 4;
    cvtc_sc(p.h0 + i * 4, (l ? h1_slot(wsb, 0) : h0_slot(wsb, 0)) + fragoff((int)b, (int)k0));
  }

  // ---- c-state -> registers (threads 0..63; thread m owns (m, j=bid*4+u)) ----
  float cR0[4] = {0.f, 0.f, 0.f, 0.f}, cR1[4] = {0.f, 0.f, 0.f, 0.f};
  if (tid < 64) {
#pragma unroll
    for (int u = 0; u < 4; ++u) {
      cR0[u] = p.c0[(long)tid * 1024 + bid * 4 + u];
      cR1[u] = p.c0[65536 + (long)tid * 1024 + bid * 4 + u];
    }
  }

  gsync_fence(bar, gen); ++gen;

  // ---- S1: attention tables ----
  ctxw_gemm(bid, Ctx, Wai, CtxW);
  ctxw_gemm(bid, Ctx, Wc, CtxWc);
  ctxo_gemm(bid, Ctx, Wao, CtxOT);
  gsync_fence(bar, gen); ++gen;

  // ---- P4 geometry (XCD-pinned) + Wao h1-half fragments in registers ----
  const int xcd = bid & 7, idx = bid >> 3;
  const int ntP4 = xcd * 8 + (idx & 7), mtP4 = idx >> 3;
  const int browP4 = ntP4 * 16 + (lane & 15);
  const int ke_ = (lane >> 4) * 8;
  bfrag waoreg[4];
#pragma unroll
  for (int q = 0; q < 4; ++q)
    waoreg[q] = *(const bfrag*)(Wao + (long)browP4 * 2048 + 1024 + (w * 4 + q) * 32 + ke_);

  const int mt_ = w & 3, kh_ = w >> 2;
  const int brow_ = lane & 15;

  // ---- pre-loop P1(0) lookahead: emb(0) + h0 slot 0 ----
  f32x4 accP1 = {0.f, 0.f, 0.f, 0.f}, accP2;
  {
    const char* E0  = wsb + EBF_O;
    const char* H0p = h0_slot(wsb, 0);
    if (kh_ == 0) {
      gseg<2>(accP1, E0,  0,  mt_, lane, W0, 2560, 0,  brow_, ke_);
      gseg<4>(accP1, H0p, 0,  mt_, lane, W0, 2560, 48, brow_, ke_);
    } else {
      gseg<2>(accP1, E0,  8,  mt_, lane, W0, 2560, 8,  brow_, ke_);
      gseg<4>(accP1, H0p, 16, mt_, lane, W0, 2560, 64, brow_, ke_);
    }
  }

  for (int t = 0; t < 32; ++t) {
    const char* OFc   = of_slot(wsb, t);
    char*       Hb0cF = h0_slot(wsb, t + 1);
    char*       Hb1cF = h1_slot(wsb, t + 1);
    const char* Hb1pF = h1_slot(wsb, t);
    char*       ABt   = wsb + AB_O + (long)t * 16384;

    // ---- P1 remainder: out-feed segment ----
    {
      f32x4 acc = accP1;
      if (kh_ == 0) gseg<4>(acc, OFc, 0,  mt_, lane, W0, 2560, 16, brow_, ke_);
      else          gseg<4>(acc, OFc, 16, mt_, lane, W0, 2560, 32, brow_, ke_);
      scr_store(scr, mt_ * 2 + kh_, acc);
      __syncthreads();
      if (tid < 64) pointwise64(bid, scr, p.b0, cR0, Hb0cF);
    }
    barr_arrive(bar, gen);
    // P2 lookahead: h1prev segment
    accP2 = f32x4{0.f, 0.f, 0.f, 0.f};
    if (kh_ == 0) gseg<4>(accP2, Hb1pF, 0,  mt_, lane, W1, 2048, 32, brow_, ke_);
    else          gseg<4>(accP2, Hb1pF, 16, mt_, lane, W1, 2048, 48, brow_, ke_);
    barr_wait(bar, gen); ++gen;

    // ---- P2 remainder: h0new segment ----
    {
      f32x4 acc = accP2;
      if (kh_ == 0) gseg<4>(acc, Hb0cF, 0,  mt_, lane, W1, 2048, 0,  brow_, ke_);
      else          gseg<4>(acc, Hb0cF, 16, mt_, lane, W1, 2048, 16, brow_, ke_);
      scr_store(scr, mt_ * 2 + kh_, acc);
      __syncthreads();
      if (tid < 64) pointwise64(bid, scr, p.b1, cR1, Hb1cF);
    }
    barr_arrive(bar, gen);
    // P1(t+1) lookahead part A: emb(t+1) + first half of h0(t+1)
    accP1 = f32x4{0.f, 0.f, 0.f, 0.f};
    {
      const char* En = wsb + EBF_O + (long)((t + 1) & 31) * 65536;
      if (kh_ == 0) {
        gseg<2>(accP1, En,    0,  mt_, lane, W0, 2560, 0,  brow_, ke_);
        gseg<2>(accP1, Hb0cF, 0,  mt_, lane, W0, 2560, 48, brow_, ke_);
      } else {
        gseg<2>(accP1, En,    8,  mt_, lane, W0, 2560, 8,  brow_, ke_);
        gseg<2>(accP1, Hb0cF, 16, mt_, lane, W0, 2560, 64, brow_, ke_);
      }
    }
    barr_wait(bar, gen); ++gen;

    // ---- P3 (blocks 0..63): scores + softmax -> a(t) + per-batch ready flag ----
    if (bid < 64) {
      const int b = bid;
      float h1v[16];
      {
        int k0 = lane * 16;
        const u32* hp0 = (const u32*)(Hb1cF + fragoff(b, k0));
        const u32* hp1 = (const u32*)(Hb1cF + fragoff(b, k0 + 8));
        u32 uu[8] = {hp0[0], hp0[1], hp0[2], hp0[3], hp1[0], hp1[1], hp1[2], hp1[3]};
#pragma unroll
        for (int i = 0; i < 8; ++i) {
          h1v[2 * i]     = bf2f((u16)(uu[i] & 0xffff));
          h1v[2 * i + 1] = bf2f((u16)(uu[i] >> 16));
        }
      }
      const u16* cwb = CtxW + (long)b * 65536;
#pragma unroll
      for (int si = 0; si < 8; ++si) {
        int s = w * 8 + si;
        const u32* u = (const u32*)(cwb + (long)s * 1024 + lane * 16);
        float acc = 0.f;
#pragma unroll
        for (int i = 0; i < 8; ++i) {
          u32 x = u[i];
          acc += h1v[2 * i] * bf2f((u16)(x & 0xffff));
          acc += h1v[2 * i + 1] * bf2f((u16)(x >> 16));
        }
#pragma unroll
        for (int off = 32; off; off >>= 1) acc += __shfl_down(acc, off, 64);
        if (lane == 0) scr2[s] = acc;
      }
      __syncthreads();
      if (w == 0) {
        float v = scr2[lane];
        float mx = v;
#pragma unroll
        for (int off = 32; off; off >>= 1) mx = fmaxf(mx, __shfl_xor(mx, off, 64));
        float e = __expf(v - mx);
        float sm = e;
#pragma unroll
        for (int off = 32; off; off >>= 1) sm += __shfl_xor(sm, off, 64);
        float a = e / sm;
        ST4SC(ABt + (u32)(b * 64 + lane) * 4, __builtin_bit_cast(u32, a));
        ST4SC((char*)(p.out + AS_OFF + (long)t * 4096 + b * 64 + lane), __builtin_bit_cast(u32, a));
        VMFLUSH();   // a-values at LLC before ready flag
        if (lane == 0)
          ST4SC(wsb + AFLAG_O + ((u32)t * 64 + b) * 4, 1u);
      }
      __syncthreads();   // release scr2 before P4h (not used) / P4c stage
    }
    // P4h: h1-half of out-projection (all blocks, 8-way K-split)
    {
      const char* bp = Hb1cF;
      bfrag h0_ = *(const bfrag*)(bp + ((((w * 4 + 0) * 4 + mtP4) * 64 + lane) << 4));
      bfrag h1_ = *(const bfrag*)(bp + ((((w * 4 + 1) * 4 + mtP4) * 64 + lane) << 4));
      bfrag h2_ = *(const bfrag*)(bp + ((((w * 4 + 2) * 4 + mtP4) * 64 + lane) << 4));
      bfrag h3_ = *(const bfrag*)(bp + ((((w * 4 + 3) * 4 + mtP4) * 64 + lane) << 4));
      f32x4 a4 = {0.f, 0.f, 0.f, 0.f};
      a4 = mfma16(h0_, waoreg[0], a4);
      a4 = mfma16(h1_, waoreg[1], a4);
      a4 = mfma16(h2_, waoreg[2], a4);
      a4 = mfma16(h3_, waoreg[3], a4);
      scr_store(scr, w, a4);
    }
    // in-loop copy-attention for step t-1 (blocks 192..255, otherwise idle here)
    if (bid >= 192 && t > 0)
      copyattn_step(bid - 192, t - 1, CtxWc, p.out, scr2, p.out);

    // ---- P4c: prefetch CtxOT -> regs, poll a-ready flags, then combine ----
    {
      const int pair = tid >> 1, half = tid & 1;
      const int m_l = pair >> 4, j_l = pair & 15;
      const int b = mtP4 * 16 + m_l, j = ntP4 * 16 + j_l;
      u32 cpr[16];
      {
        const u32* cp = (const u32*)(CtxOT + ((long)(b * 1024 + j) * 64 + half * 32));
#pragma unroll
        for (int i = 0; i < 16; ++i) cpr[i] = cp[i];
      }
      if (tid < 16) {
        const u32* fp = (const u32*)(wsb + AFLAG_O + ((u32)t * 64 + mtP4 * 16 + tid) * 4);
        while (__hip_atomic_load(fp, __ATOMIC_RELAXED, __HIP_MEMORY_SCOPE_AGENT) == 0) {}
      }
      __syncthreads();
      {
        int b0i = tid >> 6, s0i = tid & 63;
        int b1i = (tid + 512) >> 6;
        scr2[tid]       = *(const float*)(ABt + (u32)(((mtP4 * 16 + b0i) * 64 + s0i)) * 4);
        scr2[tid + 512] = *(const float*)(ABt + (u32)(((mtP4 * 16 + b1i) * 64 + s0i)) * 4);
      }
      __syncthreads();
      const float* al = scr2 + m_l * 64 + half * 32;
      float acc = 0.f;
#pragma unroll
      for (int i = 0; i < 16; ++i) {
        u32 x = cpr[i];
        acc += al[2 * i] * bf2f((u16)(x & 0xffff));
        acc += al[2 * i + 1] * bf2f((u16)(x >> 16));
      }
      float v = acc + __shfl_xor(acc, 1, 64);
      if (half == 0) {
        float h1p = 0.f;
#pragma unroll
        for (int q = 0; q < 8; ++q) h1p += scr[q * 272 + m_l * 17 + j_l];
        v = tanh_(v + h1p);
        ST4SC((char*)(p.out + (long)t * 65536 + b * 1024 + j), __builtin_bit_cast(u32, v));
        u32 hv = (u32)f2bf(v);
        ST2SC(of_slot(wsb, t + 1) + fragoff(b, j), hv);
      }
    }
    barr_arrive(bar, gen);
    // P1(t+1) lookahead part B: second half of h0(t+1)
    if (kh_ == 0) gseg<2>(accP1, Hb0cF, 8,  mt_, lane, W0, 2560, 56, brow_, ke_);
    else          gseg<2>(accP1, Hb0cF, 24, mt_, lane, W0, 2560, 72, brow_, ke_);
    barr_wait(bar, gen); ++gen;
  }

  // ---- epilogue: final states (slot 32; h from frag, c from registers) ----
  if (tid < 64) {
#pragma unroll
    for (int u = 0; u < 4; ++u) {
      int j = bid * 4 + u;
      p.out[CT_OFF + (long)tid * 1024 + j]         = cR0[u];
      p.out[CT_OFF + 65536 + (long)tid * 1024 + j] = cR1[u];
    }
  }
  if (tid < 256) {
    int u = tid >> 6, m = tid & 63, j = bid * 4 + u;
    u16 a0 = *(const u16*)(h0_slot(wsb, 32) + fragoff(m, j));
    u16 a1 = *(const u16*)(h1_slot(wsb, 32) + fragoff(m, j));
    p.out[HT_OFF + (long)m * 1024 + j]         = bf2f(a0);
    p.out[HT_OFF + 65536 + (long)m * 1024 + j] = bf2f(a1);
  }

  // ---- final copy-attention step (tau = 31) ----
  if (bid >= 192) {
    __syncthreads();
    copyattn_step(bid - 192, 31, CtxWc, p.out, scr2, p.out);
  }
}

// ---------------- host ----------------
extern "C" void kernel_launch(void* const* d_in, const int* in_sizes, int n_in,
                              void* d_out, int out_size, void* d_ws, size_t ws_size,
                              hipStream_t stream) {
  KParams p;
  p.input       = (const int*)d_in[0];
  p.h0          = (const float*)d_in[1];
  p.c0          = (const float*)d_in[2];
  p.context     = (const float*)d_in[3];
  p.init_output = (const float*)d_in[4];
  p.embedding   = (const float*)d_in[5];
  p.W_ih0       = (const float*)d_in[6];
  p.W_hh0       = (const float*)d_in[7];
  p.b0          = (const float*)d_in[8];
  p.W_ih1       = (const float*)d_in[9];
  p.W_hh1       = (const float*)d_in[10];
  p.b1          = (const float*)d_in[11];
  p.attn_in     = (const float*)d_in[12];
  p.attn_out    = (const float*)d_in[13];
  p.copy_in     = (const float*)d_in[14];
  p.out         = (float*)d_out;
  p.ws          = (char*)d_ws;

  (void)hipFuncSetAttribute((const void*)decoder_kernel,
                            hipFuncAttributeMaxDynamicSharedMemorySize, 160256);
  // zero: a-buffer (512KB) + a-ready flags (8KB) + barrier flags/bcast (2KB)
  (void)hipMemsetAsync((char*)d_ws + AB_O, 0, 534528, stream);
  void* args[] = { &p };
  (void)hipLaunchCooperativeKernel((void*)decoder_kernel, dim3(256), dim3(512),
                                   args, 160256, stream);
}